// Round 9
// baseline (632.817 us; speedup 1.0000x reference)
//
#include <hip/hip_runtime.h>
#include <math.h>

#define IMH 192
#define IMW 192
#define HWF 36864
#define PDIM 194

typedef unsigned short u16t;
typedef __attribute__((ext_vector_type(8))) short short8;
typedef __attribute__((ext_vector_type(4))) float f32x4;

__device__ __forceinline__ float sigmoidf(float x){ return 1.f/(1.f+expf(-x)); }
__device__ __forceinline__ float lrelu(float x){ return x > 0.f ? x : 0.1f*x; }
__device__ __forceinline__ float b2f(u16t h){ unsigned u = ((unsigned)h)<<16; return __uint_as_float(u); }
__device__ __forceinline__ u16t f2b(float f){
  unsigned u = __float_as_uint(f);
  u += 0x7FFFu + ((u>>16)&1u);
  return (u16t)(u>>16);
}

__device__ __forceinline__ float bilin(const float* __restrict__ img, float ys, float xs, int H, int W){
  float y0f = floorf(ys), x0f = floorf(xs);
  float wy = ys - y0f, wx = xs - x0f;
  int y0 = (int)y0f, x0 = (int)x0f;
  float acc = 0.f;
  #pragma unroll
  for (int dy=0; dy<2; ++dy){
    int yi = y0+dy;
    float wyv = dy ? wy : 1.f-wy;
    if (yi < 0 || yi >= H) continue;
    #pragma unroll
    for (int dx=0; dx<2; ++dx){
      int xi = x0+dx;
      float wxv = dx ? wx : 1.f-wx;
      if (xi < 0 || xi >= W) continue;
      acc += img[yi*W+xi]*(wyv*wxv);
    }
  }
  return acc;
}

// ================= descriptor-driven setup kernels =================
struct PkD { const float* w; u16t* dst; int Cin, Cout, NT, total; };
struct PkD8 { PkD d[8]; };
__global__ __launch_bounds__(256) void pack_all(PkD8 ds){
  PkD d = ds.d[blockIdx.y];
  int id = blockIdx.x*256 + threadIdx.x;
  if (id >= d.total) return;
  int j = id & 7, l = (id>>3) & 63;
  int r = id >> 9;
  int nt = r % d.NT; r /= d.NT;
  int KC = d.Cin >> 5;
  int kc = r % KC; int tap = r / KC;
  int c = kc*32 + ((l>>4)<<3) + j;
  int o = nt*16 + (l&15);
  float v = (o < d.Cout) ? d.w[((size_t)o*d.Cin + c)*9 + tap] : 0.f;
  d.dst[id] = f2b(v);
}

// conv1 weights (64,1,3,3) -> MFMA B-frag, K padded 9->32: [nt][lane][8]
__global__ __launch_bounds__(256) void pack_w1(const float* __restrict__ w1, u16t* __restrict__ dst){
  int id = blockIdx.x*256 + threadIdx.x;   // 2048
  int j = id & 7, l = (id>>3) & 63, nt = id >> 9;
  int o = nt*16 + (l&15);
  int k = ((l>>4)<<3) + j;
  float v = (k < 9) ? w1[o*9 + k] : 0.f;
  dst[id] = f2b(v);
}

struct RpD { const float* w; float* wp; };
struct RpD3 { RpD d[3]; };
__global__ __launch_bounds__(256) void repack_all(RpD3 ds){
  RpD d = ds.d[blockIdx.y];
  int id = blockIdx.x*256 + threadIdx.x;
  int par = id >> 12, o = (id >> 6) & 63, i = id & 63;
  int ry = par >> 1, rx = par & 1;
  #pragma unroll
  for (int jy = 0; jy < 2; ++jy)
    #pragma unroll
    for (int jx = 0; jx < 2; ++jx){
      int ka = 3 - ry - 2*jy, kb = 3 - rx - 2*jx;
      d.wp[((size_t)((par*64 + o)*64 + i))*4 + jy*2 + jx] = d.w[((size_t)(i*64 + o))*16 + ka*4 + kb];
    }
}

struct PzD { u16t* buf; int C, dim, nimg; size_t stride; };
struct PzD5 { PzD d[5]; };
__global__ __launch_bounds__(256) void padzero_all(PzD5 ds){
  PzD d = ds.d[blockIdx.y];
  int per = (4*d.dim - 4)*d.C;
  long total = (long)per*d.nimg;
  for (long id = (long)blockIdx.x*256 + threadIdx.x; id < total; id += (long)gridDim.x*256){
    int n = (int)(id / per), c2 = (int)(id % per);
    int cell = c2 / d.C, c = c2 % d.C;
    int d2 = d.dim - 1;
    int r, col;
    if (cell < d.dim){ r = 0; col = cell; }
    else if (cell < 2*d.dim){ r = d2; col = cell - d.dim; }
    else if (cell < 3*d.dim - 2){ r = cell - 2*d.dim + 1; col = 0; }
    else { r = cell - (3*d.dim - 2) + 1; col = d2; }
    d.buf[(size_t)n*d.stride + ((size_t)r*d.dim + col)*d.C + c] = 0;
  }
}

__global__ __launch_bounds__(256) void padzero2(u16t* buf, int C, int dim){
  int total = (4*dim - 4)*C;
  for (int id = blockIdx.x*256 + threadIdx.x; id < total; id += gridDim.x*256){
    int cell = id / C, c = id % C;
    int d2 = dim - 1;
    int r, col;
    if (cell < dim){ r = 0; col = cell; }
    else if (cell < 2*dim){ r = d2; col = cell - dim; }
    else if (cell < 3*dim - 2){ r = cell - 2*dim + 1; col = 0; }
    else { r = cell - (3*dim - 2) + 1; col = d2; }
    buf[((size_t)r*dim + col)*C + c] = 0;
  }
}

// ========== fused backbone: conv1 (1->64, MFMA K=9 padded to 32) + conv2 (64->64, MFMA) ==========
// Block = 4-row x 16-px x 64-ch conv2-output tile. Stage 8x20 raw fp32 input in LDS;
// conv1 via MFMA (wave w = o-tile w, 7 px-tiles); feat1 -> swizzled sA (stride 64,
// slot=(g+px)&7); conv2 MFMA from sA. img<7 -> fpad NHWC448 padded, else prednhwc tight.
__global__ __launch_bounds__(256) void bbfused(
    const float* __restrict__ lqs, const float* __restrict__ preds,
    const u16t* __restrict__ w1pack, const float* __restrict__ b1,
    const u16t* __restrict__ Bp, const float* __restrict__ b2,
    u16t* __restrict__ fpad, u16t* __restrict__ prednhwc)
{
  __shared__ float sIn1[8][20];
  __shared__ u16t sA[108*64];
  int bid = blockIdx.x;
  bid = (bid & 7)*(gridDim.x >> 3) + (bid >> 3);       // XCD banding
  const int tid = threadIdx.x;
  const int img = bid / 576;
  const int rem = bid - img*576;
  const int y0 = (rem/12)*4, xs = (rem%12)*16;
  const float* ip = (img < 7) ? (lqs + (size_t)img*HWF) : (preds + (size_t)(img-7)*HWF);
  for (int u = tid; u < 160; u += 256){
    int lr = u/20, lc = u%20;
    int iy = y0 - 2 + lr, ix = xs - 2 + lc;
    sIn1[lr][lc] = (iy >= 0 && iy < IMH && ix >= 0 && ix < IMW) ? ip[iy*IMW + ix] : 0.f;
  }
  __syncthreads();
  const int wave = tid >> 6, lane = tid & 63;
  const int m = lane & 15, q = lane >> 4;
  // ---- conv1 via MFMA: wave = o-tile (16 ch), 7 px-tiles of 16 ----
  short8 bfr = *(const short8*)(w1pack + (size_t)wave*512 + lane*8);
  f32x4 c1[7];
  #pragma unroll
  for (int p = 0; p < 7; ++p){
    int px = p*16 + m;
    bool valid = px < 108;
    int rr = valid ? px/18 : 0, cc = valid ? px%18 : 0;
    short8 av = {0,0,0,0,0,0,0,0};
    #pragma unroll
    for (int j = 0; j < 8; ++j){
      int k = q*8 + j;
      if (valid && k < 9){
        av[j] = (short)f2b(sIn1[rr + k/3][cc + k%3]);
      }
    }
    f32x4 z = {0.f,0.f,0.f,0.f};
    c1[p] = __builtin_amdgcn_mfma_f32_16x16x32_bf16(av, bfr, z, 0, 0, 0);
  }
  // ---- feat1 epilogue -> swizzled sA (C/D: col=lane&15 -> o, row=q*4+r -> px) ----
  {
    int o = wave*16 + m;
    float b1v = b1[o];
    int g = o >> 3, ol = o & 7;
    #pragma unroll
    for (int p = 0; p < 7; ++p){
      #pragma unroll
      for (int r = 0; r < 4; ++r){
        int pxo = p*16 + q*4 + r;
        if (pxo >= 108) continue;
        int rr2 = pxo/18, cc2 = pxo%18;
        int pr = y0 + rr2, pc = xs + cc2;
        bool border = (pr == 0) | (pr == 193) | (pc == 0) | (pc == 193);
        float v = c1[p][r] + b1v;
        sA[(size_t)pxo*64 + ((g + pxo)&7)*8 + ol] = border ? (u16t)0 : f2b(v);
      }
    }
  }
  __syncthreads();
  // ---- conv2 MFMA from sA ----
  const int rp = wave >> 1, np = wave & 1;
  f32x4 acc[2][2];
  #pragma unroll
  for (int r = 0; r < 2; ++r)
    #pragma unroll
    for (int n = 0; n < 2; ++n) acc[r][n] = (f32x4){0.f,0.f,0.f,0.f};
  #pragma unroll
  for (int kc = 0; kc < 2; ++kc){
    #pragma unroll
    for (int tap = 0; tap < 9; ++tap){
      const int dy = tap/3, dx = tap%3;
      short8 af[2];
      #pragma unroll
      for (int r = 0; r < 2; ++r){
        int px = (2*rp + r + dy)*18 + dx + m;
        af[r] = *(const short8*)&sA[(size_t)px*64 + ((kc*4 + q + px)&7)*8];
      }
      const u16t* bp = Bp + ((size_t)(tap*2 + kc)*4 + np*2)*512 + lane*8;
      short8 b0 = *(const short8*)bp;
      short8 b1v = *(const short8*)(bp + 512);
      #pragma unroll
      for (int r = 0; r < 2; ++r){
        acc[r][0] = __builtin_amdgcn_mfma_f32_16x16x32_bf16(af[r], b0, acc[r][0], 0, 0, 0);
        acc[r][1] = __builtin_amdgcn_mfma_f32_16x16x32_bf16(af[r], b1v, acc[r][1], 0, 0, 0);
      }
    }
  }
  const int px0 = q*4;
  #pragma unroll
  for (int r = 0; r < 2; ++r){
    int yout = y0 + 2*rp + r;
    #pragma unroll
    for (int n = 0; n < 2; ++n){
      int oL = (np*2 + n)*16 + m;
      float bv = b2[oL];
      #pragma unroll
      for (int g = 0; g < 4; ++g){
        int px = xs + px0 + g;
        float v = acc[r][n][g] + bv;
        if (img < 7)
          fpad[((size_t)(yout+1)*PDIM + px+1)*448 + (size_t)img*64 + oL] = f2b(v);
        else
          prednhwc[(size_t)(img-7)*((size_t)HWF*64) + ((size_t)yout*IMW + px)*64 + oL] = f2b(v);
      }
    }
  }
}

// ========== LDS-staged MFMA implicit-GEMM 3x3 stride-1 conv (swizzled sA, stride 32) ==========
// OMODE 4: fuse epilogue 0.1*lrelu(s)+lrelu(f) -> out0pad; OMODE 5: fp32 NCHW, blockIdx.y=o-block
template<int STREAMS, int KC, int OMODE, int NTT, int SWZ>
__global__ __launch_bounds__(256) void cgemm(
    const u16t* __restrict__ A0, const u16t* __restrict__ A1,
    const u16t* __restrict__ Bp, const float* __restrict__ bias,
    float* __restrict__ outf, u16t* __restrict__ outb, u16t* __restrict__ outb2,
    int Cout, int blocksPerImg, int pitchIn, int csIn, size_t aImgStride, int KCtot)
{
  __shared__ u16t sA[STREAMS*108*32];
  int bid = blockIdx.x;
  if (SWZ) bid = (bid & 7)*(gridDim.x >> 3) + (bid >> 3);
  const int tid = threadIdx.x;
  const int wave = tid >> 6, lane = tid & 63;
  const int m = lane & 15, q = lane >> 4;
  const int img = bid / blocksPerImg;
  const int rem = bid - img*blocksPerImg;
  const int y0 = (rem/12)*4, xs = (rem%12)*16;
  const int rp = wave >> 1, np = wave & 1;
  const int ntB = (OMODE == 5) ? blockIdx.y*4 : 0;
  f32x4 acc[STREAMS][2][2];
  #pragma unroll
  for (int s = 0; s < STREAMS; ++s)
    #pragma unroll
    for (int r = 0; r < 2; ++r)
      #pragma unroll
      for (int n = 0; n < 2; ++n) acc[s][r][n] = (f32x4){0.f,0.f,0.f,0.f};

  #pragma unroll 1
  for (int kc = 0; kc < KC; ++kc){
    if (kc) __syncthreads();
    for (int u = tid; u < STREAMS*216; u += 256){
      int st = u/216, r2 = u%216, p = r2>>1, h = r2&1;
      int rr = p/18, cc = p%18;
      size_t ga = (size_t)img*aImgStride + ((size_t)(y0+rr)*pitchIn + xs+cc)*csIn + kc*32 + h*16;
      const u16t* gp = ((STREAMS==2 && st==1) ? A1 : A0) + ga;
      short8 v0 = *(const short8*)gp;
      short8 v1 = *(const short8*)(gp + 8);
      u16t* base = &sA[((size_t)(st*108 + p))*32];
      *(short8*)(base + ((2*h + p)&3)*8) = v0;
      *(short8*)(base + ((2*h + 1 + p)&3)*8) = v1;
    }
    __syncthreads();
    #pragma unroll
    for (int tap = 0; tap < 9; ++tap){
      const int dy = tap/3, dx = tap%3;
      short8 af[STREAMS][2];
      #pragma unroll
      for (int st = 0; st < STREAMS; ++st)
        #pragma unroll
        for (int r = 0; r < 2; ++r){
          int px = (2*rp + r + dy)*18 + dx + m;
          af[st][r] = *(const short8*)&sA[((size_t)(st*108 + px))*32 + ((q + px)&3)*8];
        }
      const u16t* bp = Bp + ((size_t)(tap*KCtot + kc)*NTT + ntB + np*2)*512 + lane*8;
      short8 b0 = *(const short8*)bp;
      short8 b1 = *(const short8*)(bp + 512);
      #pragma unroll
      for (int st = 0; st < STREAMS; ++st)
        #pragma unroll
        for (int r = 0; r < 2; ++r){
          acc[st][r][0] = __builtin_amdgcn_mfma_f32_16x16x32_bf16(af[st][r], b0, acc[st][r][0], 0, 0, 0);
          acc[st][r][1] = __builtin_amdgcn_mfma_f32_16x16x32_bf16(af[st][r], b1, acc[st][r][1], 0, 0, 0);
        }
    }
  }
  const int px0 = q*4;
  #pragma unroll
  for (int r = 0; r < 2; ++r){
    int yout = y0 + 2*rp + r;
    #pragma unroll
    for (int n = 0; n < 2; ++n){
      int oL = (np*2 + n)*16 + m;
      if (OMODE == 4){
        float bv = bias[oL];
        #pragma unroll
        for (int g = 0; g < 4; ++g){
          int px = xs + px0 + g;
          float v = 0.1f*lrelu(acc[0][r][n][g] + bv) + lrelu(acc[1][r][n][g] + bv);
          outb[((size_t)(yout+1)*PDIM + px+1)*64 + oL] = f2b(v);
        }
      } else {
        int o = ntB*16 + oL;
        if (o < Cout){
          float bv = bias[o];
          #pragma unroll
          for (int g = 0; g < 4; ++g){
            int px = xs + px0 + g;
            outf[(size_t)o*HWF + (size_t)yout*IMW + px] = acc[0][r][n][g] + bv;
          }
        }
      }
    }
  }
}

// ---------- no-LDS MFMA implicit-GEMM (U-Net smalls); blockIdx.y = o-group of NT ----------
template<int NT, int KC, int STRIDE, int OMODE, int ACT, int SWZ>
__global__ __launch_bounds__(256) void gconv3(
    const u16t* __restrict__ A0, const u16t* __restrict__ Bp, const float* __restrict__ bias,
    float* __restrict__ outf, u16t* __restrict__ outb,
    int Cout, int Wout, int strips, int blocksPerImg,
    int pitchIn, int csIn, int coIn, size_t aImgStride,
    size_t outImgStride, int pitchOut, int csOut, int coOut,
    int KCtot, int NTtot)
{
  int bid = blockIdx.x;
  if (SWZ) bid = (bid & 7)*(gridDim.x >> 3) + (bid >> 3);
  const int wave = threadIdx.x >> 6;
  const int lane = threadIdx.x & 63;
  const int img = bid / blocksPerImg;
  const int sid = (bid - img*blocksPerImg)*4 + wave;
  const int y = sid / strips, xs = (sid % strips) * 16;
  const int m = lane & 15, q = lane >> 4;
  const int ntOff = blockIdx.y*NT;
  f32x4 acc[NT];
  #pragma unroll
  for (int nt = 0; nt < NT; ++nt) acc[nt] = (f32x4){0.f,0.f,0.f,0.f};

  for (int tap = 0; tap < 9; ++tap){
    int dy = tap/3, dx = tap%3;
    int row = STRIDE*y + dy;
    int col = (STRIDE == 1) ? (xs + m + dx) : (2*(xs + m) + dx);
    size_t abase = (size_t)img*aImgStride + ((size_t)row*pitchIn + col)*csIn + coIn + q*8;
    const u16t* ap0 = A0 + abase;
    const u16t* bp = Bp + ((size_t)(tap*KCtot)*NTtot + ntOff)*512 + lane*8;
    #pragma unroll
    for (int kc = 0; kc < KC; ++kc){
      short8 av0 = *(const short8*)(ap0 + kc*32);
      #pragma unroll
      for (int nt = 0; nt < NT; ++nt){
        short8 bv = *(const short8*)(bp + (size_t)(kc*NTtot + nt)*512);
        acc[nt] = __builtin_amdgcn_mfma_f32_16x16x32_bf16(av0, bv, acc[nt], 0, 0, 0);
      }
    }
  }
  const int prow0 = q*4;
  #pragma unroll
  for (int nt = 0; nt < NT; ++nt){
    int o = (ntOff + nt)*16 + m;
    if (o >= Cout) continue;
    float bv = bias[o];
    #pragma unroll
    for (int r = 0; r < 4; ++r){
      int px = xs + prow0 + r;
      if (px >= Wout) continue;
      float v = acc[nt][r] + bv;
      if (ACT) v = fmaxf(v, 0.f);
      if (OMODE == 0){
        outf[((size_t)img*Cout + o)*((size_t)Wout*Wout) + (size_t)y*Wout + px] = v;
      } else if (OMODE == 1){
        outb[(size_t)img*outImgStride + ((size_t)(y+1)*pitchOut + px+1)*csOut + coOut + o] = f2b(v);
      } else {
        outb[(size_t)img*outImgStride + ((size_t)y*pitchOut + px)*csOut + coOut + o] = f2b(v);
      }
    }
  }
}

// ---------- gating + flow-warp, channels-last bf16, XCD-banded, all 7 t per thread ----------
__global__ __launch_bounds__(256) void gate_nhwc(
    const u16t* __restrict__ fpad, const u16t* __restrict__ pred,
    const float* __restrict__ mv, u16t* __restrict__ spad)
{
  int bid = blockIdx.x;
  int xcd = bid & 7, lb = bid >> 3;
  int idx = (xcd*18 + lb)*256 + threadIdx.x;
  int y = idx/IMW, x = idx%IMW;
  size_t pc = ((size_t)(y+1)*PDIM + (x+1))*448;
  const u16t* rp = fpad + pc + 192;
  short8 r8[8];
  #pragma unroll
  for (int c8 = 0; c8 < 8; ++c8) r8[c8] = *(const short8*)(rp + c8*8);
  #pragma unroll 1
  for (int t = 0; t < 7; ++t){
    const u16t* pp = pred + ((size_t)t*HWF + idx)*64;
    u16t* sp = spad + pc + (size_t)t*64;
    const u16t* tp[4]; float tw[4];
    if (t == 0){
      tp[0] = fpad + pc; tw[0] = 1.f;
      tp[1] = tp[2] = tp[3] = fpad + pc; tw[1] = tw[2] = tw[3] = 0.f;
    } else {
      float fx = mv[(((size_t)(t-1)*HWF + idx))*2 + 0];
      float fy = mv[(((size_t)(t-1)*HWF + idx))*2 + 1];
      float ys = (float)y + fy, xsf = (float)x + fx;
      float y0f = floorf(ys), x0f = floorf(xsf);
      float wy = ys - y0f, wx = xsf - x0f;
      int y0 = (int)y0f, x0i = (int)x0f;
      int kk = 0;
      #pragma unroll
      for (int dy2 = 0; dy2 < 2; ++dy2)
        #pragma unroll
        for (int dx2 = 0; dx2 < 2; ++dx2){
          int yi = y0+dy2, xi = x0i+dx2;
          float wv = (dy2 ? wy : 1.f-wy)*(dx2 ? wx : 1.f-wx);
          bool ok = (yi >= 0 && yi <= 191 && xi >= 0 && xi <= 191);
          int yc = min(max(yi,0),191), xc = min(max(xi,0),191);
          tp[kk] = fpad + ((size_t)(yc+1)*PDIM + xc+1)*448 + (size_t)(t-1)*64;
          tw[kk] = ok ? wv : 0.f;
          ++kk;
        }
    }
    #pragma unroll
    for (int c8 = 0; c8 < 8; ++c8){
      short8 pv = *(const short8*)(pp + c8*8);
      short8 t0v = *(const short8*)(tp[0] + c8*8);
      short8 t1v = *(const short8*)(tp[1] + c8*8);
      short8 t2v = *(const short8*)(tp[2] + c8*8);
      short8 t3v = *(const short8*)(tp[3] + c8*8);
      short8 ov;
      #pragma unroll
      for (int j = 0; j < 8; ++j){
        float r = b2f((u16t)r8[c8][j]);
        float p = b2f((u16t)pv[j]);
        float a = tw[0]*b2f((u16t)t0v[j]) + tw[1]*b2f((u16t)t1v[j])
                + tw[2]*b2f((u16t)t2v[j]) + tw[3]*b2f((u16t)t3v[j]);
        float sv = a*sigmoidf(a*r) + p*sigmoidf(p*r);
        ov[j] = (short)f2b(sv);
      }
      *(short8*)(sp + c8*8) = ov;
    }
  }
}

// ---------------- convT 4x4 s2 p1 (+relu): parity-decomposed, fp32 in, bf16 NHWC out ----------------
__global__ __launch_bounds__(256) void convT_tile2(
    const float* __restrict__ in, const float* __restrict__ wp,
    const float* __restrict__ bias, u16t* __restrict__ outb,
    int Hin, int tilesX, int pitchOut, int csOut, int coOut)
{
  const int CC = 4;
  __shared__ float sIn[CC][10*11];
  __shared__ float sW[16][CC][4][4];
  const int Win = Hin;
  const int o0 = blockIdx.x*16;
  const int tile = blockIdx.y;
  const int ty0 = (tile/tilesX)*16, tx0 = (tile%tilesX)*16;
  const int tid = threadIdx.x;
  const int py = tid>>4, px = tid&15;
  const int ry = py&1, rx = px&1, par = ry*2 + rx;
  const int lr = py>>1, lc = px>>1;
  const int r0 = ty0>>1, c0 = tx0>>1;
  float acc[16] = {};
  for (int ib = 0; ib < 64; ib += CC){
    for (int i = tid; i < CC*100; i += 256){
      int c = i/100, rem = i%100, r = rem/10, col = rem%10;
      int gy = r0 - 1 + r, gx = c0 - 1 + col;
      float v = 0.f;
      if (gy >= 0 && gy < Hin && gx >= 0 && gx < Win)
        v = in[(size_t)(ib + c)*Hin*Win + gy*Win + gx];
      sIn[c][r*11 + col] = v;
    }
    for (int i = tid; i < 1024; i += 256){
      int ol = i >> 6, rem = i & 63, ci = rem >> 4, p2 = (rem >> 2) & 3, j = rem & 3;
      sW[ol][ci][p2][j] = wp[((size_t)((p2*64 + o0 + ol)*64) + ib + ci)*4 + j];
    }
    __syncthreads();
    #pragma unroll
    for (int ci = 0; ci < CC; ++ci){
      int rb = lr + ry, cb = lc + rx;
      float t00 = sIn[ci][rb*11 + cb],     t01 = sIn[ci][rb*11 + cb + 1];
      float t10 = sIn[ci][(rb+1)*11 + cb], t11 = sIn[ci][(rb+1)*11 + cb + 1];
      #pragma unroll
      for (int ol = 0; ol < 16; ++ol){
        const float* wv = &sW[ol][ci][par][0];
        acc[ol] += t00*wv[0] + t01*wv[1] + t10*wv[2] + t11*wv[3];
      }
    }
    __syncthreads();
  }
  int gy = ty0 + py, gx = tx0 + px;
  u16t* op = outb + ((size_t)(gy+1)*pitchOut + gx+1)*csOut + coOut + o0;
  short8 pa, pb;
  #pragma unroll
  for (int i = 0; i < 8; ++i) pa[i] = (short)f2b(fmaxf(acc[i] + bias[o0+i], 0.f));
  #pragma unroll
  for (int i = 0; i < 8; ++i) pb[i] = (short)f2b(fmaxf(acc[8+i] + bias[o0+8+i], 0.f));
  *(short8*)op = pa;
  *(short8*)(op + 8) = pb;
}

// ---------------- deformable conv ----------------
__global__ __launch_bounds__(256) void deform_sample_k(
    const float* __restrict__ lqs, const float* __restrict__ om,
    float* __restrict__ vbuf)
{
  int idx = blockIdx.x*256 + threadIdx.x;
  int g = blockIdx.y;
  int h = idx / IMW, x = idx % IMW;
  const float* img = lqs + (size_t)g*HWF;
  #pragma unroll
  for (int k = 0; k < 9; ++k){
    int j = g*9 + k;
    float offy = om[(size_t)(j*2 + 0)*HWF + idx];
    float offx = om[(size_t)(j*2 + 1)*HWF + idx];
    float m = sigmoidf(om[(size_t)(126 + j)*HWF + idx]);
    float ys = (float)(h + (k/3) - 1) + offy;
    float xs = (float)(x + (k%3) - 1) + offx;
    vbuf[(size_t)j*HWF + idx] = bilin(img, ys, xs, IMH, IMW) * m;
  }
}

__global__ __launch_bounds__(256) void deform_out_k(
    const float* __restrict__ vbuf, const float* __restrict__ dcw,
    const float* __restrict__ dcb, float* __restrict__ out)
{
  __shared__ float sw[16*63];
  int idx = blockIdx.x*256 + threadIdx.x;
  int o0 = blockIdx.y*16;
  for (int i = threadIdx.x; i < 16*63; i += 256)
    sw[i] = dcw[(size_t)o0*63 + i];
  __syncthreads();
  float v[63];
  #pragma unroll
  for (int j = 0; j < 63; ++j) v[j] = vbuf[(size_t)j*HWF + idx];
  for (int ol = 0; ol < 16; ++ol){
    float acc = dcb[o0 + ol];
    #pragma unroll
    for (int j = 0; j < 63; ++j) acc += v[j]*sw[ol*63 + j];
    out[(size_t)(o0 + ol)*HWF + idx] = fmaxf(acc, 0.f);
  }
}

extern "C" void kernel_launch(void* const* d_in, const int* in_sizes, int n_in,
                              void* d_out, int out_size, void* d_ws, size_t ws_size,
                              hipStream_t stream)
{
  const float* lqs   = (const float*)d_in[0];
  const float* preds = (const float*)d_in[1];
  const float* mv    = (const float*)d_in[2];
  const float* bw1   = (const float*)d_in[3];
  const float* bb1   = (const float*)d_in[4];
  const float* bw2   = (const float*)d_in[5];
  const float* bb2   = (const float*)d_in[6];
  const float* dn1w  = (const float*)d_in[7];
  const float* dn1b  = (const float*)d_in[8];
  const float* dn2w  = (const float*)d_in[9];
  const float* dn2b  = (const float*)d_in[10];
  const float* up1cw = (const float*)d_in[11];
  const float* up1cb = (const float*)d_in[12];
  const float* up1tw = (const float*)d_in[13];
  const float* up1tb = (const float*)d_in[14];
  const float* up2cw = (const float*)d_in[15];
  const float* up2cb = (const float*)d_in[16];
  const float* up2tw = (const float*)d_in[17];
  const float* up2tb = (const float*)d_in[18];
  const float* trcw  = (const float*)d_in[19];
  const float* trcb  = (const float*)d_in[20];
  const float* trtw  = (const float*)d_in[21];
  const float* trtb  = (const float*)d_in[22];
  const float* ffw   = (const float*)d_in[23];
  const float* ffb   = (const float*)d_in[24];
  const float* omw   = (const float*)d_in[25];
  const float* omb   = (const float*)d_in[26];
  const float* dcw   = (const float*)d_in[27];
  const float* dcb   = (const float*)d_in[28];
  float* outp = (float*)d_out;

  char* p = (char*)d_ws;
  const size_t PIMG64 = (size_t)PDIM*PDIM*64;
  u16t* spadreg  = (u16t*)p; p += 14*PIMG64*2;                // spad [194][194][448]; later featfpad
  u16t* fpad     = (u16t*)p; p += (size_t)PDIM*PDIM*448*2;    // feat NHWC448; later vbuf (fp32)
  u16t* prednhwc = (u16t*)p; p += (size_t)7*HWF*64*2;         // pred NHWC64; later om (fp32)
  u16t* out0pad  = (u16t*)p; p += (size_t)PDIM*PDIM*64*2;
  u16t* cat1pad  = (u16t*)p; p += (size_t)98*98*128*2;
  u16t* cat2pad  = (u16t*)p; p += (size_t)50*50*128*2;
  float* t0      = (float*)p; p += (size_t)24*24*64*4;
  float* u2      = (float*)p; p += (size_t)48*48*64*4;
  float* u1      = (float*)p; p += (size_t)96*96*64*4;
  u16t* ffwpack  = (u16t*)p; p += 258048*2;
  u16t* c2pack   = (u16t*)p; p += 36864*2;
  u16t* ompack   = (u16t*)p; p += 110592*2;
  u16t* dn1pack  = (u16t*)p; p += 36864*2;
  u16t* dn2pack  = (u16t*)p; p += 36864*2;
  u16t* trcpack  = (u16t*)p; p += 36864*2;
  u16t* up2cpack = (u16t*)p; p += 73728*2;
  u16t* up1cpack = (u16t*)p; p += 73728*2;
  u16t* w1pack   = (u16t*)p; p += 2048*2;
  float* wp0     = (float*)p; p += 65536*4;
  float* wp1     = (float*)p; p += 65536*4;
  float* wp2     = (float*)p; p += 65536*4;

  u16t* spad = spadreg;
  u16t* featfpad = spadreg;
  float* om = (float*)prednhwc;
  float* vbuf = (float*)fpad;

  dim3 blk(256);
  // setup
  PkD8 pk = {{ {ffw, ffwpack, 448, 64, 4, 258048}, {bw2, c2pack, 64, 64, 4, 36864},
               {omw, ompack, 64, 189, 12, 110592}, {dn1w, dn1pack, 64, 64, 4, 36864},
               {dn2w, dn2pack, 64, 64, 4, 36864},  {trcw, trcpack, 64, 64, 4, 36864},
               {up2cw, up2cpack, 128, 64, 4, 73728}, {up1cw, up1cpack, 128, 64, 4, 73728} }};
  pack_all<<<dim3(1008,8), blk, 0, stream>>>(pk);
  pack_w1<<<dim3(8), blk, 0, stream>>>(bw1, w1pack);
  RpD3 rp3 = {{ {trtw, wp0}, {up2tw, wp1}, {up1tw, wp2} }};
  repack_all<<<dim3(64,3), blk, 0, stream>>>(rp3);
  PzD5 pz = {{ {spad, 448, PDIM, 1, 0}, {fpad, 448, PDIM, 1, 0},
               {out0pad, 64, PDIM, 1, 0}, {cat1pad, 128, 98, 1, 0}, {cat2pad, 128, 50, 1, 0} }};
  padzero_all<<<dim3(2704,5), blk, 0, stream>>>(pz);
  // fused backbone (conv1 MFMA + conv2 MFMA, no HBM intermediate)
  bbfused<<<dim3(8064), blk, 0, stream>>>(lqs, preds, w1pack, bb1, c2pack, bb2, fpad, prednhwc);
  // gate (+warp) -> spad
  gate_nhwc<<<dim3(144), blk, 0, stream>>>(fpad, prednhwc, mv, spad);
  // fused dual conv -> out0pad
  cgemm<2,14,4,4,1><<<dim3(576,1), blk, 0, stream>>>(spad, fpad, ffwpack, ffb,
      nullptr, out0pad, nullptr, 64, 576, PDIM, 448, 0, 14);
  // U-Net (NT=1 o-splits for occupancy)
  gconv3<1,2,2,1,1,1><<<dim3(144,4), blk, 0, stream>>>(out0pad, dn1pack, dn1b, nullptr, cat1pad,
      64, 96, 6, 144, PDIM, 64, 0, 0, 0, 98, 128, 64, 2, 4);       // out1 -> cat1[64:]
  gconv3<1,2,2,1,1,0><<<dim3(36,4), blk, 0, stream>>>(cat1pad, dn2pack, dn2b, nullptr, cat2pad,
      64, 48, 3, 36, 98, 128, 64, 0, 0, 50, 128, 64, 2, 4);        // out2 -> cat2[64:]
  gconv3<1,2,2,0,1,0><<<dim3(12,4), blk, 0, stream>>>(cat2pad, trcpack, trcb, t0, nullptr,
      64, 24, 2, 12, 50, 128, 64, 0, 0, 0, 0, 0, 2, 4);            // t0 (fp32 NCHW)
  convT_tile2<<<dim3(4,9), blk, 0, stream>>>(t0, wp0, trtb, cat2pad, 24, 3, 50, 128, 0);   // t1 -> cat2[:64]
  gconv3<1,4,1,0,1,0><<<dim3(36,4), blk, 0, stream>>>(cat2pad, up2cpack, up2cb, u2, nullptr,
      64, 48, 3, 36, 50, 128, 0, 0, 0, 0, 0, 0, 4, 4);             // u2 (fp32 NCHW)
  convT_tile2<<<dim3(4,36), blk, 0, stream>>>(u2, wp1, up2tb, cat1pad, 48, 6, 98, 128, 0); // u2t -> cat1[:64]
  gconv3<1,4,1,0,1,1><<<dim3(144,4), blk, 0, stream>>>(cat1pad, up1cpack, up1cb, u1, nullptr,
      64, 96, 6, 144, 98, 128, 0, 0, 0, 0, 0, 0, 4, 4);            // u1 (fp32 NCHW)
  // final convT -> featfpad
  padzero2<<<dim3(194), blk, 0, stream>>>(featfpad, 64, PDIM);
  convT_tile2<<<dim3(4,144), blk, 0, stream>>>(u1, wp2, up1tb, featfpad, 96, 12, PDIM, 64, 0);
  // offsets/masks conv (64 -> 189)
  cgemm<1,2,5,12,1><<<dim3(576,3), blk, 0, stream>>>(featfpad, nullptr, ompack, omb,
      om, nullptr, nullptr, 189, 576, PDIM, 64, 0, 2);
  // deformable conv
  deform_sample_k<<<dim3(144,7), blk, 0, stream>>>(lqs, om, vbuf);
  deform_out_k<<<dim3(144,4), blk, 0, stream>>>(vbuf, dcw, dcb, outp);
}

// Round 10
// 614.608 us; speedup vs baseline: 1.0296x; 1.0296x over previous
//
#include <hip/hip_runtime.h>
#include <math.h>

#define IMH 192
#define IMW 192
#define HWF 36864
#define PDIM 194

typedef unsigned short u16t;
typedef __attribute__((ext_vector_type(8))) short short8;
typedef __attribute__((ext_vector_type(4))) float f32x4;

__device__ __forceinline__ float sigmoidf(float x){ return 1.f/(1.f+expf(-x)); }
__device__ __forceinline__ float lrelu(float x){ return x > 0.f ? x : 0.1f*x; }
__device__ __forceinline__ float b2f(u16t h){ unsigned u = ((unsigned)h)<<16; return __uint_as_float(u); }
__device__ __forceinline__ u16t f2b(float f){
  unsigned u = __float_as_uint(f);
  u += 0x7FFFu + ((u>>16)&1u);
  return (u16t)(u>>16);
}

__device__ __forceinline__ float bilin(const float* __restrict__ img, float ys, float xs, int H, int W){
  float y0f = floorf(ys), x0f = floorf(xs);
  float wy = ys - y0f, wx = xs - x0f;
  int y0 = (int)y0f, x0 = (int)x0f;
  float acc = 0.f;
  #pragma unroll
  for (int dy=0; dy<2; ++dy){
    int yi = y0+dy;
    float wyv = dy ? wy : 1.f-wy;
    if (yi < 0 || yi >= H) continue;
    #pragma unroll
    for (int dx=0; dx<2; ++dx){
      int xi = x0+dx;
      float wxv = dx ? wx : 1.f-wx;
      if (xi < 0 || xi >= W) continue;
      acc += img[yi*W+xi]*(wyv*wxv);
    }
  }
  return acc;
}

// ================= descriptor-driven setup kernels =================
struct PkD { const float* w; u16t* dst; int Cin, Cout, NT, total; };
struct PkD8 { PkD d[8]; };
__global__ __launch_bounds__(256) void pack_all(PkD8 ds){
  PkD d = ds.d[blockIdx.y];
  int id = blockIdx.x*256 + threadIdx.x;
  if (id >= d.total) return;
  int j = id & 7, l = (id>>3) & 63;
  int r = id >> 9;
  int nt = r % d.NT; r /= d.NT;
  int KC = d.Cin >> 5;
  int kc = r % KC; int tap = r / KC;
  int c = kc*32 + ((l>>4)<<3) + j;
  int o = nt*16 + (l&15);
  float v = (o < d.Cout) ? d.w[((size_t)o*d.Cin + c)*9 + tap] : 0.f;
  d.dst[id] = f2b(v);
}

struct RpD { const float* w; float* wp; };
struct RpD3 { RpD d[3]; };
__global__ __launch_bounds__(256) void repack_all(RpD3 ds){
  RpD d = ds.d[blockIdx.y];
  int id = blockIdx.x*256 + threadIdx.x;
  int par = id >> 12, o = (id >> 6) & 63, i = id & 63;
  int ry = par >> 1, rx = par & 1;
  #pragma unroll
  for (int jy = 0; jy < 2; ++jy)
    #pragma unroll
    for (int jx = 0; jx < 2; ++jx){
      int ka = 3 - ry - 2*jy, kb = 3 - rx - 2*jx;
      d.wp[((size_t)((par*64 + o)*64 + i))*4 + jy*2 + jx] = d.w[((size_t)(i*64 + o))*16 + ka*4 + kb];
    }
}

struct PzD { u16t* buf; int C, dim, nimg; size_t stride; };
struct PzD5 { PzD d[5]; };
__global__ __launch_bounds__(256) void padzero_all(PzD5 ds){
  PzD d = ds.d[blockIdx.y];
  int per = (4*d.dim - 4)*d.C;
  long total = (long)per*d.nimg;
  for (long id = (long)blockIdx.x*256 + threadIdx.x; id < total; id += (long)gridDim.x*256){
    int n = (int)(id / per), c2 = (int)(id % per);
    int cell = c2 / d.C, c = c2 % d.C;
    int d2 = d.dim - 1;
    int r, col;
    if (cell < d.dim){ r = 0; col = cell; }
    else if (cell < 2*d.dim){ r = d2; col = cell - d.dim; }
    else if (cell < 3*d.dim - 2){ r = cell - 2*d.dim + 1; col = 0; }
    else { r = cell - (3*d.dim - 2) + 1; col = d2; }
    d.buf[(size_t)n*d.stride + ((size_t)r*d.dim + col)*d.C + c] = 0;
  }
}

__global__ __launch_bounds__(256) void padzero2(u16t* buf, int C, int dim){
  int total = (4*dim - 4)*C;
  for (int id = blockIdx.x*256 + threadIdx.x; id < total; id += gridDim.x*256){
    int cell = id / C, c = id % C;
    int d2 = dim - 1;
    int r, col;
    if (cell < dim){ r = 0; col = cell; }
    else if (cell < 2*dim){ r = d2; col = cell - dim; }
    else if (cell < 3*dim - 2){ r = cell - 2*dim + 1; col = 0; }
    else { r = cell - (3*dim - 2) + 1; col = d2; }
    buf[((size_t)r*dim + col)*C + c] = 0;
  }
}

// ========== fused backbone: conv1 (1->64, fp32 FMA, lane=channel) + conv2 (64->64, MFMA) ==========
// Block = 4-row x 16-px x 64-ch conv2-output tile. Stage 8x20 raw fp32 input in LDS;
// conv1: lane o holds its 9 weights in VGPRs, wave walks 27 wave-uniform pixels with
// broadcast taps + 3-tap row-sliding reuse -> swizzled sA (stride 64, slot=(g+px)&7);
// conv2 MFMA from sA. img<7 -> fpad NHWC448 padded, else prednhwc tight.
__global__ __launch_bounds__(256) void bbfused(
    const float* __restrict__ lqs, const float* __restrict__ preds,
    const float* __restrict__ w1, const float* __restrict__ b1,
    const u16t* __restrict__ Bp, const float* __restrict__ b2,
    u16t* __restrict__ fpad, u16t* __restrict__ prednhwc)
{
  __shared__ float sIn1[8][20];
  __shared__ u16t sA[108*64];
  int bid = blockIdx.x;
  bid = (bid & 7)*(gridDim.x >> 3) + (bid >> 3);       // XCD banding
  const int tid = threadIdx.x;
  const int img = bid / 576;
  const int rem = bid - img*576;
  const int y0 = (rem/12)*4, xs = (rem%12)*16;
  const float* ip = (img < 7) ? (lqs + (size_t)img*HWF) : (preds + (size_t)(img-7)*HWF);
  for (int u = tid; u < 160; u += 256){
    int lr = u/20, lc = u%20;
    int iy = y0 - 2 + lr, ix = xs - 2 + lc;
    sIn1[lr][lc] = (iy >= 0 && iy < IMH && ix >= 0 && ix < IMW) ? ip[iy*IMW + ix] : 0.f;
  }
  const int wave = tid >> 6, lane = tid & 63;
  // conv1 weights+bias into registers (lane = output channel)
  float wr[9];
  #pragma unroll
  for (int k = 0; k < 9; ++k) wr[k] = w1[lane*9 + k];
  float b1v = b1[lane];
  const int gsw = lane >> 3, ol = lane & 7;
  __syncthreads();
  // ---- conv1: wave-uniform pixel loop, broadcast taps, row-sliding reuse ----
  {
    float t[9];
    #pragma unroll 1
    for (int i = 0; i < 27; ++i){
      int px = wave*27 + i;
      int rr = px/18, cc = px%18;
      if (i == 0 || cc == 0){
        #pragma unroll
        for (int dy = 0; dy < 3; ++dy)
          #pragma unroll
          for (int dx = 0; dx < 3; ++dx) t[dy*3+dx] = sIn1[rr+dy][cc+dx];
      } else {
        #pragma unroll
        for (int dy = 0; dy < 3; ++dy){
          t[dy*3] = t[dy*3+1]; t[dy*3+1] = t[dy*3+2];
          t[dy*3+2] = sIn1[rr+dy][cc+2];
        }
      }
      float acc = b1v;
      #pragma unroll
      for (int k = 0; k < 9; ++k) acc += t[k]*wr[k];
      int pr = y0 + rr, pc = xs + cc;
      bool border = (pr == 0) | (pr == 193) | (pc == 0) | (pc == 193);
      sA[(size_t)px*64 + ((gsw + px)&7)*8 + ol] = border ? (u16t)0 : f2b(acc);
    }
  }
  __syncthreads();
  // ---- conv2 MFMA from sA ----
  const int m = lane & 15, q = lane >> 4;
  const int rp = wave >> 1, np = wave & 1;
  f32x4 acc[2][2];
  #pragma unroll
  for (int r = 0; r < 2; ++r)
    #pragma unroll
    for (int n = 0; n < 2; ++n) acc[r][n] = (f32x4){0.f,0.f,0.f,0.f};
  #pragma unroll
  for (int kc = 0; kc < 2; ++kc){
    #pragma unroll
    for (int tap = 0; tap < 9; ++tap){
      const int dy = tap/3, dx = tap%3;
      short8 af[2];
      #pragma unroll
      for (int r = 0; r < 2; ++r){
        int px = (2*rp + r + dy)*18 + dx + m;
        af[r] = *(const short8*)&sA[(size_t)px*64 + ((kc*4 + q + px)&7)*8];
      }
      const u16t* bp = Bp + ((size_t)(tap*2 + kc)*4 + np*2)*512 + lane*8;
      short8 b0 = *(const short8*)bp;
      short8 b1w = *(const short8*)(bp + 512);
      #pragma unroll
      for (int r = 0; r < 2; ++r){
        acc[r][0] = __builtin_amdgcn_mfma_f32_16x16x32_bf16(af[r], b0, acc[r][0], 0, 0, 0);
        acc[r][1] = __builtin_amdgcn_mfma_f32_16x16x32_bf16(af[r], b1w, acc[r][1], 0, 0, 0);
      }
    }
  }
  const int px0 = q*4;
  #pragma unroll
  for (int r = 0; r < 2; ++r){
    int yout = y0 + 2*rp + r;
    #pragma unroll
    for (int n = 0; n < 2; ++n){
      int oL = (np*2 + n)*16 + m;
      float bv = b2[oL];
      #pragma unroll
      for (int g = 0; g < 4; ++g){
        int px = xs + px0 + g;
        float v = acc[r][n][g] + bv;
        if (img < 7)
          fpad[((size_t)(yout+1)*PDIM + px+1)*448 + (size_t)img*64 + oL] = f2b(v);
        else
          prednhwc[(size_t)(img-7)*((size_t)HWF*64) + ((size_t)yout*IMW + px)*64 + oL] = f2b(v);
      }
    }
  }
}

// ========== LDS-staged MFMA implicit-GEMM 3x3 stride-1 conv (swizzled sA, stride 32) ==========
// OMODE 4: fuse epilogue 0.1*lrelu(s)+lrelu(f) -> out0pad; OMODE 5: fp32 NCHW, blockIdx.y=o-block
template<int STREAMS, int KC, int OMODE, int NTT, int SWZ>
__global__ __launch_bounds__(256) void cgemm(
    const u16t* __restrict__ A0, const u16t* __restrict__ A1,
    const u16t* __restrict__ Bp, const float* __restrict__ bias,
    float* __restrict__ outf, u16t* __restrict__ outb, u16t* __restrict__ outb2,
    int Cout, int blocksPerImg, int pitchIn, int csIn, size_t aImgStride, int KCtot)
{
  __shared__ u16t sA[STREAMS*108*32];
  int bid = blockIdx.x;
  if (SWZ) bid = (bid & 7)*(gridDim.x >> 3) + (bid >> 3);
  const int tid = threadIdx.x;
  const int wave = tid >> 6, lane = tid & 63;
  const int m = lane & 15, q = lane >> 4;
  const int img = bid / blocksPerImg;
  const int rem = bid - img*blocksPerImg;
  const int y0 = (rem/12)*4, xs = (rem%12)*16;
  const int rp = wave >> 1, np = wave & 1;
  const int ntB = (OMODE == 5) ? blockIdx.y*4 : 0;
  f32x4 acc[STREAMS][2][2];
  #pragma unroll
  for (int s = 0; s < STREAMS; ++s)
    #pragma unroll
    for (int r = 0; r < 2; ++r)
      #pragma unroll
      for (int n = 0; n < 2; ++n) acc[s][r][n] = (f32x4){0.f,0.f,0.f,0.f};

  #pragma unroll 1
  for (int kc = 0; kc < KC; ++kc){
    if (kc) __syncthreads();
    for (int u = tid; u < STREAMS*216; u += 256){
      int st = u/216, r2 = u%216, p = r2>>1, h = r2&1;
      int rr = p/18, cc = p%18;
      size_t ga = (size_t)img*aImgStride + ((size_t)(y0+rr)*pitchIn + xs+cc)*csIn + kc*32 + h*16;
      const u16t* gp = ((STREAMS==2 && st==1) ? A1 : A0) + ga;
      short8 v0 = *(const short8*)gp;
      short8 v1 = *(const short8*)(gp + 8);
      u16t* base = &sA[((size_t)(st*108 + p))*32];
      *(short8*)(base + ((2*h + p)&3)*8) = v0;
      *(short8*)(base + ((2*h + 1 + p)&3)*8) = v1;
    }
    __syncthreads();
    #pragma unroll
    for (int tap = 0; tap < 9; ++tap){
      const int dy = tap/3, dx = tap%3;
      short8 af[STREAMS][2];
      #pragma unroll
      for (int st = 0; st < STREAMS; ++st)
        #pragma unroll
        for (int r = 0; r < 2; ++r){
          int px = (2*rp + r + dy)*18 + dx + m;
          af[st][r] = *(const short8*)&sA[((size_t)(st*108 + px))*32 + ((q + px)&3)*8];
        }
      const u16t* bp = Bp + ((size_t)(tap*KCtot + kc)*NTT + ntB + np*2)*512 + lane*8;
      short8 b0 = *(const short8*)bp;
      short8 b1 = *(const short8*)(bp + 512);
      #pragma unroll
      for (int st = 0; st < STREAMS; ++st)
        #pragma unroll
        for (int r = 0; r < 2; ++r){
          acc[st][r][0] = __builtin_amdgcn_mfma_f32_16x16x32_bf16(af[st][r], b0, acc[st][r][0], 0, 0, 0);
          acc[st][r][1] = __builtin_amdgcn_mfma_f32_16x16x32_bf16(af[st][r], b1, acc[st][r][1], 0, 0, 0);
        }
    }
  }
  const int px0 = q*4;
  #pragma unroll
  for (int r = 0; r < 2; ++r){
    int yout = y0 + 2*rp + r;
    #pragma unroll
    for (int n = 0; n < 2; ++n){
      int oL = (np*2 + n)*16 + m;
      if (OMODE == 4){
        float bv = bias[oL];
        #pragma unroll
        for (int g = 0; g < 4; ++g){
          int px = xs + px0 + g;
          float v = 0.1f*lrelu(acc[0][r][n][g] + bv) + lrelu(acc[1][r][n][g] + bv);
          outb[((size_t)(yout+1)*PDIM + px+1)*64 + oL] = f2b(v);
        }
      } else {
        int o = ntB*16 + oL;
        if (o < Cout){
          float bv = bias[o];
          #pragma unroll
          for (int g = 0; g < 4; ++g){
            int px = xs + px0 + g;
            outf[(size_t)o*HWF + (size_t)yout*IMW + px] = acc[0][r][n][g] + bv;
          }
        }
      }
    }
  }
}

// ---------- no-LDS MFMA implicit-GEMM (U-Net smalls); blockIdx.y = o-group of NT ----------
template<int NT, int KC, int STRIDE, int OMODE, int ACT, int SWZ>
__global__ __launch_bounds__(256) void gconv3(
    const u16t* __restrict__ A0, const u16t* __restrict__ Bp, const float* __restrict__ bias,
    float* __restrict__ outf, u16t* __restrict__ outb,
    int Cout, int Wout, int strips, int blocksPerImg,
    int pitchIn, int csIn, int coIn, size_t aImgStride,
    size_t outImgStride, int pitchOut, int csOut, int coOut,
    int KCtot, int NTtot)
{
  int bid = blockIdx.x;
  if (SWZ) bid = (bid & 7)*(gridDim.x >> 3) + (bid >> 3);
  const int wave = threadIdx.x >> 6;
  const int lane = threadIdx.x & 63;
  const int img = bid / blocksPerImg;
  const int sid = (bid - img*blocksPerImg)*4 + wave;
  const int y = sid / strips, xs = (sid % strips) * 16;
  const int m = lane & 15, q = lane >> 4;
  const int ntOff = blockIdx.y*NT;
  f32x4 acc[NT];
  #pragma unroll
  for (int nt = 0; nt < NT; ++nt) acc[nt] = (f32x4){0.f,0.f,0.f,0.f};

  for (int tap = 0; tap < 9; ++tap){
    int dy = tap/3, dx = tap%3;
    int row = STRIDE*y + dy;
    int col = (STRIDE == 1) ? (xs + m + dx) : (2*(xs + m) + dx);
    size_t abase = (size_t)img*aImgStride + ((size_t)row*pitchIn + col)*csIn + coIn + q*8;
    const u16t* ap0 = A0 + abase;
    const u16t* bp = Bp + ((size_t)(tap*KCtot)*NTtot + ntOff)*512 + lane*8;
    #pragma unroll
    for (int kc = 0; kc < KC; ++kc){
      short8 av0 = *(const short8*)(ap0 + kc*32);
      #pragma unroll
      for (int nt = 0; nt < NT; ++nt){
        short8 bv = *(const short8*)(bp + (size_t)(kc*NTtot + nt)*512);
        acc[nt] = __builtin_amdgcn_mfma_f32_16x16x32_bf16(av0, bv, acc[nt], 0, 0, 0);
      }
    }
  }
  const int prow0 = q*4;
  #pragma unroll
  for (int nt = 0; nt < NT; ++nt){
    int o = (ntOff + nt)*16 + m;
    if (o >= Cout) continue;
    float bv = bias[o];
    #pragma unroll
    for (int r = 0; r < 4; ++r){
      int px = xs + prow0 + r;
      if (px >= Wout) continue;
      float v = acc[nt][r] + bv;
      if (ACT) v = fmaxf(v, 0.f);
      if (OMODE == 0){
        outf[((size_t)img*Cout + o)*((size_t)Wout*Wout) + (size_t)y*Wout + px] = v;
      } else if (OMODE == 1){
        outb[(size_t)img*outImgStride + ((size_t)(y+1)*pitchOut + px+1)*csOut + coOut + o] = f2b(v);
      } else {
        outb[(size_t)img*outImgStride + ((size_t)y*pitchOut + px)*csOut + coOut + o] = f2b(v);
      }
    }
  }
}

// ---------- gating + flow-warp, channels-last bf16, XCD-banded, all 7 t per thread ----------
__global__ __launch_bounds__(256) void gate_nhwc(
    const u16t* __restrict__ fpad, const u16t* __restrict__ pred,
    const float* __restrict__ mv, u16t* __restrict__ spad)
{
  int bid = blockIdx.x;
  int xcd = bid & 7, lb = bid >> 3;
  int idx = (xcd*18 + lb)*256 + threadIdx.x;
  int y = idx/IMW, x = idx%IMW;
  size_t pc = ((size_t)(y+1)*PDIM + (x+1))*448;
  const u16t* rp = fpad + pc + 192;
  short8 r8[8];
  #pragma unroll
  for (int c8 = 0; c8 < 8; ++c8) r8[c8] = *(const short8*)(rp + c8*8);
  #pragma unroll 1
  for (int t = 0; t < 7; ++t){
    const u16t* pp = pred + ((size_t)t*HWF + idx)*64;
    u16t* sp = spad + pc + (size_t)t*64;
    const u16t* tp[4]; float tw[4];
    if (t == 0){
      tp[0] = fpad + pc; tw[0] = 1.f;
      tp[1] = tp[2] = tp[3] = fpad + pc; tw[1] = tw[2] = tw[3] = 0.f;
    } else {
      float fx = mv[(((size_t)(t-1)*HWF + idx))*2 + 0];
      float fy = mv[(((size_t)(t-1)*HWF + idx))*2 + 1];
      float ys = (float)y + fy, xsf = (float)x + fx;
      float y0f = floorf(ys), x0f = floorf(xsf);
      float wy = ys - y0f, wx = xsf - x0f;
      int y0 = (int)y0f, x0i = (int)x0f;
      int kk = 0;
      #pragma unroll
      for (int dy2 = 0; dy2 < 2; ++dy2)
        #pragma unroll
        for (int dx2 = 0; dx2 < 2; ++dx2){
          int yi = y0+dy2, xi = x0i+dx2;
          float wv = (dy2 ? wy : 1.f-wy)*(dx2 ? wx : 1.f-wx);
          bool ok = (yi >= 0 && yi <= 191 && xi >= 0 && xi <= 191);
          int yc = min(max(yi,0),191), xc = min(max(xi,0),191);
          tp[kk] = fpad + ((size_t)(yc+1)*PDIM + xc+1)*448 + (size_t)(t-1)*64;
          tw[kk] = ok ? wv : 0.f;
          ++kk;
        }
    }
    #pragma unroll
    for (int c8 = 0; c8 < 8; ++c8){
      short8 pv = *(const short8*)(pp + c8*8);
      short8 t0v = *(const short8*)(tp[0] + c8*8);
      short8 t1v = *(const short8*)(tp[1] + c8*8);
      short8 t2v = *(const short8*)(tp[2] + c8*8);
      short8 t3v = *(const short8*)(tp[3] + c8*8);
      short8 ov;
      #pragma unroll
      for (int j = 0; j < 8; ++j){
        float r = b2f((u16t)r8[c8][j]);
        float p = b2f((u16t)pv[j]);
        float a = tw[0]*b2f((u16t)t0v[j]) + tw[1]*b2f((u16t)t1v[j])
                + tw[2]*b2f((u16t)t2v[j]) + tw[3]*b2f((u16t)t3v[j]);
        float sv = a*sigmoidf(a*r) + p*sigmoidf(p*r);
        ov[j] = (short)f2b(sv);
      }
      *(short8*)(sp + c8*8) = ov;
    }
  }
}

// ---------------- convT 4x4 s2 p1 (+relu): parity-decomposed, fp32 in, bf16 NHWC out ----------------
__global__ __launch_bounds__(256) void convT_tile2(
    const float* __restrict__ in, const float* __restrict__ wp,
    const float* __restrict__ bias, u16t* __restrict__ outb,
    int Hin, int tilesX, int pitchOut, int csOut, int coOut)
{
  const int CC = 4;
  __shared__ float sIn[CC][10*11];
  __shared__ float sW[16][CC][4][4];
  const int Win = Hin;
  const int o0 = blockIdx.x*16;
  const int tile = blockIdx.y;
  const int ty0 = (tile/tilesX)*16, tx0 = (tile%tilesX)*16;
  const int tid = threadIdx.x;
  const int py = tid>>4, px = tid&15;
  const int ry = py&1, rx = px&1, par = ry*2 + rx;
  const int lr = py>>1, lc = px>>1;
  const int r0 = ty0>>1, c0 = tx0>>1;
  float acc[16] = {};
  for (int ib = 0; ib < 64; ib += CC){
    for (int i = tid; i < CC*100; i += 256){
      int c = i/100, rem = i%100, r = rem/10, col = rem%10;
      int gy = r0 - 1 + r, gx = c0 - 1 + col;
      float v = 0.f;
      if (gy >= 0 && gy < Hin && gx >= 0 && gx < Win)
        v = in[(size_t)(ib + c)*Hin*Win + gy*Win + gx];
      sIn[c][r*11 + col] = v;
    }
    for (int i = tid; i < 1024; i += 256){
      int ol = i >> 6, rem = i & 63, ci = rem >> 4, p2 = (rem >> 2) & 3, j = rem & 3;
      sW[ol][ci][p2][j] = wp[((size_t)((p2*64 + o0 + ol)*64) + ib + ci)*4 + j];
    }
    __syncthreads();
    #pragma unroll
    for (int ci = 0; ci < CC; ++ci){
      int rb = lr + ry, cb = lc + rx;
      float t00 = sIn[ci][rb*11 + cb],     t01 = sIn[ci][rb*11 + cb + 1];
      float t10 = sIn[ci][(rb+1)*11 + cb], t11 = sIn[ci][(rb+1)*11 + cb + 1];
      #pragma unroll
      for (int ol = 0; ol < 16; ++ol){
        const float* wv = &sW[ol][ci][par][0];
        acc[ol] += t00*wv[0] + t01*wv[1] + t10*wv[2] + t11*wv[3];
      }
    }
    __syncthreads();
  }
  int gy = ty0 + py, gx = tx0 + px;
  u16t* op = outb + ((size_t)(gy+1)*pitchOut + gx+1)*csOut + coOut + o0;
  short8 pa, pb;
  #pragma unroll
  for (int i = 0; i < 8; ++i) pa[i] = (short)f2b(fmaxf(acc[i] + bias[o0+i], 0.f));
  #pragma unroll
  for (int i = 0; i < 8; ++i) pb[i] = (short)f2b(fmaxf(acc[8+i] + bias[o0+8+i], 0.f));
  *(short8*)op = pa;
  *(short8*)(op + 8) = pb;
}

// ---------------- deformable conv ----------------
__global__ __launch_bounds__(256) void deform_sample_k(
    const float* __restrict__ lqs, const float* __restrict__ om,
    float* __restrict__ vbuf)
{
  int idx = blockIdx.x*256 + threadIdx.x;
  int g = blockIdx.y;
  int h = idx / IMW, x = idx % IMW;
  const float* img = lqs + (size_t)g*HWF;
  #pragma unroll
  for (int k = 0; k < 9; ++k){
    int j = g*9 + k;
    float offy = om[(size_t)(j*2 + 0)*HWF + idx];
    float offx = om[(size_t)(j*2 + 1)*HWF + idx];
    float m = sigmoidf(om[(size_t)(126 + j)*HWF + idx]);
    float ys = (float)(h + (k/3) - 1) + offy;
    float xs = (float)(x + (k%3) - 1) + offx;
    vbuf[(size_t)j*HWF + idx] = bilin(img, ys, xs, IMH, IMW) * m;
  }
}

__global__ __launch_bounds__(256) void deform_out_k(
    const float* __restrict__ vbuf, const float* __restrict__ dcw,
    const float* __restrict__ dcb, float* __restrict__ out)
{
  __shared__ float sw[16*63];
  int idx = blockIdx.x*256 + threadIdx.x;
  int o0 = blockIdx.y*16;
  for (int i = threadIdx.x; i < 16*63; i += 256)
    sw[i] = dcw[(size_t)o0*63 + i];
  __syncthreads();
  float v[63];
  #pragma unroll
  for (int j = 0; j < 63; ++j) v[j] = vbuf[(size_t)j*HWF + idx];
  for (int ol = 0; ol < 16; ++ol){
    float acc = dcb[o0 + ol];
    #pragma unroll
    for (int j = 0; j < 63; ++j) acc += v[j]*sw[ol*63 + j];
    out[(size_t)(o0 + ol)*HWF + idx] = fmaxf(acc, 0.f);
  }
}

extern "C" void kernel_launch(void* const* d_in, const int* in_sizes, int n_in,
                              void* d_out, int out_size, void* d_ws, size_t ws_size,
                              hipStream_t stream)
{
  const float* lqs   = (const float*)d_in[0];
  const float* preds = (const float*)d_in[1];
  const float* mv    = (const float*)d_in[2];
  const float* bw1   = (const float*)d_in[3];
  const float* bb1   = (const float*)d_in[4];
  const float* bw2   = (const float*)d_in[5];
  const float* bb2   = (const float*)d_in[6];
  const float* dn1w  = (const float*)d_in[7];
  const float* dn1b  = (const float*)d_in[8];
  const float* dn2w  = (const float*)d_in[9];
  const float* dn2b  = (const float*)d_in[10];
  const float* up1cw = (const float*)d_in[11];
  const float* up1cb = (const float*)d_in[12];
  const float* up1tw = (const float*)d_in[13];
  const float* up1tb = (const float*)d_in[14];
  const float* up2cw = (const float*)d_in[15];
  const float* up2cb = (const float*)d_in[16];
  const float* up2tw = (const float*)d_in[17];
  const float* up2tb = (const float*)d_in[18];
  const float* trcw  = (const float*)d_in[19];
  const float* trcb  = (const float*)d_in[20];
  const float* trtw  = (const float*)d_in[21];
  const float* trtb  = (const float*)d_in[22];
  const float* ffw   = (const float*)d_in[23];
  const float* ffb   = (const float*)d_in[24];
  const float* omw   = (const float*)d_in[25];
  const float* omb   = (const float*)d_in[26];
  const float* dcw   = (const float*)d_in[27];
  const float* dcb   = (const float*)d_in[28];
  float* outp = (float*)d_out;

  char* p = (char*)d_ws;
  const size_t PIMG64 = (size_t)PDIM*PDIM*64;
  u16t* spadreg  = (u16t*)p; p += 14*PIMG64*2;                // spad [194][194][448]; later featfpad
  u16t* fpad     = (u16t*)p; p += (size_t)PDIM*PDIM*448*2;    // feat NHWC448; later vbuf (fp32)
  u16t* prednhwc = (u16t*)p; p += (size_t)7*HWF*64*2;         // pred NHWC64; later om (fp32)
  u16t* out0pad  = (u16t*)p; p += (size_t)PDIM*PDIM*64*2;
  u16t* cat1pad  = (u16t*)p; p += (size_t)98*98*128*2;
  u16t* cat2pad  = (u16t*)p; p += (size_t)50*50*128*2;
  float* t0      = (float*)p; p += (size_t)24*24*64*4;
  float* u2      = (float*)p; p += (size_t)48*48*64*4;
  float* u1      = (float*)p; p += (size_t)96*96*64*4;
  u16t* ffwpack  = (u16t*)p; p += 258048*2;
  u16t* c2pack   = (u16t*)p; p += 36864*2;
  u16t* ompack   = (u16t*)p; p += 110592*2;
  u16t* dn1pack  = (u16t*)p; p += 36864*2;
  u16t* dn2pack  = (u16t*)p; p += 36864*2;
  u16t* trcpack  = (u16t*)p; p += 36864*2;
  u16t* up2cpack = (u16t*)p; p += 73728*2;
  u16t* up1cpack = (u16t*)p; p += 73728*2;
  float* wp0     = (float*)p; p += 65536*4;
  float* wp1     = (float*)p; p += 65536*4;
  float* wp2     = (float*)p; p += 65536*4;

  u16t* spad = spadreg;
  u16t* featfpad = spadreg;
  float* om = (float*)prednhwc;
  float* vbuf = (float*)fpad;

  dim3 blk(256);
  // setup
  PkD8 pk = {{ {ffw, ffwpack, 448, 64, 4, 258048}, {bw2, c2pack, 64, 64, 4, 36864},
               {omw, ompack, 64, 189, 12, 110592}, {dn1w, dn1pack, 64, 64, 4, 36864},
               {dn2w, dn2pack, 64, 64, 4, 36864},  {trcw, trcpack, 64, 64, 4, 36864},
               {up2cw, up2cpack, 128, 64, 4, 73728}, {up1cw, up1cpack, 128, 64, 4, 73728} }};
  pack_all<<<dim3(1008,8), blk, 0, stream>>>(pk);
  RpD3 rp3 = {{ {trtw, wp0}, {up2tw, wp1}, {up1tw, wp2} }};
  repack_all<<<dim3(64,3), blk, 0, stream>>>(rp3);
  PzD5 pz = {{ {spad, 448, PDIM, 1, 0}, {fpad, 448, PDIM, 1, 0},
               {out0pad, 64, PDIM, 1, 0}, {cat1pad, 128, 98, 1, 0}, {cat2pad, 128, 50, 1, 0} }};
  padzero_all<<<dim3(2704,5), blk, 0, stream>>>(pz);
  // fused backbone (conv1 fp32-FMA lane=channel + conv2 MFMA, no HBM intermediate)
  bbfused<<<dim3(8064), blk, 0, stream>>>(lqs, preds, bw1, bb1, c2pack, bb2, fpad, prednhwc);
  // gate (+warp) -> spad
  gate_nhwc<<<dim3(144), blk, 0, stream>>>(fpad, prednhwc, mv, spad);
  // fused dual conv -> out0pad
  cgemm<2,14,4,4,1><<<dim3(576,1), blk, 0, stream>>>(spad, fpad, ffwpack, ffb,
      nullptr, out0pad, nullptr, 64, 576, PDIM, 448, 0, 14);
  // U-Net (NT=1 o-splits for occupancy)
  gconv3<1,2,2,1,1,1><<<dim3(144,4), blk, 0, stream>>>(out0pad, dn1pack, dn1b, nullptr, cat1pad,
      64, 96, 6, 144, PDIM, 64, 0, 0, 0, 98, 128, 64, 2, 4);       // out1 -> cat1[64:]
  gconv3<1,2,2,1,1,0><<<dim3(36,4), blk, 0, stream>>>(cat1pad, dn2pack, dn2b, nullptr, cat2pad,
      64, 48, 3, 36, 98, 128, 64, 0, 0, 50, 128, 64, 2, 4);        // out2 -> cat2[64:]
  gconv3<1,2,2,0,1,0><<<dim3(12,4), blk, 0, stream>>>(cat2pad, trcpack, trcb, t0, nullptr,
      64, 24, 2, 12, 50, 128, 64, 0, 0, 0, 0, 0, 2, 4);            // t0 (fp32 NCHW)
  convT_tile2<<<dim3(4,9), blk, 0, stream>>>(t0, wp0, trtb, cat2pad, 24, 3, 50, 128, 0);   // t1 -> cat2[:64]
  gconv3<1,4,1,0,1,0><<<dim3(36,4), blk, 0, stream>>>(cat2pad, up2cpack, up2cb, u2, nullptr,
      64, 48, 3, 36, 50, 128, 0, 0, 0, 0, 0, 0, 4, 4);             // u2 (fp32 NCHW)
  convT_tile2<<<dim3(4,36), blk, 0, stream>>>(u2, wp1, up2tb, cat1pad, 48, 6, 98, 128, 0); // u2t -> cat1[:64]
  gconv3<1,4,1,0,1,1><<<dim3(144,4), blk, 0, stream>>>(cat1pad, up1cpack, up1cb, u1, nullptr,
      64, 96, 6, 144, 98, 128, 0, 0, 0, 0, 0, 0, 4, 4);            // u1 (fp32 NCHW)
  // final convT -> featfpad
  padzero2<<<dim3(194), blk, 0, stream>>>(featfpad, 64, PDIM);
  convT_tile2<<<dim3(4,144), blk, 0, stream>>>(u1, wp2, up1tb, featfpad, 96, 12, PDIM, 64, 0);
  // offsets/masks conv (64 -> 189)
  cgemm<1,2,5,12,1><<<dim3(576,3), blk, 0, stream>>>(featfpad, nullptr, ompack, omb,
      om, nullptr, nullptr, 189, 576, PDIM, 64, 0, 2);
  // deformable conv
  deform_sample_k<<<dim3(144,7), blk, 0, stream>>>(lqs, om, vbuf);
  deform_out_k<<<dim3(144,4), blk, 0, stream>>>(vbuf, dcw, dcb, outp);
}

// Round 11
// 588.043 us; speedup vs baseline: 1.0761x; 1.0452x over previous
//
#include <hip/hip_runtime.h>
#include <math.h>

#define IMH 192
#define IMW 192
#define HWF 36864
#define PDIM 194

typedef unsigned short u16t;
typedef __attribute__((ext_vector_type(8))) short short8;
typedef __attribute__((ext_vector_type(4))) float f32x4;

__device__ __forceinline__ float sigmoidf(float x){ return 1.f/(1.f+expf(-x)); }
__device__ __forceinline__ float lrelu(float x){ return x > 0.f ? x : 0.1f*x; }
__device__ __forceinline__ float b2f(u16t h){ unsigned u = ((unsigned)h)<<16; return __uint_as_float(u); }
__device__ __forceinline__ u16t f2b(float f){
  unsigned u = __float_as_uint(f);
  u += 0x7FFFu + ((u>>16)&1u);
  return (u16t)(u>>16);
}

__device__ __forceinline__ float bilin(const float* __restrict__ img, float ys, float xs, int H, int W){
  float y0f = floorf(ys), x0f = floorf(xs);
  float wy = ys - y0f, wx = xs - x0f;
  int y0 = (int)y0f, x0 = (int)x0f;
  float acc = 0.f;
  #pragma unroll
  for (int dy=0; dy<2; ++dy){
    int yi = y0+dy;
    float wyv = dy ? wy : 1.f-wy;
    if (yi < 0 || yi >= H) continue;
    #pragma unroll
    for (int dx=0; dx<2; ++dx){
      int xi = x0+dx;
      float wxv = dx ? wx : 1.f-wx;
      if (xi < 0 || xi >= W) continue;
      acc += img[yi*W+xi]*(wyv*wxv);
    }
  }
  return acc;
}

// ================= descriptor-driven setup kernels =================
struct PkD { const float* w; u16t* dst; int Cin, Cout, NT, total; };
struct PkD8 { PkD d[8]; };
__global__ __launch_bounds__(256) void pack_all(PkD8 ds){
  PkD d = ds.d[blockIdx.y];
  int id = blockIdx.x*256 + threadIdx.x;
  if (id >= d.total) return;
  int j = id & 7, l = (id>>3) & 63;
  int r = id >> 9;
  int nt = r % d.NT; r /= d.NT;
  int KC = d.Cin >> 5;
  int kc = r % KC; int tap = r / KC;
  int c = kc*32 + ((l>>4)<<3) + j;
  int o = nt*16 + (l&15);
  float v = (o < d.Cout) ? d.w[((size_t)o*d.Cin + c)*9 + tap] : 0.f;
  d.dst[id] = f2b(v);
}

struct RpD { const float* w; float* wp; };
struct RpD3 { RpD d[3]; };
__global__ __launch_bounds__(256) void repack_all(RpD3 ds){
  RpD d = ds.d[blockIdx.y];
  int id = blockIdx.x*256 + threadIdx.x;
  int par = id >> 12, o = (id >> 6) & 63, i = id & 63;
  int ry = par >> 1, rx = par & 1;
  #pragma unroll
  for (int jy = 0; jy < 2; ++jy)
    #pragma unroll
    for (int jx = 0; jx < 2; ++jx){
      int ka = 3 - ry - 2*jy, kb = 3 - rx - 2*jx;
      d.wp[((size_t)((par*64 + o)*64 + i))*4 + jy*2 + jx] = d.w[((size_t)(i*64 + o))*16 + ka*4 + kb];
    }
}

struct PzD { u16t* buf; int C, dim, nimg; size_t stride; };
struct PzD5 { PzD d[5]; };
__global__ __launch_bounds__(256) void padzero_all(PzD5 ds){
  PzD d = ds.d[blockIdx.y];
  int per = (4*d.dim - 4)*d.C;
  long total = (long)per*d.nimg;
  for (long id = (long)blockIdx.x*256 + threadIdx.x; id < total; id += (long)gridDim.x*256){
    int n = (int)(id / per), c2 = (int)(id % per);
    int cell = c2 / d.C, c = c2 % d.C;
    int d2 = d.dim - 1;
    int r, col;
    if (cell < d.dim){ r = 0; col = cell; }
    else if (cell < 2*d.dim){ r = d2; col = cell - d.dim; }
    else if (cell < 3*d.dim - 2){ r = cell - 2*d.dim + 1; col = 0; }
    else { r = cell - (3*d.dim - 2) + 1; col = d2; }
    d.buf[(size_t)n*d.stride + ((size_t)r*d.dim + col)*d.C + c] = 0;
  }
}

__global__ __launch_bounds__(256) void padzero2(u16t* buf, int C, int dim){
  int total = (4*dim - 4)*C;
  for (int id = blockIdx.x*256 + threadIdx.x; id < total; id += gridDim.x*256){
    int cell = id / C, c = id % C;
    int d2 = dim - 1;
    int r, col;
    if (cell < dim){ r = 0; col = cell; }
    else if (cell < 2*dim){ r = d2; col = cell - dim; }
    else if (cell < 3*dim - 2){ r = cell - 2*dim + 1; col = 0; }
    else { r = cell - (3*dim - 2) + 1; col = d2; }
    buf[((size_t)r*dim + col)*C + c] = 0;
  }
}

// ========== fused backbone: conv1 (1->64, fp32 FMA, scalar-cached weights) + conv2 (64->64, MFMA) ==========
// Block = 4-row x 16-px x 64-ch conv2-output tile. Stage 8x20 raw fp32 input in LDS.
// conv1: thread = (half = tid>>7 [wave-uniform], pixel = tid&127); all weight/bias indices
// are wave-uniform -> s_load scalar-cache reads, SGPR-operand FMAs. Taps: 9 per-lane LDS
// reads. Output -> swizzled sA (stride 64, slot=(g+px)&7). conv2 MFMA from sA.
// img<7 -> fpad NHWC448 padded, else prednhwc tight.
__global__ __launch_bounds__(256) void bbfused(
    const float* __restrict__ lqs, const float* __restrict__ preds,
    const float* __restrict__ w1, const float* __restrict__ b1,
    const u16t* __restrict__ Bp, const float* __restrict__ b2,
    u16t* __restrict__ fpad, u16t* __restrict__ prednhwc)
{
  __shared__ float sIn1[8][20];
  __shared__ u16t sA[108*64];
  int bid = blockIdx.x;
  bid = (bid & 7)*(gridDim.x >> 3) + (bid >> 3);       // XCD banding
  const int tid = threadIdx.x;
  const int img = bid / 576;
  const int rem = bid - img*576;
  const int y0 = (rem/12)*4, xs = (rem%12)*16;
  const float* ip = (img < 7) ? (lqs + (size_t)img*HWF) : (preds + (size_t)(img-7)*HWF);
  for (int u = tid; u < 160; u += 256){
    int lr = u/20, lc = u%20;
    int iy = y0 - 2 + lr, ix = xs - 2 + lc;
    sIn1[lr][lc] = (iy >= 0 && iy < IMH && ix >= 0 && ix < IMW) ? ip[iy*IMW + ix] : 0.f;
  }
  __syncthreads();
  // ---- conv1: thread = (half, pixel); weights via scalar cache ----
  {
    const int half = __builtin_amdgcn_readfirstlane(tid >> 7);  // wave-uniform
    const int pxl = tid & 127;
    if (pxl < 108){
      int rr = pxl/18, cc = pxl%18;
      float t[9];
      #pragma unroll
      for (int dy = 0; dy < 3; ++dy)
        #pragma unroll
        for (int dx = 0; dx < 3; ++dx) t[dy*3+dx] = sIn1[rr+dy][cc+dx];
      int pr = y0 + rr, pc = xs + cc;
      bool border = (pr == 0) | (pr == 193) | (pc == 0) | (pc == 193);
      const float* wh = w1 + half*288;     // scalar base
      const float* bh = b1 + half*32;
      u16t* outr = &sA[(size_t)pxl*64];
      #pragma unroll
      for (int o8 = 0; o8 < 4; ++o8){
        short8 ov;
        #pragma unroll
        for (int j = 0; j < 8; ++j){
          int oc = o8*8 + j;
          float acc = bh[oc];
          #pragma unroll
          for (int k = 0; k < 9; ++k) acc += t[k]*wh[oc*9 + k];
          ov[j] = (short)(border ? (u16t)0 : f2b(acc));
        }
        int g = half*4 + o8;
        *(short8*)(outr + ((g + pxl)&7)*8) = ov;
      }
    }
  }
  __syncthreads();
  // ---- conv2 MFMA from sA ----
  const int wave = tid >> 6, lane = tid & 63;
  const int m = lane & 15, q = lane >> 4;
  const int rp = wave >> 1, np = wave & 1;
  f32x4 acc[2][2];
  #pragma unroll
  for (int r = 0; r < 2; ++r)
    #pragma unroll
    for (int n = 0; n < 2; ++n) acc[r][n] = (f32x4){0.f,0.f,0.f,0.f};
  #pragma unroll
  for (int kc = 0; kc < 2; ++kc){
    #pragma unroll
    for (int tap = 0; tap < 9; ++tap){
      const int dy = tap/3, dx = tap%3;
      short8 af[2];
      #pragma unroll
      for (int r = 0; r < 2; ++r){
        int px = (2*rp + r + dy)*18 + dx + m;
        af[r] = *(const short8*)&sA[(size_t)px*64 + ((kc*4 + q + px)&7)*8];
      }
      const u16t* bp = Bp + ((size_t)(tap*2 + kc)*4 + np*2)*512 + lane*8;
      short8 b0 = *(const short8*)bp;
      short8 b1w = *(const short8*)(bp + 512);
      #pragma unroll
      for (int r = 0; r < 2; ++r){
        acc[r][0] = __builtin_amdgcn_mfma_f32_16x16x32_bf16(af[r], b0, acc[r][0], 0, 0, 0);
        acc[r][1] = __builtin_amdgcn_mfma_f32_16x16x32_bf16(af[r], b1w, acc[r][1], 0, 0, 0);
      }
    }
  }
  const int px0 = q*4;
  #pragma unroll
  for (int r = 0; r < 2; ++r){
    int yout = y0 + 2*rp + r;
    #pragma unroll
    for (int n = 0; n < 2; ++n){
      int oL = (np*2 + n)*16 + m;
      float bv = b2[oL];
      #pragma unroll
      for (int g = 0; g < 4; ++g){
        int px = xs + px0 + g;
        float v = acc[r][n][g] + bv;
        if (img < 7)
          fpad[((size_t)(yout+1)*PDIM + px+1)*448 + (size_t)img*64 + oL] = f2b(v);
        else
          prednhwc[(size_t)(img-7)*((size_t)HWF*64) + ((size_t)yout*IMW + px)*64 + oL] = f2b(v);
      }
    }
  }
}

// ========== LDS-staged MFMA implicit-GEMM 3x3 stride-1 conv (swizzled sA, stride 32) ==========
// OMODE 4: fuse epilogue 0.1*lrelu(s)+lrelu(f) -> out0pad; OMODE 5: fp32 NCHW, blockIdx.y=o-block
template<int STREAMS, int KC, int OMODE, int NTT, int SWZ>
__global__ __launch_bounds__(256) void cgemm(
    const u16t* __restrict__ A0, const u16t* __restrict__ A1,
    const u16t* __restrict__ Bp, const float* __restrict__ bias,
    float* __restrict__ outf, u16t* __restrict__ outb, u16t* __restrict__ outb2,
    int Cout, int blocksPerImg, int pitchIn, int csIn, size_t aImgStride, int KCtot)
{
  __shared__ u16t sA[STREAMS*108*32];
  int bid = blockIdx.x;
  if (SWZ) bid = (bid & 7)*(gridDim.x >> 3) + (bid >> 3);
  const int tid = threadIdx.x;
  const int wave = tid >> 6, lane = tid & 63;
  const int m = lane & 15, q = lane >> 4;
  const int img = bid / blocksPerImg;
  const int rem = bid - img*blocksPerImg;
  const int y0 = (rem/12)*4, xs = (rem%12)*16;
  const int rp = wave >> 1, np = wave & 1;
  const int ntB = (OMODE == 5) ? blockIdx.y*4 : 0;
  f32x4 acc[STREAMS][2][2];
  #pragma unroll
  for (int s = 0; s < STREAMS; ++s)
    #pragma unroll
    for (int r = 0; r < 2; ++r)
      #pragma unroll
      for (int n = 0; n < 2; ++n) acc[s][r][n] = (f32x4){0.f,0.f,0.f,0.f};

  #pragma unroll 1
  for (int kc = 0; kc < KC; ++kc){
    if (kc) __syncthreads();
    for (int u = tid; u < STREAMS*216; u += 256){
      int st = u/216, r2 = u%216, p = r2>>1, h = r2&1;
      int rr = p/18, cc = p%18;
      size_t ga = (size_t)img*aImgStride + ((size_t)(y0+rr)*pitchIn + xs+cc)*csIn + kc*32 + h*16;
      const u16t* gp = ((STREAMS==2 && st==1) ? A1 : A0) + ga;
      short8 v0 = *(const short8*)gp;
      short8 v1 = *(const short8*)(gp + 8);
      u16t* base = &sA[((size_t)(st*108 + p))*32];
      *(short8*)(base + ((2*h + p)&3)*8) = v0;
      *(short8*)(base + ((2*h + 1 + p)&3)*8) = v1;
    }
    __syncthreads();
    #pragma unroll
    for (int tap = 0; tap < 9; ++tap){
      const int dy = tap/3, dx = tap%3;
      short8 af[STREAMS][2];
      #pragma unroll
      for (int st = 0; st < STREAMS; ++st)
        #pragma unroll
        for (int r = 0; r < 2; ++r){
          int px = (2*rp + r + dy)*18 + dx + m;
          af[st][r] = *(const short8*)&sA[((size_t)(st*108 + px))*32 + ((q + px)&3)*8];
        }
      const u16t* bp = Bp + ((size_t)(tap*KCtot + kc)*NTT + ntB + np*2)*512 + lane*8;
      short8 b0 = *(const short8*)bp;
      short8 b1 = *(const short8*)(bp + 512);
      #pragma unroll
      for (int st = 0; st < STREAMS; ++st)
        #pragma unroll
        for (int r = 0; r < 2; ++r){
          acc[st][r][0] = __builtin_amdgcn_mfma_f32_16x16x32_bf16(af[st][r], b0, acc[st][r][0], 0, 0, 0);
          acc[st][r][1] = __builtin_amdgcn_mfma_f32_16x16x32_bf16(af[st][r], b1, acc[st][r][1], 0, 0, 0);
        }
    }
  }
  const int px0 = q*4;
  #pragma unroll
  for (int r = 0; r < 2; ++r){
    int yout = y0 + 2*rp + r;
    #pragma unroll
    for (int n = 0; n < 2; ++n){
      int oL = (np*2 + n)*16 + m;
      if (OMODE == 4){
        float bv = bias[oL];
        #pragma unroll
        for (int g = 0; g < 4; ++g){
          int px = xs + px0 + g;
          float v = 0.1f*lrelu(acc[0][r][n][g] + bv) + lrelu(acc[1][r][n][g] + bv);
          outb[((size_t)(yout+1)*PDIM + px+1)*64 + oL] = f2b(v);
        }
      } else {
        int o = ntB*16 + oL;
        if (o < Cout){
          float bv = bias[o];
          #pragma unroll
          for (int g = 0; g < 4; ++g){
            int px = xs + px0 + g;
            outf[(size_t)o*HWF + (size_t)yout*IMW + px] = acc[0][r][n][g] + bv;
          }
        }
      }
    }
  }
}

// ---------- no-LDS MFMA implicit-GEMM (U-Net smalls); blockIdx.y = o-group of NT ----------
template<int NT, int KC, int STRIDE, int OMODE, int ACT, int SWZ>
__global__ __launch_bounds__(256) void gconv3(
    const u16t* __restrict__ A0, const u16t* __restrict__ Bp, const float* __restrict__ bias,
    float* __restrict__ outf, u16t* __restrict__ outb,
    int Cout, int Wout, int strips, int blocksPerImg,
    int pitchIn, int csIn, int coIn, size_t aImgStride,
    size_t outImgStride, int pitchOut, int csOut, int coOut,
    int KCtot, int NTtot)
{
  int bid = blockIdx.x;
  if (SWZ) bid = (bid & 7)*(gridDim.x >> 3) + (bid >> 3);
  const int wave = threadIdx.x >> 6;
  const int lane = threadIdx.x & 63;
  const int img = bid / blocksPerImg;
  const int sid = (bid - img*blocksPerImg)*4 + wave;
  const int y = sid / strips, xs = (sid % strips) * 16;
  const int m = lane & 15, q = lane >> 4;
  const int ntOff = blockIdx.y*NT;
  f32x4 acc[NT];
  #pragma unroll
  for (int nt = 0; nt < NT; ++nt) acc[nt] = (f32x4){0.f,0.f,0.f,0.f};

  for (int tap = 0; tap < 9; ++tap){
    int dy = tap/3, dx = tap%3;
    int row = STRIDE*y + dy;
    int col = (STRIDE == 1) ? (xs + m + dx) : (2*(xs + m) + dx);
    size_t abase = (size_t)img*aImgStride + ((size_t)row*pitchIn + col)*csIn + coIn + q*8;
    const u16t* ap0 = A0 + abase;
    const u16t* bp = Bp + ((size_t)(tap*KCtot)*NTtot + ntOff)*512 + lane*8;
    #pragma unroll
    for (int kc = 0; kc < KC; ++kc){
      short8 av0 = *(const short8*)(ap0 + kc*32);
      #pragma unroll
      for (int nt = 0; nt < NT; ++nt){
        short8 bv = *(const short8*)(bp + (size_t)(kc*NTtot + nt)*512);
        acc[nt] = __builtin_amdgcn_mfma_f32_16x16x32_bf16(av0, bv, acc[nt], 0, 0, 0);
      }
    }
  }
  const int prow0 = q*4;
  #pragma unroll
  for (int nt = 0; nt < NT; ++nt){
    int o = (ntOff + nt)*16 + m;
    if (o >= Cout) continue;
    float bv = bias[o];
    #pragma unroll
    for (int r = 0; r < 4; ++r){
      int px = xs + prow0 + r;
      if (px >= Wout) continue;
      float v = acc[nt][r] + bv;
      if (ACT) v = fmaxf(v, 0.f);
      if (OMODE == 0){
        outf[((size_t)img*Cout + o)*((size_t)Wout*Wout) + (size_t)y*Wout + px] = v;
      } else if (OMODE == 1){
        outb[(size_t)img*outImgStride + ((size_t)(y+1)*pitchOut + px+1)*csOut + coOut + o] = f2b(v);
      } else {
        outb[(size_t)img*outImgStride + ((size_t)y*pitchOut + px)*csOut + coOut + o] = f2b(v);
      }
    }
  }
}

// ---------- gating + flow-warp, channels-last bf16, XCD-banded, all 7 t per thread ----------
__global__ __launch_bounds__(256) void gate_nhwc(
    const u16t* __restrict__ fpad, const u16t* __restrict__ pred,
    const float* __restrict__ mv, u16t* __restrict__ spad)
{
  int bid = blockIdx.x;
  int xcd = bid & 7, lb = bid >> 3;
  int idx = (xcd*18 + lb)*256 + threadIdx.x;
  int y = idx/IMW, x = idx%IMW;
  size_t pc = ((size_t)(y+1)*PDIM + (x+1))*448;
  const u16t* rp = fpad + pc + 192;
  short8 r8[8];
  #pragma unroll
  for (int c8 = 0; c8 < 8; ++c8) r8[c8] = *(const short8*)(rp + c8*8);
  #pragma unroll 1
  for (int t = 0; t < 7; ++t){
    const u16t* pp = pred + ((size_t)t*HWF + idx)*64;
    u16t* sp = spad + pc + (size_t)t*64;
    const u16t* tp[4]; float tw[4];
    if (t == 0){
      tp[0] = fpad + pc; tw[0] = 1.f;
      tp[1] = tp[2] = tp[3] = fpad + pc; tw[1] = tw[2] = tw[3] = 0.f;
    } else {
      float fx = mv[(((size_t)(t-1)*HWF + idx))*2 + 0];
      float fy = mv[(((size_t)(t-1)*HWF + idx))*2 + 1];
      float ys = (float)y + fy, xsf = (float)x + fx;
      float y0f = floorf(ys), x0f = floorf(xsf);
      float wy = ys - y0f, wx = xsf - x0f;
      int y0 = (int)y0f, x0i = (int)x0f;
      int kk = 0;
      #pragma unroll
      for (int dy2 = 0; dy2 < 2; ++dy2)
        #pragma unroll
        for (int dx2 = 0; dx2 < 2; ++dx2){
          int yi = y0+dy2, xi = x0i+dx2;
          float wv = (dy2 ? wy : 1.f-wy)*(dx2 ? wx : 1.f-wx);
          bool ok = (yi >= 0 && yi <= 191 && xi >= 0 && xi <= 191);
          int yc = min(max(yi,0),191), xc = min(max(xi,0),191);
          tp[kk] = fpad + ((size_t)(yc+1)*PDIM + xc+1)*448 + (size_t)(t-1)*64;
          tw[kk] = ok ? wv : 0.f;
          ++kk;
        }
    }
    #pragma unroll
    for (int c8 = 0; c8 < 8; ++c8){
      short8 pv = *(const short8*)(pp + c8*8);
      short8 t0v = *(const short8*)(tp[0] + c8*8);
      short8 t1v = *(const short8*)(tp[1] + c8*8);
      short8 t2v = *(const short8*)(tp[2] + c8*8);
      short8 t3v = *(const short8*)(tp[3] + c8*8);
      short8 ov;
      #pragma unroll
      for (int j = 0; j < 8; ++j){
        float r = b2f((u16t)r8[c8][j]);
        float p = b2f((u16t)pv[j]);
        float a = tw[0]*b2f((u16t)t0v[j]) + tw[1]*b2f((u16t)t1v[j])
                + tw[2]*b2f((u16t)t2v[j]) + tw[3]*b2f((u16t)t3v[j]);
        float sv = a*sigmoidf(a*r) + p*sigmoidf(p*r);
        ov[j] = (short)f2b(sv);
      }
      *(short8*)(sp + c8*8) = ov;
    }
  }
}

// ---------------- convT 4x4 s2 p1 (+relu): parity-decomposed, fp32 in, bf16 NHWC out ----------------
__global__ __launch_bounds__(256) void convT_tile2(
    const float* __restrict__ in, const float* __restrict__ wp,
    const float* __restrict__ bias, u16t* __restrict__ outb,
    int Hin, int tilesX, int pitchOut, int csOut, int coOut)
{
  const int CC = 4;
  __shared__ float sIn[CC][10*11];
  __shared__ float sW[16][CC][4][4];
  const int Win = Hin;
  const int o0 = blockIdx.x*16;
  const int tile = blockIdx.y;
  const int ty0 = (tile/tilesX)*16, tx0 = (tile%tilesX)*16;
  const int tid = threadIdx.x;
  const int py = tid>>4, px = tid&15;
  const int ry = py&1, rx = px&1, par = ry*2 + rx;
  const int lr = py>>1, lc = px>>1;
  const int r0 = ty0>>1, c0 = tx0>>1;
  float acc[16] = {};
  for (int ib = 0; ib < 64; ib += CC){
    for (int i = tid; i < CC*100; i += 256){
      int c = i/100, rem = i%100, r = rem/10, col = rem%10;
      int gy = r0 - 1 + r, gx = c0 - 1 + col;
      float v = 0.f;
      if (gy >= 0 && gy < Hin && gx >= 0 && gx < Win)
        v = in[(size_t)(ib + c)*Hin*Win + gy*Win + gx];
      sIn[c][r*11 + col] = v;
    }
    for (int i = tid; i < 1024; i += 256){
      int ol = i >> 6, rem = i & 63, ci = rem >> 4, p2 = (rem >> 2) & 3, j = rem & 3;
      sW[ol][ci][p2][j] = wp[((size_t)((p2*64 + o0 + ol)*64) + ib + ci)*4 + j];
    }
    __syncthreads();
    #pragma unroll
    for (int ci = 0; ci < CC; ++ci){
      int rb = lr + ry, cb = lc + rx;
      float t00 = sIn[ci][rb*11 + cb],     t01 = sIn[ci][rb*11 + cb + 1];
      float t10 = sIn[ci][(rb+1)*11 + cb], t11 = sIn[ci][(rb+1)*11 + cb + 1];
      #pragma unroll
      for (int ol = 0; ol < 16; ++ol){
        const float* wv = &sW[ol][ci][par][0];
        acc[ol] += t00*wv[0] + t01*wv[1] + t10*wv[2] + t11*wv[3];
      }
    }
    __syncthreads();
  }
  int gy = ty0 + py, gx = tx0 + px;
  u16t* op = outb + ((size_t)(gy+1)*pitchOut + gx+1)*csOut + coOut + o0;
  short8 pa, pb;
  #pragma unroll
  for (int i = 0; i < 8; ++i) pa[i] = (short)f2b(fmaxf(acc[i] + bias[o0+i], 0.f));
  #pragma unroll
  for (int i = 0; i < 8; ++i) pb[i] = (short)f2b(fmaxf(acc[8+i] + bias[o0+8+i], 0.f));
  *(short8*)op = pa;
  *(short8*)(op + 8) = pb;
}

// ---------------- deformable conv ----------------
__global__ __launch_bounds__(256) void deform_sample_k(
    const float* __restrict__ lqs, const float* __restrict__ om,
    float* __restrict__ vbuf)
{
  int idx = blockIdx.x*256 + threadIdx.x;
  int g = blockIdx.y;
  int h = idx / IMW, x = idx % IMW;
  const float* img = lqs + (size_t)g*HWF;
  #pragma unroll
  for (int k = 0; k < 9; ++k){
    int j = g*9 + k;
    float offy = om[(size_t)(j*2 + 0)*HWF + idx];
    float offx = om[(size_t)(j*2 + 1)*HWF + idx];
    float m = sigmoidf(om[(size_t)(126 + j)*HWF + idx]);
    float ys = (float)(h + (k/3) - 1) + offy;
    float xs = (float)(x + (k%3) - 1) + offx;
    vbuf[(size_t)j*HWF + idx] = bilin(img, ys, xs, IMH, IMW) * m;
  }
}

__global__ __launch_bounds__(256) void deform_out_k(
    const float* __restrict__ vbuf, const float* __restrict__ dcw,
    const float* __restrict__ dcb, float* __restrict__ out)
{
  __shared__ float sw[16*63];
  int idx = blockIdx.x*256 + threadIdx.x;
  int o0 = blockIdx.y*16;
  for (int i = threadIdx.x; i < 16*63; i += 256)
    sw[i] = dcw[(size_t)o0*63 + i];
  __syncthreads();
  float v[63];
  #pragma unroll
  for (int j = 0; j < 63; ++j) v[j] = vbuf[(size_t)j*HWF + idx];
  for (int ol = 0; ol < 16; ++ol){
    float acc = dcb[o0 + ol];
    #pragma unroll
    for (int j = 0; j < 63; ++j) acc += v[j]*sw[ol*63 + j];
    out[(size_t)(o0 + ol)*HWF + idx] = fmaxf(acc, 0.f);
  }
}

extern "C" void kernel_launch(void* const* d_in, const int* in_sizes, int n_in,
                              void* d_out, int out_size, void* d_ws, size_t ws_size,
                              hipStream_t stream)
{
  const float* lqs   = (const float*)d_in[0];
  const float* preds = (const float*)d_in[1];
  const float* mv    = (const float*)d_in[2];
  const float* bw1   = (const float*)d_in[3];
  const float* bb1   = (const float*)d_in[4];
  const float* bw2   = (const float*)d_in[5];
  const float* bb2   = (const float*)d_in[6];
  const float* dn1w  = (const float*)d_in[7];
  const float* dn1b  = (const float*)d_in[8];
  const float* dn2w  = (const float*)d_in[9];
  const float* dn2b  = (const float*)d_in[10];
  const float* up1cw = (const float*)d_in[11];
  const float* up1cb = (const float*)d_in[12];
  const float* up1tw = (const float*)d_in[13];
  const float* up1tb = (const float*)d_in[14];
  const float* up2cw = (const float*)d_in[15];
  const float* up2cb = (const float*)d_in[16];
  const float* up2tw = (const float*)d_in[17];
  const float* up2tb = (const float*)d_in[18];
  const float* trcw  = (const float*)d_in[19];
  const float* trcb  = (const float*)d_in[20];
  const float* trtw  = (const float*)d_in[21];
  const float* trtb  = (const float*)d_in[22];
  const float* ffw   = (const float*)d_in[23];
  const float* ffb   = (const float*)d_in[24];
  const float* omw   = (const float*)d_in[25];
  const float* omb   = (const float*)d_in[26];
  const float* dcw   = (const float*)d_in[27];
  const float* dcb   = (const float*)d_in[28];
  float* outp = (float*)d_out;

  char* p = (char*)d_ws;
  const size_t PIMG64 = (size_t)PDIM*PDIM*64;
  u16t* spadreg  = (u16t*)p; p += 14*PIMG64*2;                // spad [194][194][448]; later featfpad
  u16t* fpad     = (u16t*)p; p += (size_t)PDIM*PDIM*448*2;    // feat NHWC448; later vbuf (fp32)
  u16t* prednhwc = (u16t*)p; p += (size_t)7*HWF*64*2;         // pred NHWC64; later om (fp32)
  u16t* out0pad  = (u16t*)p; p += (size_t)PDIM*PDIM*64*2;
  u16t* cat1pad  = (u16t*)p; p += (size_t)98*98*128*2;
  u16t* cat2pad  = (u16t*)p; p += (size_t)50*50*128*2;
  float* t0      = (float*)p; p += (size_t)24*24*64*4;
  float* u2      = (float*)p; p += (size_t)48*48*64*4;
  float* u1      = (float*)p; p += (size_t)96*96*64*4;
  u16t* ffwpack  = (u16t*)p; p += 258048*2;
  u16t* c2pack   = (u16t*)p; p += 36864*2;
  u16t* ompack   = (u16t*)p; p += 110592*2;
  u16t* dn1pack  = (u16t*)p; p += 36864*2;
  u16t* dn2pack  = (u16t*)p; p += 36864*2;
  u16t* trcpack  = (u16t*)p; p += 36864*2;
  u16t* up2cpack = (u16t*)p; p += 73728*2;
  u16t* up1cpack = (u16t*)p; p += 73728*2;
  float* wp0     = (float*)p; p += 65536*4;
  float* wp1     = (float*)p; p += 65536*4;
  float* wp2     = (float*)p; p += 65536*4;

  u16t* spad = spadreg;
  u16t* featfpad = spadreg;
  float* om = (float*)prednhwc;
  float* vbuf = (float*)fpad;

  dim3 blk(256);
  // setup
  PkD8 pk = {{ {ffw, ffwpack, 448, 64, 4, 258048}, {bw2, c2pack, 64, 64, 4, 36864},
               {omw, ompack, 64, 189, 12, 110592}, {dn1w, dn1pack, 64, 64, 4, 36864},
               {dn2w, dn2pack, 64, 64, 4, 36864},  {trcw, trcpack, 64, 64, 4, 36864},
               {up2cw, up2cpack, 128, 64, 4, 73728}, {up1cw, up1cpack, 128, 64, 4, 73728} }};
  pack_all<<<dim3(1008,8), blk, 0, stream>>>(pk);
  RpD3 rp3 = {{ {trtw, wp0}, {up2tw, wp1}, {up1tw, wp2} }};
  repack_all<<<dim3(64,3), blk, 0, stream>>>(rp3);
  PzD5 pz = {{ {spad, 448, PDIM, 1, 0}, {fpad, 448, PDIM, 1, 0},
               {out0pad, 64, PDIM, 1, 0}, {cat1pad, 128, 98, 1, 0}, {cat2pad, 128, 50, 1, 0} }};
  padzero_all<<<dim3(2704,5), blk, 0, stream>>>(pz);
  // fused backbone (conv1 scalar-weight FMA + conv2 MFMA, no HBM intermediate)
  bbfused<<<dim3(8064), blk, 0, stream>>>(lqs, preds, bw1, bb1, c2pack, bb2, fpad, prednhwc);
  // gate (+warp) -> spad
  gate_nhwc<<<dim3(144), blk, 0, stream>>>(fpad, prednhwc, mv, spad);
  // fused dual conv -> out0pad
  cgemm<2,14,4,4,1><<<dim3(576,1), blk, 0, stream>>>(spad, fpad, ffwpack, ffb,
      nullptr, out0pad, nullptr, 64, 576, PDIM, 448, 0, 14);
  // U-Net (NT=1 o-splits for occupancy)
  gconv3<1,2,2,1,1,1><<<dim3(144,4), blk, 0, stream>>>(out0pad, dn1pack, dn1b, nullptr, cat1pad,
      64, 96, 6, 144, PDIM, 64, 0, 0, 0, 98, 128, 64, 2, 4);       // out1 -> cat1[64:]
  gconv3<1,2,2,1,1,0><<<dim3(36,4), blk, 0, stream>>>(cat1pad, dn2pack, dn2b, nullptr, cat2pad,
      64, 48, 3, 36, 98, 128, 64, 0, 0, 50, 128, 64, 2, 4);        // out2 -> cat2[64:]
  gconv3<1,2,2,0,1,0><<<dim3(12,4), blk, 0, stream>>>(cat2pad, trcpack, trcb, t0, nullptr,
      64, 24, 2, 12, 50, 128, 64, 0, 0, 0, 0, 0, 2, 4);            // t0 (fp32 NCHW)
  convT_tile2<<<dim3(4,9), blk, 0, stream>>>(t0, wp0, trtb, cat2pad, 24, 3, 50, 128, 0);   // t1 -> cat2[:64]
  gconv3<1,4,1,0,1,0><<<dim3(36,4), blk, 0, stream>>>(cat2pad, up2cpack, up2cb, u2, nullptr,
      64, 48, 3, 36, 50, 128, 0, 0, 0, 0, 0, 0, 4, 4);             // u2 (fp32 NCHW)
  convT_tile2<<<dim3(4,36), blk, 0, stream>>>(u2, wp1, up2tb, cat1pad, 48, 6, 98, 128, 0); // u2t -> cat1[:64]
  gconv3<1,4,1,0,1,1><<<dim3(144,4), blk, 0, stream>>>(cat1pad, up1cpack, up1cb, u1, nullptr,
      64, 96, 6, 144, 98, 128, 0, 0, 0, 0, 0, 0, 4, 4);            // u1 (fp32 NCHW)
  // final convT -> featfpad
  padzero2<<<dim3(194), blk, 0, stream>>>(featfpad, 64, PDIM);
  convT_tile2<<<dim3(4,144), blk, 0, stream>>>(u1, wp2, up1tb, featfpad, 96, 12, PDIM, 64, 0);
  // offsets/masks conv (64 -> 189)
  cgemm<1,2,5,12,1><<<dim3(576,3), blk, 0, stream>>>(featfpad, nullptr, ompack, omb,
      om, nullptr, nullptr, 189, 576, PDIM, 64, 0, 2);
  // deformable conv
  deform_sample_k<<<dim3(144,7), blk, 0, stream>>>(lqs, om, vbuf);
  deform_out_k<<<dim3(144,4), blk, 0, stream>>>(vbuf, dcw, dcb, outp);
}

// Round 12
// 567.283 us; speedup vs baseline: 1.1155x; 1.0366x over previous
//
#include <hip/hip_runtime.h>
#include <math.h>

#define IMH 192
#define IMW 192
#define HWF 36864
#define PDIM 194

typedef unsigned short u16t;
typedef __attribute__((ext_vector_type(8))) short short8;
typedef __attribute__((ext_vector_type(4))) float f32x4;

__device__ __forceinline__ float sigmoidf(float x){ return 1.f/(1.f+expf(-x)); }
__device__ __forceinline__ float lrelu(float x){ return x > 0.f ? x : 0.1f*x; }
__device__ __forceinline__ float b2f(u16t h){ unsigned u = ((unsigned)h)<<16; return __uint_as_float(u); }
__device__ __forceinline__ u16t f2b(float f){
  unsigned u = __float_as_uint(f);
  u += 0x7FFFu + ((u>>16)&1u);
  return (u16t)(u>>16);
}

__device__ __forceinline__ float bilin(const float* __restrict__ img, float ys, float xs, int H, int W){
  float y0f = floorf(ys), x0f = floorf(xs);
  float wy = ys - y0f, wx = xs - x0f;
  int y0 = (int)y0f, x0 = (int)x0f;
  float acc = 0.f;
  #pragma unroll
  for (int dy=0; dy<2; ++dy){
    int yi = y0+dy;
    float wyv = dy ? wy : 1.f-wy;
    if (yi < 0 || yi >= H) continue;
    #pragma unroll
    for (int dx=0; dx<2; ++dx){
      int xi = x0+dx;
      float wxv = dx ? wx : 1.f-wx;
      if (xi < 0 || xi >= W) continue;
      acc += img[yi*W+xi]*(wyv*wxv);
    }
  }
  return acc;
}

// ================= descriptor-driven setup kernels =================
struct PkD { const float* w; u16t* dst; int Cin, Cout, NT, total; };
struct PkD8 { PkD d[8]; };
__global__ __launch_bounds__(256) void pack_all(PkD8 ds){
  PkD d = ds.d[blockIdx.y];
  int id = blockIdx.x*256 + threadIdx.x;
  if (id >= d.total) return;
  int j = id & 7, l = (id>>3) & 63;
  int r = id >> 9;
  int nt = r % d.NT; r /= d.NT;
  int KC = d.Cin >> 5;
  int kc = r % KC; int tap = r / KC;
  int c = kc*32 + ((l>>4)<<3) + j;
  int o = nt*16 + (l&15);
  float v = (o < d.Cout) ? d.w[((size_t)o*d.Cin + c)*9 + tap] : 0.f;
  d.dst[id] = f2b(v);
}

struct RpD { const float* w; float* wp; };
struct RpD3 { RpD d[3]; };
__global__ __launch_bounds__(256) void repack_all(RpD3 ds){
  RpD d = ds.d[blockIdx.y];
  int id = blockIdx.x*256 + threadIdx.x;
  int par = id >> 12, o = (id >> 6) & 63, i = id & 63;
  int ry = par >> 1, rx = par & 1;
  #pragma unroll
  for (int jy = 0; jy < 2; ++jy)
    #pragma unroll
    for (int jx = 0; jx < 2; ++jx){
      int ka = 3 - ry - 2*jy, kb = 3 - rx - 2*jx;
      d.wp[((size_t)((par*64 + o)*64 + i))*4 + jy*2 + jx] = d.w[((size_t)(i*64 + o))*16 + ka*4 + kb];
    }
}

struct PzD { u16t* buf; int C, dim, nimg; size_t stride; };
struct PzD5 { PzD d[5]; };
__global__ __launch_bounds__(256) void padzero_all(PzD5 ds){
  PzD d = ds.d[blockIdx.y];
  int per = (4*d.dim - 4)*d.C;
  long total = (long)per*d.nimg;
  for (long id = (long)blockIdx.x*256 + threadIdx.x; id < total; id += (long)gridDim.x*256){
    int n = (int)(id / per), c2 = (int)(id % per);
    int cell = c2 / d.C, c = c2 % d.C;
    int d2 = d.dim - 1;
    int r, col;
    if (cell < d.dim){ r = 0; col = cell; }
    else if (cell < 2*d.dim){ r = d2; col = cell - d.dim; }
    else if (cell < 3*d.dim - 2){ r = cell - 2*d.dim + 1; col = 0; }
    else { r = cell - (3*d.dim - 2) + 1; col = d2; }
    d.buf[(size_t)n*d.stride + ((size_t)r*d.dim + col)*d.C + c] = 0;
  }
}

__global__ __launch_bounds__(256) void padzero2(u16t* buf, int C, int dim){
  int total = (4*dim - 4)*C;
  for (int id = blockIdx.x*256 + threadIdx.x; id < total; id += gridDim.x*256){
    int cell = id / C, c = id % C;
    int d2 = dim - 1;
    int r, col;
    if (cell < dim){ r = 0; col = cell; }
    else if (cell < 2*dim){ r = d2; col = cell - dim; }
    else if (cell < 3*dim - 2){ r = cell - 2*dim + 1; col = 0; }
    else { r = cell - (3*dim - 2) + 1; col = d2; }
    buf[((size_t)r*dim + col)*C + c] = 0;
  }
}

// ========== fused backbone: conv1 (1->64, fp32 FMA, scalar-cached weights) + conv2 (64->64, MFMA) ==========
__global__ __launch_bounds__(256) void bbfused(
    const float* __restrict__ lqs, const float* __restrict__ preds,
    const float* __restrict__ w1, const float* __restrict__ b1,
    const u16t* __restrict__ Bp, const float* __restrict__ b2,
    u16t* __restrict__ fpad, u16t* __restrict__ prednhwc)
{
  __shared__ float sIn1[8][20];
  __shared__ u16t sA[108*64];
  int bid = blockIdx.x;
  bid = (bid & 7)*(gridDim.x >> 3) + (bid >> 3);       // XCD banding
  const int tid = threadIdx.x;
  const int img = bid / 576;
  const int rem = bid - img*576;
  const int y0 = (rem/12)*4, xs = (rem%12)*16;
  const float* ip = (img < 7) ? (lqs + (size_t)img*HWF) : (preds + (size_t)(img-7)*HWF);
  for (int u = tid; u < 160; u += 256){
    int lr = u/20, lc = u%20;
    int iy = y0 - 2 + lr, ix = xs - 2 + lc;
    sIn1[lr][lc] = (iy >= 0 && iy < IMH && ix >= 0 && ix < IMW) ? ip[iy*IMW + ix] : 0.f;
  }
  __syncthreads();
  // ---- conv1: thread = (half, pixel); weights via scalar cache ----
  {
    const int half = __builtin_amdgcn_readfirstlane(tid >> 7);  // wave-uniform
    const int pxl = tid & 127;
    if (pxl < 108){
      int rr = pxl/18, cc = pxl%18;
      float t[9];
      #pragma unroll
      for (int dy = 0; dy < 3; ++dy)
        #pragma unroll
        for (int dx = 0; dx < 3; ++dx) t[dy*3+dx] = sIn1[rr+dy][cc+dx];
      int pr = y0 + rr, pc = xs + cc;
      bool border = (pr == 0) | (pr == 193) | (pc == 0) | (pc == 193);
      const float* wh = w1 + half*288;     // scalar base
      const float* bh = b1 + half*32;
      u16t* outr = &sA[(size_t)pxl*64];
      #pragma unroll
      for (int o8 = 0; o8 < 4; ++o8){
        short8 ov;
        #pragma unroll
        for (int j = 0; j < 8; ++j){
          int oc = o8*8 + j;
          float acc = bh[oc];
          #pragma unroll
          for (int k = 0; k < 9; ++k) acc += t[k]*wh[oc*9 + k];
          ov[j] = (short)(border ? (u16t)0 : f2b(acc));
        }
        int g = half*4 + o8;
        *(short8*)(outr + ((g + pxl)&7)*8) = ov;
      }
    }
  }
  __syncthreads();
  // ---- conv2 MFMA from sA ----
  const int wave = tid >> 6, lane = tid & 63;
  const int m = lane & 15, q = lane >> 4;
  const int rp = wave >> 1, np = wave & 1;
  f32x4 acc[2][2];
  #pragma unroll
  for (int r = 0; r < 2; ++r)
    #pragma unroll
    for (int n = 0; n < 2; ++n) acc[r][n] = (f32x4){0.f,0.f,0.f,0.f};
  #pragma unroll
  for (int kc = 0; kc < 2; ++kc){
    #pragma unroll
    for (int tap = 0; tap < 9; ++tap){
      const int dy = tap/3, dx = tap%3;
      short8 af[2];
      #pragma unroll
      for (int r = 0; r < 2; ++r){
        int px = (2*rp + r + dy)*18 + dx + m;
        af[r] = *(const short8*)&sA[(size_t)px*64 + ((kc*4 + q + px)&7)*8];
      }
      const u16t* bp = Bp + ((size_t)(tap*2 + kc)*4 + np*2)*512 + lane*8;
      short8 b0 = *(const short8*)bp;
      short8 b1w = *(const short8*)(bp + 512);
      #pragma unroll
      for (int r = 0; r < 2; ++r){
        acc[r][0] = __builtin_amdgcn_mfma_f32_16x16x32_bf16(af[r], b0, acc[r][0], 0, 0, 0);
        acc[r][1] = __builtin_amdgcn_mfma_f32_16x16x32_bf16(af[r], b1w, acc[r][1], 0, 0, 0);
      }
    }
  }
  const int px0 = q*4;
  #pragma unroll
  for (int r = 0; r < 2; ++r){
    int yout = y0 + 2*rp + r;
    #pragma unroll
    for (int n = 0; n < 2; ++n){
      int oL = (np*2 + n)*16 + m;
      float bv = b2[oL];
      #pragma unroll
      for (int g = 0; g < 4; ++g){
        int px = xs + px0 + g;
        float v = acc[r][n][g] + bv;
        if (img < 7)
          fpad[((size_t)(yout+1)*PDIM + px+1)*448 + (size_t)img*64 + oL] = f2b(v);
        else
          prednhwc[(size_t)(img-7)*((size_t)HWF*64) + ((size_t)yout*IMW + px)*64 + oL] = f2b(v);
      }
    }
  }
}

// ========== LDS-staged MFMA implicit-GEMM 3x3 stride-1 conv (swizzled sA, stride 32) ==========
template<int STREAMS, int KC, int OMODE, int NTT, int SWZ>
__global__ __launch_bounds__(256) void cgemm(
    const u16t* __restrict__ A0, const u16t* __restrict__ A1,
    const u16t* __restrict__ Bp, const float* __restrict__ bias,
    float* __restrict__ outf, u16t* __restrict__ outb, u16t* __restrict__ outb2,
    int Cout, int blocksPerImg, int pitchIn, int csIn, size_t aImgStride, int KCtot)
{
  __shared__ u16t sA[STREAMS*108*32];
  int bid = blockIdx.x;
  if (SWZ) bid = (bid & 7)*(gridDim.x >> 3) + (bid >> 3);
  const int tid = threadIdx.x;
  const int wave = tid >> 6, lane = tid & 63;
  const int m = lane & 15, q = lane >> 4;
  const int img = bid / blocksPerImg;
  const int rem = bid - img*blocksPerImg;
  const int y0 = (rem/12)*4, xs = (rem%12)*16;
  const int rp = wave >> 1, np = wave & 1;
  const int ntB = (OMODE == 5) ? blockIdx.y*4 : 0;
  f32x4 acc[STREAMS][2][2];
  #pragma unroll
  for (int s = 0; s < STREAMS; ++s)
    #pragma unroll
    for (int r = 0; r < 2; ++r)
      #pragma unroll
      for (int n = 0; n < 2; ++n) acc[s][r][n] = (f32x4){0.f,0.f,0.f,0.f};

  #pragma unroll 1
  for (int kc = 0; kc < KC; ++kc){
    if (kc) __syncthreads();
    for (int u = tid; u < STREAMS*216; u += 256){
      int st = u/216, r2 = u%216, p = r2>>1, h = r2&1;
      int rr = p/18, cc = p%18;
      size_t ga = (size_t)img*aImgStride + ((size_t)(y0+rr)*pitchIn + xs+cc)*csIn + kc*32 + h*16;
      const u16t* gp = ((STREAMS==2 && st==1) ? A1 : A0) + ga;
      short8 v0 = *(const short8*)gp;
      short8 v1 = *(const short8*)(gp + 8);
      u16t* base = &sA[((size_t)(st*108 + p))*32];
      *(short8*)(base + ((2*h + p)&3)*8) = v0;
      *(short8*)(base + ((2*h + 1 + p)&3)*8) = v1;
    }
    __syncthreads();
    #pragma unroll
    for (int tap = 0; tap < 9; ++tap){
      const int dy = tap/3, dx = tap%3;
      short8 af[STREAMS][2];
      #pragma unroll
      for (int st = 0; st < STREAMS; ++st)
        #pragma unroll
        for (int r = 0; r < 2; ++r){
          int px = (2*rp + r + dy)*18 + dx + m;
          af[st][r] = *(const short8*)&sA[((size_t)(st*108 + px))*32 + ((q + px)&3)*8];
        }
      const u16t* bp = Bp + ((size_t)(tap*KCtot + kc)*NTT + ntB + np*2)*512 + lane*8;
      short8 b0 = *(const short8*)bp;
      short8 b1 = *(const short8*)(bp + 512);
      #pragma unroll
      for (int st = 0; st < STREAMS; ++st)
        #pragma unroll
        for (int r = 0; r < 2; ++r){
          acc[st][r][0] = __builtin_amdgcn_mfma_f32_16x16x32_bf16(af[st][r], b0, acc[st][r][0], 0, 0, 0);
          acc[st][r][1] = __builtin_amdgcn_mfma_f32_16x16x32_bf16(af[st][r], b1, acc[st][r][1], 0, 0, 0);
        }
    }
  }
  const int px0 = q*4;
  #pragma unroll
  for (int r = 0; r < 2; ++r){
    int yout = y0 + 2*rp + r;
    #pragma unroll
    for (int n = 0; n < 2; ++n){
      int oL = (np*2 + n)*16 + m;
      if (OMODE == 4){
        float bv = bias[oL];
        #pragma unroll
        for (int g = 0; g < 4; ++g){
          int px = xs + px0 + g;
          float v = 0.1f*lrelu(acc[0][r][n][g] + bv) + lrelu(acc[1][r][n][g] + bv);
          outb[((size_t)(yout+1)*PDIM + px+1)*64 + oL] = f2b(v);
        }
      } else {
        int o = ntB*16 + oL;
        if (o < Cout){
          float bv = bias[o];
          #pragma unroll
          for (int g = 0; g < 4; ++g){
            int px = xs + px0 + g;
            outf[(size_t)o*HWF + (size_t)yout*IMW + px] = acc[0][r][n][g] + bv;
          }
        }
      }
    }
  }
}

// ---------- no-LDS MFMA implicit-GEMM (U-Net smalls); blockIdx.y = o-group of NT ----------
template<int NT, int KC, int STRIDE, int OMODE, int ACT, int SWZ>
__global__ __launch_bounds__(256) void gconv3(
    const u16t* __restrict__ A0, const u16t* __restrict__ Bp, const float* __restrict__ bias,
    float* __restrict__ outf, u16t* __restrict__ outb,
    int Cout, int Wout, int strips, int blocksPerImg,
    int pitchIn, int csIn, int coIn, size_t aImgStride,
    size_t outImgStride, int pitchOut, int csOut, int coOut,
    int KCtot, int NTtot)
{
  int bid = blockIdx.x;
  if (SWZ) bid = (bid & 7)*(gridDim.x >> 3) + (bid >> 3);
  const int wave = threadIdx.x >> 6;
  const int lane = threadIdx.x & 63;
  const int img = bid / blocksPerImg;
  const int sid = (bid - img*blocksPerImg)*4 + wave;
  const int y = sid / strips, xs = (sid % strips) * 16;
  const int m = lane & 15, q = lane >> 4;
  const int ntOff = blockIdx.y*NT;
  f32x4 acc[NT];
  #pragma unroll
  for (int nt = 0; nt < NT; ++nt) acc[nt] = (f32x4){0.f,0.f,0.f,0.f};

  for (int tap = 0; tap < 9; ++tap){
    int dy = tap/3, dx = tap%3;
    int row = STRIDE*y + dy;
    int col = (STRIDE == 1) ? (xs + m + dx) : (2*(xs + m) + dx);
    size_t abase = (size_t)img*aImgStride + ((size_t)row*pitchIn + col)*csIn + coIn + q*8;
    const u16t* ap0 = A0 + abase;
    const u16t* bp = Bp + ((size_t)(tap*KCtot)*NTtot + ntOff)*512 + lane*8;
    #pragma unroll
    for (int kc = 0; kc < KC; ++kc){
      short8 av0 = *(const short8*)(ap0 + kc*32);
      #pragma unroll
      for (int nt = 0; nt < NT; ++nt){
        short8 bv = *(const short8*)(bp + (size_t)(kc*NTtot + nt)*512);
        acc[nt] = __builtin_amdgcn_mfma_f32_16x16x32_bf16(av0, bv, acc[nt], 0, 0, 0);
      }
    }
  }
  const int prow0 = q*4;
  #pragma unroll
  for (int nt = 0; nt < NT; ++nt){
    int o = (ntOff + nt)*16 + m;
    if (o >= Cout) continue;
    float bv = bias[o];
    #pragma unroll
    for (int r = 0; r < 4; ++r){
      int px = xs + prow0 + r;
      if (px >= Wout) continue;
      float v = acc[nt][r] + bv;
      if (ACT) v = fmaxf(v, 0.f);
      if (OMODE == 0){
        outf[((size_t)img*Cout + o)*((size_t)Wout*Wout) + (size_t)y*Wout + px] = v;
      } else if (OMODE == 1){
        outb[(size_t)img*outImgStride + ((size_t)(y+1)*pitchOut + px+1)*csOut + coOut + o] = f2b(v);
      } else {
        outb[(size_t)img*outImgStride + ((size_t)y*pitchOut + px)*csOut + coOut + o] = f2b(v);
      }
    }
  }
}

// ---------- gating + flow-warp, channels-last bf16, XCD-banded ----------
// grid (144, 4): blockIdx.y = channel quarter (16 ch); all 7 t per thread.
// Warp-tap addresses depend only on pixel; only mv reads are duplicated (~2 MB x4).
__global__ __launch_bounds__(256) void gate_nhwc(
    const u16t* __restrict__ fpad, const u16t* __restrict__ pred,
    const float* __restrict__ mv, u16t* __restrict__ spad)
{
  int bid = blockIdx.x;
  int cq = blockIdx.y;           // channel quarter: ch [cq*16, cq*16+16)
  int xcd = bid & 7, lb = bid >> 3;
  int idx = (xcd*18 + lb)*256 + threadIdx.x;
  int y = idx/IMW, x = idx%IMW;
  size_t pc = ((size_t)(y+1)*PDIM + (x+1))*448;
  const int co = cq*16;
  const u16t* rp = fpad + pc + 192 + co;
  short8 r8[2];
  #pragma unroll
  for (int c8 = 0; c8 < 2; ++c8) r8[c8] = *(const short8*)(rp + c8*8);
  #pragma unroll 1
  for (int t = 0; t < 7; ++t){
    const u16t* pp = pred + ((size_t)t*HWF + idx)*64 + co;
    u16t* sp = spad + pc + (size_t)t*64 + co;
    const u16t* tp[4]; float tw[4];
    if (t == 0){
      tp[0] = fpad + pc + co; tw[0] = 1.f;
      tp[1] = tp[2] = tp[3] = tp[0]; tw[1] = tw[2] = tw[3] = 0.f;
    } else {
      float fx = mv[(((size_t)(t-1)*HWF + idx))*2 + 0];
      float fy = mv[(((size_t)(t-1)*HWF + idx))*2 + 1];
      float ys = (float)y + fy, xsf = (float)x + fx;
      float y0f = floorf(ys), x0f = floorf(xsf);
      float wy = ys - y0f, wx = xsf - x0f;
      int y0 = (int)y0f, x0i = (int)x0f;
      int kk = 0;
      #pragma unroll
      for (int dy2 = 0; dy2 < 2; ++dy2)
        #pragma unroll
        for (int dx2 = 0; dx2 < 2; ++dx2){
          int yi = y0+dy2, xi = x0i+dx2;
          float wv = (dy2 ? wy : 1.f-wy)*(dx2 ? wx : 1.f-wx);
          bool ok = (yi >= 0 && yi <= 191 && xi >= 0 && xi <= 191);
          int yc = min(max(yi,0),191), xc = min(max(xi,0),191);
          tp[kk] = fpad + ((size_t)(yc+1)*PDIM + xc+1)*448 + (size_t)(t-1)*64 + co;
          tw[kk] = ok ? wv : 0.f;
          ++kk;
        }
    }
    #pragma unroll
    for (int c8 = 0; c8 < 2; ++c8){
      short8 pv = *(const short8*)(pp + c8*8);
      short8 t0v = *(const short8*)(tp[0] + c8*8);
      short8 t1v = *(const short8*)(tp[1] + c8*8);
      short8 t2v = *(const short8*)(tp[2] + c8*8);
      short8 t3v = *(const short8*)(tp[3] + c8*8);
      short8 ov;
      #pragma unroll
      for (int j = 0; j < 8; ++j){
        float r = b2f((u16t)r8[c8][j]);
        float p = b2f((u16t)pv[j]);
        float a = tw[0]*b2f((u16t)t0v[j]) + tw[1]*b2f((u16t)t1v[j])
                + tw[2]*b2f((u16t)t2v[j]) + tw[3]*b2f((u16t)t3v[j]);
        float sv = a*sigmoidf(a*r) + p*sigmoidf(p*r);
        ov[j] = (short)f2b(sv);
      }
      *(short8*)(sp + c8*8) = ov;
    }
  }
}

// ---------------- convT 4x4 s2 p1 (+relu): parity-decomposed, fp32 in, bf16 NHWC out ----------------
__global__ __launch_bounds__(256) void convT_tile2(
    const float* __restrict__ in, const float* __restrict__ wp,
    const float* __restrict__ bias, u16t* __restrict__ outb,
    int Hin, int tilesX, int pitchOut, int csOut, int coOut)
{
  const int CC = 4;
  __shared__ float sIn[CC][10*11];
  __shared__ float sW[16][CC][4][4];
  const int Win = Hin;
  const int o0 = blockIdx.x*16;
  const int tile = blockIdx.y;
  const int ty0 = (tile/tilesX)*16, tx0 = (tile%tilesX)*16;
  const int tid = threadIdx.x;
  const int py = tid>>4, px = tid&15;
  const int ry = py&1, rx = px&1, par = ry*2 + rx;
  const int lr = py>>1, lc = px>>1;
  const int r0 = ty0>>1, c0 = tx0>>1;
  float acc[16] = {};
  for (int ib = 0; ib < 64; ib += CC){
    for (int i = tid; i < CC*100; i += 256){
      int c = i/100, rem = i%100, r = rem/10, col = rem%10;
      int gy = r0 - 1 + r, gx = c0 - 1 + col;
      float v = 0.f;
      if (gy >= 0 && gy < Hin && gx >= 0 && gx < Win)
        v = in[(size_t)(ib + c)*Hin*Win + gy*Win + gx];
      sIn[c][r*11 + col] = v;
    }
    for (int i = tid; i < 1024; i += 256){
      int ol = i >> 6, rem = i & 63, ci = rem >> 4, p2 = (rem >> 2) & 3, j = rem & 3;
      sW[ol][ci][p2][j] = wp[((size_t)((p2*64 + o0 + ol)*64) + ib + ci)*4 + j];
    }
    __syncthreads();
    #pragma unroll
    for (int ci = 0; ci < CC; ++ci){
      int rb = lr + ry, cb = lc + rx;
      float t00 = sIn[ci][rb*11 + cb],     t01 = sIn[ci][rb*11 + cb + 1];
      float t10 = sIn[ci][(rb+1)*11 + cb], t11 = sIn[ci][(rb+1)*11 + cb + 1];
      #pragma unroll
      for (int ol = 0; ol < 16; ++ol){
        const float* wv = &sW[ol][ci][par][0];
        acc[ol] += t00*wv[0] + t01*wv[1] + t10*wv[2] + t11*wv[3];
      }
    }
    __syncthreads();
  }
  int gy = ty0 + py, gx = tx0 + px;
  u16t* op = outb + ((size_t)(gy+1)*pitchOut + gx+1)*csOut + coOut + o0;
  short8 pa, pb;
  #pragma unroll
  for (int i = 0; i < 8; ++i) pa[i] = (short)f2b(fmaxf(acc[i] + bias[o0+i], 0.f));
  #pragma unroll
  for (int i = 0; i < 8; ++i) pb[i] = (short)f2b(fmaxf(acc[8+i] + bias[o0+8+i], 0.f));
  *(short8*)op = pa;
  *(short8*)(op + 8) = pb;
}

// ---------------- deformable conv ----------------
__global__ __launch_bounds__(256) void deform_sample_k(
    const float* __restrict__ lqs, const float* __restrict__ om,
    float* __restrict__ vbuf)
{
  int idx = blockIdx.x*256 + threadIdx.x;
  int g = blockIdx.y;
  int h = idx / IMW, x = idx % IMW;
  const float* img = lqs + (size_t)g*HWF;
  #pragma unroll
  for (int k = 0; k < 9; ++k){
    int j = g*9 + k;
    float offy = om[(size_t)(j*2 + 0)*HWF + idx];
    float offx = om[(size_t)(j*2 + 1)*HWF + idx];
    float m = sigmoidf(om[(size_t)(126 + j)*HWF + idx]);
    float ys = (float)(h + (k/3) - 1) + offy;
    float xs = (float)(x + (k%3) - 1) + offx;
    vbuf[(size_t)j*HWF + idx] = bilin(img, ys, xs, IMH, IMW) * m;
  }
}

__global__ __launch_bounds__(256) void deform_out_k(
    const float* __restrict__ vbuf, const float* __restrict__ dcw,
    const float* __restrict__ dcb, float* __restrict__ out)
{
  __shared__ float sw[16*63];
  int idx = blockIdx.x*256 + threadIdx.x;
  int o0 = blockIdx.y*16;
  for (int i = threadIdx.x; i < 16*63; i += 256)
    sw[i] = dcw[(size_t)o0*63 + i];
  __syncthreads();
  float v[63];
  #pragma unroll
  for (int j = 0; j < 63; ++j) v[j] = vbuf[(size_t)j*HWF + idx];
  for (int ol = 0; ol < 16; ++ol){
    float acc = dcb[o0 + ol];
    #pragma unroll
    for (int j = 0; j < 63; ++j) acc += v[j]*sw[ol*63 + j];
    out[(size_t)(o0 + ol)*HWF + idx] = fmaxf(acc, 0.f);
  }
}

extern "C" void kernel_launch(void* const* d_in, const int* in_sizes, int n_in,
                              void* d_out, int out_size, void* d_ws, size_t ws_size,
                              hipStream_t stream)
{
  const float* lqs   = (const float*)d_in[0];
  const float* preds = (const float*)d_in[1];
  const float* mv    = (const float*)d_in[2];
  const float* bw1   = (const float*)d_in[3];
  const float* bb1   = (const float*)d_in[4];
  const float* bw2   = (const float*)d_in[5];
  const float* bb2   = (const float*)d_in[6];
  const float* dn1w  = (const float*)d_in[7];
  const float* dn1b  = (const float*)d_in[8];
  const float* dn2w  = (const float*)d_in[9];
  const float* dn2b  = (const float*)d_in[10];
  const float* up1cw = (const float*)d_in[11];
  const float* up1cb = (const float*)d_in[12];
  const float* up1tw = (const float*)d_in[13];
  const float* up1tb = (const float*)d_in[14];
  const float* up2cw = (const float*)d_in[15];
  const float* up2cb = (const float*)d_in[16];
  const float* up2tw = (const float*)d_in[17];
  const float* up2tb = (const float*)d_in[18];
  const float* trcw  = (const float*)d_in[19];
  const float* trcb  = (const float*)d_in[20];
  const float* trtw  = (const float*)d_in[21];
  const float* trtb  = (const float*)d_in[22];
  const float* ffw   = (const float*)d_in[23];
  const float* ffb   = (const float*)d_in[24];
  const float* omw   = (const float*)d_in[25];
  const float* omb   = (const float*)d_in[26];
  const float* dcw   = (const float*)d_in[27];
  const float* dcb   = (const float*)d_in[28];
  float* outp = (float*)d_out;

  char* p = (char*)d_ws;
  const size_t PIMG64 = (size_t)PDIM*PDIM*64;
  u16t* spadreg  = (u16t*)p; p += 14*PIMG64*2;                // spad [194][194][448]; later featfpad
  u16t* fpad     = (u16t*)p; p += (size_t)PDIM*PDIM*448*2;    // feat NHWC448; later vbuf (fp32)
  u16t* prednhwc = (u16t*)p; p += (size_t)7*HWF*64*2;         // pred NHWC64; later om (fp32)
  u16t* out0pad  = (u16t*)p; p += (size_t)PDIM*PDIM*64*2;
  u16t* cat1pad  = (u16t*)p; p += (size_t)98*98*128*2;
  u16t* cat2pad  = (u16t*)p; p += (size_t)50*50*128*2;
  float* t0      = (float*)p; p += (size_t)24*24*64*4;
  float* u2      = (float*)p; p += (size_t)48*48*64*4;
  float* u1      = (float*)p; p += (size_t)96*96*64*4;
  u16t* ffwpack  = (u16t*)p; p += 258048*2;
  u16t* c2pack   = (u16t*)p; p += 36864*2;
  u16t* ompack   = (u16t*)p; p += 110592*2;
  u16t* dn1pack  = (u16t*)p; p += 36864*2;
  u16t* dn2pack  = (u16t*)p; p += 36864*2;
  u16t* trcpack  = (u16t*)p; p += 36864*2;
  u16t* up2cpack = (u16t*)p; p += 73728*2;
  u16t* up1cpack = (u16t*)p; p += 73728*2;
  float* wp0     = (float*)p; p += 65536*4;
  float* wp1     = (float*)p; p += 65536*4;
  float* wp2     = (float*)p; p += 65536*4;

  u16t* spad = spadreg;
  u16t* featfpad = spadreg;
  float* om = (float*)prednhwc;
  float* vbuf = (float*)fpad;

  dim3 blk(256);
  // setup
  PkD8 pk = {{ {ffw, ffwpack, 448, 64, 4, 258048}, {bw2, c2pack, 64, 64, 4, 36864},
               {omw, ompack, 64, 189, 12, 110592}, {dn1w, dn1pack, 64, 64, 4, 36864},
               {dn2w, dn2pack, 64, 64, 4, 36864},  {trcw, trcpack, 64, 64, 4, 36864},
               {up2cw, up2cpack, 128, 64, 4, 73728}, {up1cw, up1cpack, 128, 64, 4, 73728} }};
  pack_all<<<dim3(1008,8), blk, 0, stream>>>(pk);
  RpD3 rp3 = {{ {trtw, wp0}, {up2tw, wp1}, {up1tw, wp2} }};
  repack_all<<<dim3(64,3), blk, 0, stream>>>(rp3);
  PzD5 pz = {{ {spad, 448, PDIM, 1, 0}, {fpad, 448, PDIM, 1, 0},
               {out0pad, 64, PDIM, 1, 0}, {cat1pad, 128, 98, 1, 0}, {cat2pad, 128, 50, 1, 0} }};
  padzero_all<<<dim3(2704,5), blk, 0, stream>>>(pz);
  // fused backbone (conv1 scalar-weight FMA + conv2 MFMA, no HBM intermediate)
  bbfused<<<dim3(8064), blk, 0, stream>>>(lqs, preds, bw1, bb1, c2pack, bb2, fpad, prednhwc);
  // gate (+warp) -> spad (channel-quartered for occupancy)
  gate_nhwc<<<dim3(144,4), blk, 0, stream>>>(fpad, prednhwc, mv, spad);
  // fused dual conv -> out0pad
  cgemm<2,14,4,4,1><<<dim3(576,1), blk, 0, stream>>>(spad, fpad, ffwpack, ffb,
      nullptr, out0pad, nullptr, 64, 576, PDIM, 448, 0, 14);
  // U-Net (NT=1 o-splits for occupancy)
  gconv3<1,2,2,1,1,1><<<dim3(144,4), blk, 0, stream>>>(out0pad, dn1pack, dn1b, nullptr, cat1pad,
      64, 96, 6, 144, PDIM, 64, 0, 0, 0, 98, 128, 64, 2, 4);       // out1 -> cat1[64:]
  gconv3<1,2,2,1,1,0><<<dim3(36,4), blk, 0, stream>>>(cat1pad, dn2pack, dn2b, nullptr, cat2pad,
      64, 48, 3, 36, 98, 128, 64, 0, 0, 50, 128, 64, 2, 4);        // out2 -> cat2[64:]
  gconv3<1,2,2,0,1,0><<<dim3(12,4), blk, 0, stream>>>(cat2pad, trcpack, trcb, t0, nullptr,
      64, 24, 2, 12, 50, 128, 64, 0, 0, 0, 0, 0, 2, 4);            // t0 (fp32 NCHW)
  convT_tile2<<<dim3(4,9), blk, 0, stream>>>(t0, wp0, trtb, cat2pad, 24, 3, 50, 128, 0);   // t1 -> cat2[:64]
  gconv3<1,4,1,0,1,0><<<dim3(36,4), blk, 0, stream>>>(cat2pad, up2cpack, up2cb, u2, nullptr,
      64, 48, 3, 36, 50, 128, 0, 0, 0, 0, 0, 0, 4, 4);             // u2 (fp32 NCHW)
  convT_tile2<<<dim3(4,36), blk, 0, stream>>>(u2, wp1, up2tb, cat1pad, 48, 6, 98, 128, 0); // u2t -> cat1[:64]
  gconv3<1,4,1,0,1,1><<<dim3(144,4), blk, 0, stream>>>(cat1pad, up1cpack, up1cb, u1, nullptr,
      64, 96, 6, 144, 98, 128, 0, 0, 0, 0, 0, 0, 4, 4);            // u1 (fp32 NCHW)
  // final convT -> featfpad
  padzero2<<<dim3(194), blk, 0, stream>>>(featfpad, 64, PDIM);
  convT_tile2<<<dim3(4,144), blk, 0, stream>>>(u1, wp2, up1tb, featfpad, 96, 12, PDIM, 64, 0);
  // offsets/masks conv (64 -> 189)
  cgemm<1,2,5,12,1><<<dim3(576,3), blk, 0, stream>>>(featfpad, nullptr, ompack, omb,
      om, nullptr, nullptr, 189, 576, PDIM, 64, 0, 2);
  // deformable conv
  deform_sample_k<<<dim3(144,7), blk, 0, stream>>>(lqs, om, vbuf);
  deform_out_k<<<dim3(144,4), blk, 0, stream>>>(vbuf, dcw, dcb, outp);
}

// Round 13
// 566.821 us; speedup vs baseline: 1.1164x; 1.0008x over previous
//
#include <hip/hip_runtime.h>
#include <math.h>

#define IMH 192
#define IMW 192
#define HWF 36864
#define PDIM 194

typedef unsigned short u16t;
typedef __attribute__((ext_vector_type(8))) short short8;
typedef __attribute__((ext_vector_type(4))) float f32x4;

__device__ __forceinline__ float sigmoidf(float x){ return 1.f/(1.f+expf(-x)); }
__device__ __forceinline__ float lrelu(float x){ return x > 0.f ? x : 0.1f*x; }
__device__ __forceinline__ float b2f(u16t h){ unsigned u = ((unsigned)h)<<16; return __uint_as_float(u); }
__device__ __forceinline__ u16t f2b(float f){
  unsigned u = __float_as_uint(f);
  u += 0x7FFFu + ((u>>16)&1u);
  return (u16t)(u>>16);
}

__device__ __forceinline__ float bilin(const float* __restrict__ img, float ys, float xs, int H, int W){
  float y0f = floorf(ys), x0f = floorf(xs);
  float wy = ys - y0f, wx = xs - x0f;
  int y0 = (int)y0f, x0 = (int)x0f;
  float acc = 0.f;
  #pragma unroll
  for (int dy=0; dy<2; ++dy){
    int yi = y0+dy;
    float wyv = dy ? wy : 1.f-wy;
    if (yi < 0 || yi >= H) continue;
    #pragma unroll
    for (int dx=0; dx<2; ++dx){
      int xi = x0+dx;
      float wxv = dx ? wx : 1.f-wx;
      if (xi < 0 || xi >= W) continue;
      acc += img[yi*W+xi]*(wyv*wxv);
    }
  }
  return acc;
}

// ================= descriptor-driven setup kernels =================
struct PkD { const float* w; u16t* dst; int Cin, Cout, NT, total; };
struct PkD8 { PkD d[8]; };
__global__ __launch_bounds__(256) void pack_all(PkD8 ds){
  PkD d = ds.d[blockIdx.y];
  int id = blockIdx.x*256 + threadIdx.x;
  if (id >= d.total) return;
  int j = id & 7, l = (id>>3) & 63;
  int r = id >> 9;
  int nt = r % d.NT; r /= d.NT;
  int KC = d.Cin >> 5;
  int kc = r % KC; int tap = r / KC;
  int c = kc*32 + ((l>>4)<<3) + j;
  int o = nt*16 + (l&15);
  float v = (o < d.Cout) ? d.w[((size_t)o*d.Cin + c)*9 + tap] : 0.f;
  d.dst[id] = f2b(v);
}

// conv1 weights (64,1,3,3) -> MFMA B-frag, K padded 9->32: [nt][lane][8]
__global__ __launch_bounds__(256) void pack_w1(const float* __restrict__ w1, u16t* __restrict__ dst){
  int id = blockIdx.x*256 + threadIdx.x;   // 2048
  int j = id & 7, l = (id>>3) & 63, nt = id >> 9;
  int o = nt*16 + (l&15);
  int k = ((l>>4)<<3) + j;
  float v = (k < 9) ? w1[o*9 + k] : 0.f;
  dst[id] = f2b(v);
}

struct RpD { const float* w; float* wp; };
struct RpD3 { RpD d[3]; };
__global__ __launch_bounds__(256) void repack_all(RpD3 ds){
  RpD d = ds.d[blockIdx.y];
  int id = blockIdx.x*256 + threadIdx.x;
  int par = id >> 12, o = (id >> 6) & 63, i = id & 63;
  int ry = par >> 1, rx = par & 1;
  #pragma unroll
  for (int jy = 0; jy < 2; ++jy)
    #pragma unroll
    for (int jx = 0; jx < 2; ++jx){
      int ka = 3 - ry - 2*jy, kb = 3 - rx - 2*jx;
      d.wp[((size_t)((par*64 + o)*64 + i))*4 + jy*2 + jx] = d.w[((size_t)(i*64 + o))*16 + ka*4 + kb];
    }
}

struct PzD { u16t* buf; int C, dim, nimg; size_t stride; };
struct PzD5 { PzD d[5]; };
__global__ __launch_bounds__(256) void padzero_all(PzD5 ds){
  PzD d = ds.d[blockIdx.y];
  int per = (4*d.dim - 4)*d.C;
  long total = (long)per*d.nimg;
  for (long id = (long)blockIdx.x*256 + threadIdx.x; id < total; id += (long)gridDim.x*256){
    int n = (int)(id / per), c2 = (int)(id % per);
    int cell = c2 / d.C, c = c2 % d.C;
    int d2 = d.dim - 1;
    int r, col;
    if (cell < d.dim){ r = 0; col = cell; }
    else if (cell < 2*d.dim){ r = d2; col = cell - d.dim; }
    else if (cell < 3*d.dim - 2){ r = cell - 2*d.dim + 1; col = 0; }
    else { r = cell - (3*d.dim - 2) + 1; col = d2; }
    d.buf[(size_t)n*d.stride + ((size_t)r*d.dim + col)*d.C + c] = 0;
  }
}

__global__ __launch_bounds__(256) void padzero2(u16t* buf, int C, int dim){
  int total = (4*dim - 4)*C;
  for (int id = blockIdx.x*256 + threadIdx.x; id < total; id += gridDim.x*256){
    int cell = id / C, c = id % C;
    int d2 = dim - 1;
    int r, col;
    if (cell < dim){ r = 0; col = cell; }
    else if (cell < 2*dim){ r = d2; col = cell - dim; }
    else if (cell < 3*dim - 2){ r = cell - 2*dim + 1; col = 0; }
    else { r = cell - (3*dim - 2) + 1; col = d2; }
    buf[((size_t)r*dim + col)*C + c] = 0;
  }
}

// ========== fused backbone: conv1 (1->64, MFMA via LDS K-layout) + conv2 (64->64, MFMA) ==========
// Block = 4-row x 16-px x 64-ch conv2-output tile.
// Phase 0: stage 8x20 raw fp32 input in LDS.
// Phase 1: ~108 threads build sK[px][16] = 9 bf16 taps (k-padded zeros; rows 108-112 zero).
// Phase 2: wave = 16-ch group (B-frag w1pack in regs); 7 MFMAs (one per 16-px tile),
//          A = 1 ds_read_b128/lane (q>=2 reads the zero row); bias+f2b -> swizzled sA.
//          Border zeroing only on edge blocks (wave-uniform branch).
// conv2 MFMA from sA. img<7 -> fpad NHWC448 padded, else prednhwc tight.
__global__ __launch_bounds__(256) void bbfused(
    const float* __restrict__ lqs, const float* __restrict__ preds,
    const u16t* __restrict__ w1pack, const float* __restrict__ b1,
    const u16t* __restrict__ Bp, const float* __restrict__ b2,
    u16t* __restrict__ fpad, u16t* __restrict__ prednhwc)
{
  __shared__ float sIn1[8][20];
  __shared__ u16t sK[113*16];     // per-pixel K-vectors; row 112 = zeros (q>=2 source)
  __shared__ u16t sA[112*64];     // feat1 tile (swizzled); rows 108-111 = scratch
  int bid = blockIdx.x;
  bid = (bid & 7)*(gridDim.x >> 3) + (bid >> 3);       // XCD banding
  const int tid = threadIdx.x;
  const int img = bid / 576;
  const int rem = bid - img*576;
  const int y0 = (rem/12)*4, xs = (rem%12)*16;
  const float* ip = (img < 7) ? (lqs + (size_t)img*HWF) : (preds + (size_t)(img-7)*HWF);
  for (int u = tid; u < 160; u += 256){
    int lr = u/20, lc = u%20;
    int iy = y0 - 2 + lr, ix = xs - 2 + lc;
    sIn1[lr][lc] = (iy >= 0 && iy < IMH && ix >= 0 && ix < IMW) ? ip[iy*IMW + ix] : 0.f;
  }
  const int wave = tid >> 6, lane = tid & 63;
  const int m = lane & 15, q = lane >> 4;
  // conv1 B-frag + bias (wave = channel group), loaded while staging completes
  short8 w1f = *(const short8*)(w1pack + (size_t)wave*512 + lane*8);
  float c1b = b1[wave*16 + m];
  __syncthreads();
  // ---- phase 1: build sK ----
  if (tid < 113){
    int px = tid;
    short8 lo = (short8){0,0,0,0,0,0,0,0};
    short8 hi = (short8){0,0,0,0,0,0,0,0};
    if (px < 108){
      int rr = px/18, cc = px%18;
      #pragma unroll
      for (int k = 0; k < 8; ++k) lo[k] = (short)f2b(sIn1[rr + k/3][cc + k%3]);
      hi[0] = (short)f2b(sIn1[rr + 2][cc + 2]);
    }
    *(short8*)&sK[px*16] = lo;
    *(short8*)&sK[px*16 + 8] = hi;
  }
  if (tid == 113){
    short8 z = (short8){0,0,0,0,0,0,0,0};
    *(short8*)&sK[112*16] = z;
    *(short8*)&sK[112*16 + 8] = z;
  }
  __syncthreads();
  // ---- phase 2: conv1 MFMA -> sA ----
  {
    const bool edgeBlk = (y0 == 0) | (y0 == 188) | (xs == 0) | (xs == 176);
    const int g = wave*2 + (m >> 3);
    const int ol = m & 7;
    #pragma unroll
    for (int tile = 0; tile < 7; ++tile){
      const u16t* ap = (q < 2) ? &sK[(tile*16 + m)*16 + q*8] : &sK[112*16];
      short8 av = *(const short8*)ap;
      f32x4 z = {0.f,0.f,0.f,0.f};
      f32x4 d = __builtin_amdgcn_mfma_f32_16x16x32_bf16(av, w1f, z, 0, 0, 0);
      if (edgeBlk){
        #pragma unroll
        for (int r = 0; r < 4; ++r){
          int pxo = tile*16 + q*4 + r;
          if (pxo >= 108) continue;
          int rr2 = pxo/18, cc2 = pxo%18;
          int pr = y0 + rr2, pc = xs + cc2;
          bool border = (pr == 0) | (pr == 193) | (pc == 0) | (pc == 193);
          u16t hv = border ? (u16t)0 : f2b(d[r] + c1b);
          sA[(size_t)pxo*64 + ((g + pxo)&7)*8 + ol] = hv;
        }
      } else {
        #pragma unroll
        for (int r = 0; r < 4; ++r){
          int pxo = tile*16 + q*4 + r;   // pxo in [0,112): rows >=108 are scratch
          sA[(size_t)pxo*64 + ((g + pxo)&7)*8 + ol] = f2b(d[r] + c1b);
        }
      }
    }
  }
  __syncthreads();
  // ---- conv2 MFMA from sA ----
  const int rp = wave >> 1, np = wave & 1;
  f32x4 acc[2][2];
  #pragma unroll
  for (int r = 0; r < 2; ++r)
    #pragma unroll
    for (int n = 0; n < 2; ++n) acc[r][n] = (f32x4){0.f,0.f,0.f,0.f};
  #pragma unroll
  for (int kc = 0; kc < 2; ++kc){
    #pragma unroll
    for (int tap = 0; tap < 9; ++tap){
      const int dy = tap/3, dx = tap%3;
      short8 af[2];
      #pragma unroll
      for (int r = 0; r < 2; ++r){
        int px = (2*rp + r + dy)*18 + dx + m;
        af[r] = *(const short8*)&sA[(size_t)px*64 + ((kc*4 + q + px)&7)*8];
      }
      const u16t* bp = Bp + ((size_t)(tap*2 + kc)*4 + np*2)*512 + lane*8;
      short8 b0 = *(const short8*)bp;
      short8 b1w = *(const short8*)(bp + 512);
      #pragma unroll
      for (int r = 0; r < 2; ++r){
        acc[r][0] = __builtin_amdgcn_mfma_f32_16x16x32_bf16(af[r], b0, acc[r][0], 0, 0, 0);
        acc[r][1] = __builtin_amdgcn_mfma_f32_16x16x32_bf16(af[r], b1w, acc[r][1], 0, 0, 0);
      }
    }
  }
  const int px0 = q*4;
  #pragma unroll
  for (int r = 0; r < 2; ++r){
    int yout = y0 + 2*rp + r;
    #pragma unroll
    for (int n = 0; n < 2; ++n){
      int oL = (np*2 + n)*16 + m;
      float bv = b2[oL];
      #pragma unroll
      for (int g2 = 0; g2 < 4; ++g2){
        int px = xs + px0 + g2;
        float v = acc[r][n][g2] + bv;
        if (img < 7)
          fpad[((size_t)(yout+1)*PDIM + px+1)*448 + (size_t)img*64 + oL] = f2b(v);
        else
          prednhwc[(size_t)(img-7)*((size_t)HWF*64) + ((size_t)yout*IMW + px)*64 + oL] = f2b(v);
      }
    }
  }
}

// ========== LDS-staged MFMA implicit-GEMM 3x3 stride-1 conv (swizzled sA, stride 32) ==========
template<int STREAMS, int KC, int OMODE, int NTT, int SWZ>
__global__ __launch_bounds__(256) void cgemm(
    const u16t* __restrict__ A0, const u16t* __restrict__ A1,
    const u16t* __restrict__ Bp, const float* __restrict__ bias,
    float* __restrict__ outf, u16t* __restrict__ outb, u16t* __restrict__ outb2,
    int Cout, int blocksPerImg, int pitchIn, int csIn, size_t aImgStride, int KCtot)
{
  __shared__ u16t sA[STREAMS*108*32];
  int bid = blockIdx.x;
  if (SWZ) bid = (bid & 7)*(gridDim.x >> 3) + (bid >> 3);
  const int tid = threadIdx.x;
  const int wave = tid >> 6, lane = tid & 63;
  const int m = lane & 15, q = lane >> 4;
  const int img = bid / blocksPerImg;
  const int rem = bid - img*blocksPerImg;
  const int y0 = (rem/12)*4, xs = (rem%12)*16;
  const int rp = wave >> 1, np = wave & 1;
  const int ntB = (OMODE == 5) ? blockIdx.y*4 : 0;
  f32x4 acc[STREAMS][2][2];
  #pragma unroll
  for (int s = 0; s < STREAMS; ++s)
    #pragma unroll
    for (int r = 0; r < 2; ++r)
      #pragma unroll
      for (int n = 0; n < 2; ++n) acc[s][r][n] = (f32x4){0.f,0.f,0.f,0.f};

  #pragma unroll 1
  for (int kc = 0; kc < KC; ++kc){
    if (kc) __syncthreads();
    for (int u = tid; u < STREAMS*216; u += 256){
      int st = u/216, r2 = u%216, p = r2>>1, h = r2&1;
      int rr = p/18, cc = p%18;
      size_t ga = (size_t)img*aImgStride + ((size_t)(y0+rr)*pitchIn + xs+cc)*csIn + kc*32 + h*16;
      const u16t* gp = ((STREAMS==2 && st==1) ? A1 : A0) + ga;
      short8 v0 = *(const short8*)gp;
      short8 v1 = *(const short8*)(gp + 8);
      u16t* base = &sA[((size_t)(st*108 + p))*32];
      *(short8*)(base + ((2*h + p)&3)*8) = v0;
      *(short8*)(base + ((2*h + 1 + p)&3)*8) = v1;
    }
    __syncthreads();
    #pragma unroll
    for (int tap = 0; tap < 9; ++tap){
      const int dy = tap/3, dx = tap%3;
      short8 af[STREAMS][2];
      #pragma unroll
      for (int st = 0; st < STREAMS; ++st)
        #pragma unroll
        for (int r = 0; r < 2; ++r){
          int px = (2*rp + r + dy)*18 + dx + m;
          af[st][r] = *(const short8*)&sA[((size_t)(st*108 + px))*32 + ((q + px)&3)*8];
        }
      const u16t* bp = Bp + ((size_t)(tap*KCtot + kc)*NTT + ntB + np*2)*512 + lane*8;
      short8 b0 = *(const short8*)bp;
      short8 b1 = *(const short8*)(bp + 512);
      #pragma unroll
      for (int st = 0; st < STREAMS; ++st)
        #pragma unroll
        for (int r = 0; r < 2; ++r){
          acc[st][r][0] = __builtin_amdgcn_mfma_f32_16x16x32_bf16(af[st][r], b0, acc[st][r][0], 0, 0, 0);
          acc[st][r][1] = __builtin_amdgcn_mfma_f32_16x16x32_bf16(af[st][r], b1, acc[st][r][1], 0, 0, 0);
        }
    }
  }
  const int px0 = q*4;
  #pragma unroll
  for (int r = 0; r < 2; ++r){
    int yout = y0 + 2*rp + r;
    #pragma unroll
    for (int n = 0; n < 2; ++n){
      int oL = (np*2 + n)*16 + m;
      if (OMODE == 4){
        float bv = bias[oL];
        #pragma unroll
        for (int g = 0; g < 4; ++g){
          int px = xs + px0 + g;
          float v = 0.1f*lrelu(acc[0][r][n][g] + bv) + lrelu(acc[1][r][n][g] + bv);
          outb[((size_t)(yout+1)*PDIM + px+1)*64 + oL] = f2b(v);
        }
      } else {
        int o = ntB*16 + oL;
        if (o < Cout){
          float bv = bias[o];
          #pragma unroll
          for (int g = 0; g < 4; ++g){
            int px = xs + px0 + g;
            outf[(size_t)o*HWF + (size_t)yout*IMW + px] = acc[0][r][n][g] + bv;
          }
        }
      }
    }
  }
}

// ---------- no-LDS MFMA implicit-GEMM (U-Net smalls); blockIdx.y = o-group of NT ----------
template<int NT, int KC, int STRIDE, int OMODE, int ACT, int SWZ>
__global__ __launch_bounds__(256) void gconv3(
    const u16t* __restrict__ A0, const u16t* __restrict__ Bp, const float* __restrict__ bias,
    float* __restrict__ outf, u16t* __restrict__ outb,
    int Cout, int Wout, int strips, int blocksPerImg,
    int pitchIn, int csIn, int coIn, size_t aImgStride,
    size_t outImgStride, int pitchOut, int csOut, int coOut,
    int KCtot, int NTtot)
{
  int bid = blockIdx.x;
  if (SWZ) bid = (bid & 7)*(gridDim.x >> 3) + (bid >> 3);
  const int wave = threadIdx.x >> 6;
  const int lane = threadIdx.x & 63;
  const int img = bid / blocksPerImg;
  const int sid = (bid - img*blocksPerImg)*4 + wave;
  const int y = sid / strips, xs = (sid % strips) * 16;
  const int m = lane & 15, q = lane >> 4;
  const int ntOff = blockIdx.y*NT;
  f32x4 acc[NT];
  #pragma unroll
  for (int nt = 0; nt < NT; ++nt) acc[nt] = (f32x4){0.f,0.f,0.f,0.f};

  for (int tap = 0; tap < 9; ++tap){
    int dy = tap/3, dx = tap%3;
    int row = STRIDE*y + dy;
    int col = (STRIDE == 1) ? (xs + m + dx) : (2*(xs + m) + dx);
    size_t abase = (size_t)img*aImgStride + ((size_t)row*pitchIn + col)*csIn + coIn + q*8;
    const u16t* ap0 = A0 + abase;
    const u16t* bp = Bp + ((size_t)(tap*KCtot)*NTtot + ntOff)*512 + lane*8;
    #pragma unroll
    for (int kc = 0; kc < KC; ++kc){
      short8 av0 = *(const short8*)(ap0 + kc*32);
      #pragma unroll
      for (int nt = 0; nt < NT; ++nt){
        short8 bv = *(const short8*)(bp + (size_t)(kc*NTtot + nt)*512);
        acc[nt] = __builtin_amdgcn_mfma_f32_16x16x32_bf16(av0, bv, acc[nt], 0, 0, 0);
      }
    }
  }
  const int prow0 = q*4;
  #pragma unroll
  for (int nt = 0; nt < NT; ++nt){
    int o = (ntOff + nt)*16 + m;
    if (o >= Cout) continue;
    float bv = bias[o];
    #pragma unroll
    for (int r = 0; r < 4; ++r){
      int px = xs + prow0 + r;
      if (px >= Wout) continue;
      float v = acc[nt][r] + bv;
      if (ACT) v = fmaxf(v, 0.f);
      if (OMODE == 0){
        outf[((size_t)img*Cout + o)*((size_t)Wout*Wout) + (size_t)y*Wout + px] = v;
      } else if (OMODE == 1){
        outb[(size_t)img*outImgStride + ((size_t)(y+1)*pitchOut + px+1)*csOut + coOut + o] = f2b(v);
      } else {
        outb[(size_t)img*outImgStride + ((size_t)y*pitchOut + px)*csOut + coOut + o] = f2b(v);
      }
    }
  }
}

// ---------- gating + flow-warp, channels-last bf16, XCD-banded, channel-quartered ----------
__global__ __launch_bounds__(256) void gate_nhwc(
    const u16t* __restrict__ fpad, const u16t* __restrict__ pred,
    const float* __restrict__ mv, u16t* __restrict__ spad)
{
  int bid = blockIdx.x;
  int cq = blockIdx.y;           // channel quarter: ch [cq*16, cq*16+16)
  int xcd = bid & 7, lb = bid >> 3;
  int idx = (xcd*18 + lb)*256 + threadIdx.x;
  int y = idx/IMW, x = idx%IMW;
  size_t pc = ((size_t)(y+1)*PDIM + (x+1))*448;
  const int co = cq*16;
  const u16t* rp = fpad + pc + 192 + co;
  short8 r8[2];
  #pragma unroll
  for (int c8 = 0; c8 < 2; ++c8) r8[c8] = *(const short8*)(rp + c8*8);
  #pragma unroll 1
  for (int t = 0; t < 7; ++t){
    const u16t* pp = pred + ((size_t)t*HWF + idx)*64 + co;
    u16t* sp = spad + pc + (size_t)t*64 + co;
    const u16t* tp[4]; float tw[4];
    if (t == 0){
      tp[0] = fpad + pc + co; tw[0] = 1.f;
      tp[1] = tp[2] = tp[3] = tp[0]; tw[1] = tw[2] = tw[3] = 0.f;
    } else {
      float fx = mv[(((size_t)(t-1)*HWF + idx))*2 + 0];
      float fy = mv[(((size_t)(t-1)*HWF + idx))*2 + 1];
      float ys = (float)y + fy, xsf = (float)x + fx;
      float y0f = floorf(ys), x0f = floorf(xsf);
      float wy = ys - y0f, wx = xsf - x0f;
      int y0 = (int)y0f, x0i = (int)x0f;
      int kk = 0;
      #pragma unroll
      for (int dy2 = 0; dy2 < 2; ++dy2)
        #pragma unroll
        for (int dx2 = 0; dx2 < 2; ++dx2){
          int yi = y0+dy2, xi = x0i+dx2;
          float wv = (dy2 ? wy : 1.f-wy)*(dx2 ? wx : 1.f-wx);
          bool ok = (yi >= 0 && yi <= 191) && (xi >= 0 && xi <= 191);
          int yc = min(max(yi,0),191), xc = min(max(xi,0),191);
          tp[kk] = fpad + ((size_t)(yc+1)*PDIM + xc+1)*448 + (size_t)(t-1)*64 + co;
          tw[kk] = ok ? wv : 0.f;
          ++kk;
        }
    }
    #pragma unroll
    for (int c8 = 0; c8 < 2; ++c8){
      short8 pv = *(const short8*)(pp + c8*8);
      short8 t0v = *(const short8*)(tp[0] + c8*8);
      short8 t1v = *(const short8*)(tp[1] + c8*8);
      short8 t2v = *(const short8*)(tp[2] + c8*8);
      short8 t3v = *(const short8*)(tp[3] + c8*8);
      short8 ov;
      #pragma unroll
      for (int j = 0; j < 8; ++j){
        float r = b2f((u16t)r8[c8][j]);
        float p = b2f((u16t)pv[j]);
        float a = tw[0]*b2f((u16t)t0v[j]) + tw[1]*b2f((u16t)t1v[j])
                + tw[2]*b2f((u16t)t2v[j]) + tw[3]*b2f((u16t)t3v[j]);
        float sv = a*sigmoidf(a*r) + p*sigmoidf(p*r);
        ov[j] = (short)f2b(sv);
      }
      *(short8*)(sp + c8*8) = ov;
    }
  }
}

// ---------------- convT 4x4 s2 p1 (+relu): parity-decomposed, fp32 in, bf16 NHWC out ----------------
__global__ __launch_bounds__(256) void convT_tile2(
    const float* __restrict__ in, const float* __restrict__ wp,
    const float* __restrict__ bias, u16t* __restrict__ outb,
    int Hin, int tilesX, int pitchOut, int csOut, int coOut)
{
  const int CC = 4;
  __shared__ float sIn[CC][10*11];
  __shared__ float sW[16][CC][4][4];
  const int Win = Hin;
  const int o0 = blockIdx.x*16;
  const int tile = blockIdx.y;
  const int ty0 = (tile/tilesX)*16, tx0 = (tile%tilesX)*16;
  const int tid = threadIdx.x;
  const int py = tid>>4, px = tid&15;
  const int ry = py&1, rx = px&1, par = ry*2 + rx;
  const int lr = py>>1, lc = px>>1;
  const int r0 = ty0>>1, c0 = tx0>>1;
  float acc[16] = {};
  for (int ib = 0; ib < 64; ib += CC){
    for (int i = tid; i < CC*100; i += 256){
      int c = i/100, rem = i%100, r = rem/10, col = rem%10;
      int gy = r0 - 1 + r, gx = c0 - 1 + col;
      float v = 0.f;
      if (gy >= 0 && gy < Hin && gx >= 0 && gx < Win)
        v = in[(size_t)(ib + c)*Hin*Win + gy*Win + gx];
      sIn[c][r*11 + col] = v;
    }
    for (int i = tid; i < 1024; i += 256){
      int ol = i >> 6, rem = i & 63, ci = rem >> 4, p2 = (rem >> 2) & 3, j = rem & 3;
      sW[ol][ci][p2][j] = wp[((size_t)((p2*64 + o0 + ol)*64) + ib + ci)*4 + j];
    }
    __syncthreads();
    #pragma unroll
    for (int ci = 0; ci < CC; ++ci){
      int rb = lr + ry, cb = lc + rx;
      float t00 = sIn[ci][rb*11 + cb],     t01 = sIn[ci][rb*11 + cb + 1];
      float t10 = sIn[ci][(rb+1)*11 + cb], t11 = sIn[ci][(rb+1)*11 + cb + 1];
      #pragma unroll
      for (int ol = 0; ol < 16; ++ol){
        const float* wv = &sW[ol][ci][par][0];
        acc[ol] += t00*wv[0] + t01*wv[1] + t10*wv[2] + t11*wv[3];
      }
    }
    __syncthreads();
  }
  int gy = ty0 + py, gx = tx0 + px;
  u16t* op = outb + ((size_t)(gy+1)*pitchOut + gx+1)*csOut + coOut + o0;
  short8 pa, pb;
  #pragma unroll
  for (int i = 0; i < 8; ++i) pa[i] = (short)f2b(fmaxf(acc[i] + bias[o0+i], 0.f));
  #pragma unroll
  for (int i = 0; i < 8; ++i) pb[i] = (short)f2b(fmaxf(acc[8+i] + bias[o0+8+i], 0.f));
  *(short8*)op = pa;
  *(short8*)(op + 8) = pb;
}

// ---------------- deformable conv ----------------
__global__ __launch_bounds__(256) void deform_sample_k(
    const float* __restrict__ lqs, const float* __restrict__ om,
    float* __restrict__ vbuf)
{
  int idx = blockIdx.x*256 + threadIdx.x;
  int g = blockIdx.y;
  int h = idx / IMW, x = idx % IMW;
  const float* img = lqs + (size_t)g*HWF;
  #pragma unroll
  for (int k = 0; k < 9; ++k){
    int j = g*9 + k;
    float offy = om[(size_t)(j*2 + 0)*HWF + idx];
    float offx = om[(size_t)(j*2 + 1)*HWF + idx];
    float m = sigmoidf(om[(size_t)(126 + j)*HWF + idx]);
    float ys = (float)(h + (k/3) - 1) + offy;
    float xs = (float)(x + (k%3) - 1) + offx;
    vbuf[(size_t)j*HWF + idx] = bilin(img, ys, xs, IMH, IMW) * m;
  }
}

__global__ __launch_bounds__(256) void deform_out_k(
    const float* __restrict__ vbuf, const float* __restrict__ dcw,
    const float* __restrict__ dcb, float* __restrict__ out)
{
  __shared__ float sw[16*63];
  int idx = blockIdx.x*256 + threadIdx.x;
  int o0 = blockIdx.y*16;
  for (int i = threadIdx.x; i < 16*63; i += 256)
    sw[i] = dcw[(size_t)o0*63 + i];
  __syncthreads();
  float v[63];
  #pragma unroll
  for (int j = 0; j < 63; ++j) v[j] = vbuf[(size_t)j*HWF + idx];
  for (int ol = 0; ol < 16; ++ol){
    float acc = dcb[o0 + ol];
    #pragma unroll
    for (int j = 0; j < 63; ++j) acc += v[j]*sw[ol*63 + j];
    out[(size_t)(o0 + ol)*HWF + idx] = fmaxf(acc, 0.f);
  }
}

extern "C" void kernel_launch(void* const* d_in, const int* in_sizes, int n_in,
                              void* d_out, int out_size, void* d_ws, size_t ws_size,
                              hipStream_t stream)
{
  const float* lqs   = (const float*)d_in[0];
  const float* preds = (const float*)d_in[1];
  const float* mv    = (const float*)d_in[2];
  const float* bw1   = (const float*)d_in[3];
  const float* bb1   = (const float*)d_in[4];
  const float* bw2   = (const float*)d_in[5];
  const float* bb2   = (const float*)d_in[6];
  const float* dn1w  = (const float*)d_in[7];
  const float* dn1b  = (const float*)d_in[8];
  const float* dn2w  = (const float*)d_in[9];
  const float* dn2b  = (const float*)d_in[10];
  const float* up1cw = (const float*)d_in[11];
  const float* up1cb = (const float*)d_in[12];
  const float* up1tw = (const float*)d_in[13];
  const float* up1tb = (const float*)d_in[14];
  const float* up2cw = (const float*)d_in[15];
  const float* up2cb = (const float*)d_in[16];
  const float* up2tw = (const float*)d_in[17];
  const float* up2tb = (const float*)d_in[18];
  const float* trcw  = (const float*)d_in[19];
  const float* trcb  = (const float*)d_in[20];
  const float* trtw  = (const float*)d_in[21];
  const float* trtb  = (const float*)d_in[22];
  const float* ffw   = (const float*)d_in[23];
  const float* ffb   = (const float*)d_in[24];
  const float* omw   = (const float*)d_in[25];
  const float* omb   = (const float*)d_in[26];
  const float* dcw   = (const float*)d_in[27];
  const float* dcb   = (const float*)d_in[28];
  float* outp = (float*)d_out;

  char* p = (char*)d_ws;
  const size_t PIMG64 = (size_t)PDIM*PDIM*64;
  u16t* spadreg  = (u16t*)p; p += 14*PIMG64*2;                // spad [194][194][448]; later featfpad
  u16t* fpad     = (u16t*)p; p += (size_t)PDIM*PDIM*448*2;    // feat NHWC448; later vbuf (fp32)
  u16t* prednhwc = (u16t*)p; p += (size_t)7*HWF*64*2;         // pred NHWC64; later om (fp32)
  u16t* out0pad  = (u16t*)p; p += (size_t)PDIM*PDIM*64*2;
  u16t* cat1pad  = (u16t*)p; p += (size_t)98*98*128*2;
  u16t* cat2pad  = (u16t*)p; p += (size_t)50*50*128*2;
  float* t0      = (float*)p; p += (size_t)24*24*64*4;
  float* u2      = (float*)p; p += (size_t)48*48*64*4;
  float* u1      = (float*)p; p += (size_t)96*96*64*4;
  u16t* ffwpack  = (u16t*)p; p += 258048*2;
  u16t* c2pack   = (u16t*)p; p += 36864*2;
  u16t* ompack   = (u16t*)p; p += 110592*2;
  u16t* dn1pack  = (u16t*)p; p += 36864*2;
  u16t* dn2pack  = (u16t*)p; p += 36864*2;
  u16t* trcpack  = (u16t*)p; p += 36864*2;
  u16t* up2cpack = (u16t*)p; p += 73728*2;
  u16t* up1cpack = (u16t*)p; p += 73728*2;
  u16t* w1pack   = (u16t*)p; p += 2048*2;
  float* wp0     = (float*)p; p += 65536*4;
  float* wp1     = (float*)p; p += 65536*4;
  float* wp2     = (float*)p; p += 65536*4;

  u16t* spad = spadreg;
  u16t* featfpad = spadreg;
  float* om = (float*)prednhwc;
  float* vbuf = (float*)fpad;

  dim3 blk(256);
  // setup
  PkD8 pk = {{ {ffw, ffwpack, 448, 64, 4, 258048}, {bw2, c2pack, 64, 64, 4, 36864},
               {omw, ompack, 64, 189, 12, 110592}, {dn1w, dn1pack, 64, 64, 4, 36864},
               {dn2w, dn2pack, 64, 64, 4, 36864},  {trcw, trcpack, 64, 64, 4, 36864},
               {up2cw, up2cpack, 128, 64, 4, 73728}, {up1cw, up1cpack, 128, 64, 4, 73728} }};
  pack_all<<<dim3(1008,8), blk, 0, stream>>>(pk);
  pack_w1<<<dim3(8), blk, 0, stream>>>(bw1, w1pack);
  RpD3 rp3 = {{ {trtw, wp0}, {up2tw, wp1}, {up1tw, wp2} }};
  repack_all<<<dim3(64,3), blk, 0, stream>>>(rp3);
  PzD5 pz = {{ {spad, 448, PDIM, 1, 0}, {fpad, 448, PDIM, 1, 0},
               {out0pad, 64, PDIM, 1, 0}, {cat1pad, 128, 98, 1, 0}, {cat2pad, 128, 50, 1, 0} }};
  padzero_all<<<dim3(2704,5), blk, 0, stream>>>(pz);
  // fused backbone (conv1 MFMA-via-LDS + conv2 MFMA, no HBM intermediate)
  bbfused<<<dim3(8064), blk, 0, stream>>>(lqs, preds, w1pack, bb1, c2pack, bb2, fpad, prednhwc);
  // gate (+warp) -> spad (channel-quartered for occupancy)
  gate_nhwc<<<dim3(144,4), blk, 0, stream>>>(fpad, prednhwc, mv, spad);
  // fused dual conv -> out0pad
  cgemm<2,14,4,4,1><<<dim3(576,1), blk, 0, stream>>>(spad, fpad, ffwpack, ffb,
      nullptr, out0pad, nullptr, 64, 576, PDIM, 448, 0, 14);
  // U-Net (NT=1 o-splits for occupancy)
  gconv3<1,2,2,1,1,1><<<dim3(144,4), blk, 0, stream>>>(out0pad, dn1pack, dn1b, nullptr, cat1pad,
      64, 96, 6, 144, PDIM, 64, 0, 0, 0, 98, 128, 64, 2, 4);       // out1 -> cat1[64:]
  gconv3<1,2,2,1,1,0><<<dim3(36,4), blk, 0, stream>>>(cat1pad, dn2pack, dn2b, nullptr, cat2pad,
      64, 48, 3, 36, 98, 128, 64, 0, 0, 50, 128, 64, 2, 4);        // out2 -> cat2[64:]
  gconv3<1,2,2,0,1,0><<<dim3(12,4), blk, 0, stream>>>(cat2pad, trcpack, trcb, t0, nullptr,
      64, 24, 2, 12, 50, 128, 64, 0, 0, 0, 0, 0, 2, 4);            // t0 (fp32 NCHW)
  convT_tile2<<<dim3(4,9), blk, 0, stream>>>(t0, wp0, trtb, cat2pad, 24, 3, 50, 128, 0);   // t1 -> cat2[:64]
  gconv3<1,4,1,0,1,0><<<dim3(36,4), blk, 0, stream>>>(cat2pad, up2cpack, up2cb, u2, nullptr,
      64, 48, 3, 36, 50, 128, 0, 0, 0, 0, 0, 0, 4, 4);             // u2 (fp32 NCHW)
  convT_tile2<<<dim3(4,36), blk, 0, stream>>>(u2, wp1, up2tb, cat1pad, 48, 6, 98, 128, 0); // u2t -> cat1[:64]
  gconv3<1,4,1,0,1,1><<<dim3(144,4), blk, 0, stream>>>(cat1pad, up1cpack, up1cb, u1, nullptr,
      64, 96, 6, 144, 98, 128, 0, 0, 0, 0, 0, 0, 4, 4);            // u1 (fp32 NCHW)
  // final convT -> featfpad
  padzero2<<<dim3(194), blk, 0, stream>>>(featfpad, 64, PDIM);
  convT_tile2<<<dim3(4,144), blk, 0, stream>>>(u1, wp2, up1tb, featfpad, 96, 12, PDIM, 64, 0);
  // offsets/masks conv (64 -> 189)
  cgemm<1,2,5,12,1><<<dim3(576,3), blk, 0, stream>>>(featfpad, nullptr, ompack, omb,
      om, nullptr, nullptr, 189, 576, PDIM, 64, 0, 2);
  // deformable conv
  deform_sample_k<<<dim3(144,7), blk, 0, stream>>>(lqs, om, vbuf);
  deform_out_k<<<dim3(144,4), blk, 0, stream>>>(vbuf, dcw, dcb, outp);
}

// Round 15
// 565.860 us; speedup vs baseline: 1.1183x; 1.0017x over previous
//
#include <hip/hip_runtime.h>
#include <math.h>

#define IMH 192
#define IMW 192
#define HWF 36864
#define PDIM 194

typedef unsigned short u16t;
typedef __attribute__((ext_vector_type(8))) short short8;
typedef __attribute__((ext_vector_type(4))) short s16x4;
typedef __attribute__((ext_vector_type(4))) float f32x4;

__device__ __forceinline__ float sigmoidf(float x){ return 1.f/(1.f+expf(-x)); }
__device__ __forceinline__ float lrelu(float x){ return x > 0.f ? x : 0.1f*x; }
__device__ __forceinline__ float b2f(u16t h){ unsigned u = ((unsigned)h)<<16; return __uint_as_float(u); }
__device__ __forceinline__ u16t f2b(float f){
  unsigned u = __float_as_uint(f);
  u += 0x7FFFu + ((u>>16)&1u);
  return (u16t)(u>>16);
}

__device__ __forceinline__ float bilin(const float* __restrict__ img, float ys, float xs, int H, int W){
  float y0f = floorf(ys), x0f = floorf(xs);
  float wy = ys - y0f, wx = xs - x0f;
  int y0 = (int)y0f, x0 = (int)x0f;
  float acc = 0.f;
  #pragma unroll
  for (int dy=0; dy<2; ++dy){
    int yi = y0+dy;
    float wyv = dy ? wy : 1.f-wy;
    if (yi < 0 || yi >= H) continue;
    #pragma unroll
    for (int dx=0; dx<2; ++dx){
      int xi = x0+dx;
      float wxv = dx ? wx : 1.f-wx;
      if (xi < 0 || xi >= W) continue;
      acc += img[yi*W+xi]*(wyv*wxv);
    }
  }
  return acc;
}

// ================= descriptor-driven setup kernels =================
struct PkD { const float* w; u16t* dst; int Cin, Cout, NT, total; };
struct PkD8 { PkD d[8]; };
__global__ __launch_bounds__(256) void pack_all(PkD8 ds){
  PkD d = ds.d[blockIdx.y];
  int id = blockIdx.x*256 + threadIdx.x;
  if (id >= d.total) return;
  int j = id & 7, l = (id>>3) & 63;
  int r = id >> 9;
  int nt = r % d.NT; r /= d.NT;
  int KC = d.Cin >> 5;
  int kc = r % KC; int tap = r / KC;
  int c = kc*32 + ((l>>4)<<3) + j;
  int o = nt*16 + (l&15);
  float v = (o < d.Cout) ? d.w[((size_t)o*d.Cin + c)*9 + tap] : 0.f;
  d.dst[id] = f2b(v);
}

// conv1 weights (64,1,3,3) -> MFMA frag, K padded 9->32: [nt][lane][8] (lane&15 = o, q*8+j = k)
__global__ __launch_bounds__(256) void pack_w1(const float* __restrict__ w1, u16t* __restrict__ dst){
  int id = blockIdx.x*256 + threadIdx.x;   // 2048
  int j = id & 7, l = (id>>3) & 63, nt = id >> 9;
  int o = nt*16 + (l&15);
  int k = ((l>>4)<<3) + j;
  float v = (k < 9) ? w1[o*9 + k] : 0.f;
  dst[id] = f2b(v);
}

struct RpD { const float* w; float* wp; };
struct RpD3 { RpD d[3]; };
__global__ __launch_bounds__(256) void repack_all(RpD3 ds){
  RpD d = ds.d[blockIdx.y];
  int id = blockIdx.x*256 + threadIdx.x;
  int par = id >> 12, o = (id >> 6) & 63, i = id & 63;
  int ry = par >> 1, rx = par & 1;
  #pragma unroll
  for (int jy = 0; jy < 2; ++jy)
    #pragma unroll
    for (int jx = 0; jx < 2; ++jx){
      int ka = 3 - ry - 2*jy, kb = 3 - rx - 2*jx;
      d.wp[((size_t)((par*64 + o)*64 + i))*4 + jy*2 + jx] = d.w[((size_t)(i*64 + o))*16 + ka*4 + kb];
    }
}

struct PzD { u16t* buf; int C, dim, nimg; size_t stride; };
struct PzD5 { PzD d[5]; };
__global__ __launch_bounds__(256) void padzero_all(PzD5 ds){
  PzD d = ds.d[blockIdx.y];
  int per = (4*d.dim - 4)*d.C;
  long total = (long)per*d.nimg;
  for (long id = (long)blockIdx.x*256 + threadIdx.x; id < total; id += (long)gridDim.x*256){
    int n = (int)(id / per), c2 = (int)(id % per);
    int cell = c2 / d.C, c = c2 % d.C;
    int d2 = d.dim - 1;
    int r, col;
    if (cell < d.dim){ r = 0; col = cell; }
    else if (cell < 2*d.dim){ r = d2; col = cell - d.dim; }
    else if (cell < 3*d.dim - 2){ r = cell - 2*d.dim + 1; col = 0; }
    else { r = cell - (3*d.dim - 2) + 1; col = d2; }
    d.buf[(size_t)n*d.stride + ((size_t)r*d.dim + col)*d.C + c] = 0;
  }
}

__global__ __launch_bounds__(256) void padzero2(u16t* buf, int C, int dim){
  int total = (4*dim - 4)*C;
  for (int id = blockIdx.x*256 + threadIdx.x; id < total; id += gridDim.x*256){
    int cell = id / C, c = id % C;
    int d2 = dim - 1;
    int r, col;
    if (cell < dim){ r = 0; col = cell; }
    else if (cell < 2*dim){ r = d2; col = cell - dim; }
    else if (cell < 3*dim - 2){ r = cell - 2*dim + 1; col = 0; }
    else { r = cell - (3*dim - 2) + 1; col = d2; }
    buf[((size_t)r*dim + col)*C + c] = 0;
  }
}

// ========== fused backbone: conv1 (1->64, MFMA, weights-as-A) + conv2 (64->64, MFMA, weights-as-A) ==========
// Operand-swap trick: A-frag and B-frag share the same lane->(non-k,k) mapping, so
// mfma(weights, activations) gives D[o][px]: each lane holds 4 consecutive CHANNELS at
// one pixel -> ds_write_b64 to sA (conv1) and 8B global stores (conv2).
__global__ __launch_bounds__(256) void bbfused(
    const float* __restrict__ lqs, const float* __restrict__ preds,
    const u16t* __restrict__ w1pack, const float* __restrict__ b1,
    const u16t* __restrict__ Bp, const float* __restrict__ b2,
    u16t* __restrict__ fpad, u16t* __restrict__ prednhwc)
{
  __shared__ float sIn1[8][20];
  __shared__ u16t sK[113*16];     // per-pixel K-vectors; row 112 = zeros (q>=2 source)
  __shared__ u16t sF[116];        // per-pixel border flag
  __shared__ u16t sA[112*64];     // feat1 tile (swizzled); rows 108-111 scratch
  int bid = blockIdx.x;
  bid = (bid & 7)*(gridDim.x >> 3) + (bid >> 3);       // XCD banding
  const int tid = threadIdx.x;
  const int img = bid / 576;
  const int rem = bid - img*576;
  const int y0 = (rem/12)*4, xs = (rem%12)*16;
  const float* ip = (img < 7) ? (lqs + (size_t)img*HWF) : (preds + (size_t)(img-7)*HWF);
  for (int u = tid; u < 160; u += 256){
    int lr = u/20, lc = u%20;
    int iy = y0 - 2 + lr, ix = xs - 2 + lc;
    sIn1[lr][lc] = (iy >= 0 && iy < IMH && ix >= 0 && ix < IMW) ? ip[iy*IMW + ix] : 0.f;
  }
  const int wave = tid >> 6, lane = tid & 63;
  const int m = lane & 15, q = lane >> 4;
  // conv1 A-frag (weights) + per-lane 4-channel bias
  short8 w1f = *(const short8*)(w1pack + (size_t)wave*512 + lane*8);
  f32x4 b1v = *(const f32x4*)(b1 + wave*16 + q*4);
  __syncthreads();
  // ---- phase 1: build sK + border flags ----
  if (tid < 113){
    int px = tid;
    short8 lo = (short8){0,0,0,0,0,0,0,0};
    short8 hi = (short8){0,0,0,0,0,0,0,0};
    u16t fl = 0;
    if (px < 108){
      int rr = px/18, cc = px%18;
      #pragma unroll
      for (int k = 0; k < 8; ++k) lo[k] = (short)f2b(sIn1[rr + k/3][cc + k%3]);
      hi[0] = (short)f2b(sIn1[rr + 2][cc + 2]);
      int pr = y0 + rr, pc = xs + cc;
      fl = ((pr == 0) | (pr == 193) | (pc == 0) | (pc == 193)) ? (u16t)1 : (u16t)0;
    }
    *(short8*)&sK[px*16] = lo;
    *(short8*)&sK[px*16 + 8] = hi;
    sF[px] = fl;
  }
  if (tid == 113){
    short8 z = (short8){0,0,0,0,0,0,0,0};
    *(short8*)&sK[112*16] = z;
    *(short8*)&sK[112*16 + 8] = z;
  }
  __syncthreads();
  // ---- phase 2: conv1 MFMA (weights as A) -> sA via ds_write_b64 ----
  {
    const bool edgeBlk = (y0 == 0) | (y0 == 188) | (xs == 0) | (xs == 176);
    const int g = wave*2 + (q>>1);   // 8-ch swizzle group of channels wave*16+q*4..+3
    const int sub = (q&1)*4;
    #pragma unroll
    for (int tile = 0; tile < 7; ++tile){
      int pxo = tile*16 + m;
      const u16t* bpK = (q < 2) ? &sK[pxo*16 + q*8] : &sK[112*16];
      short8 bv = *(const short8*)bpK;
      f32x4 z = {0.f,0.f,0.f,0.f};
      f32x4 d = __builtin_amdgcn_mfma_f32_16x16x32_bf16(w1f, bv, z, 0, 0, 0);
      s16x4 ov;
      if (edgeBlk){
        u16t fl = sF[pxo];
        #pragma unroll
        for (int r = 0; r < 4; ++r) ov[r] = fl ? (short)0 : (short)f2b(d[r] + b1v[r]);
      } else {
        #pragma unroll
        for (int r = 0; r < 4; ++r) ov[r] = (short)f2b(d[r] + b1v[r]);
      }
      *(s16x4*)&sA[(size_t)pxo*64 + ((g + pxo)&7)*8 + sub] = ov;
    }
  }
  __syncthreads();
  // ---- conv2 MFMA from sA (weights as A) ----
  const int rp = wave >> 1, np = wave & 1;
  f32x4 acc[2][2];
  #pragma unroll
  for (int r = 0; r < 2; ++r)
    #pragma unroll
    for (int n = 0; n < 2; ++n) acc[r][n] = (f32x4){0.f,0.f,0.f,0.f};
  #pragma unroll
  for (int kc = 0; kc < 2; ++kc){
    #pragma unroll
    for (int tap = 0; tap < 9; ++tap){
      const int dy = tap/3, dx = tap%3;
      short8 af[2];
      #pragma unroll
      for (int r = 0; r < 2; ++r){
        int px = (2*rp + r + dy)*18 + dx + m;
        af[r] = *(const short8*)&sA[(size_t)px*64 + ((kc*4 + q + px)&7)*8];
      }
      const u16t* bp = Bp + ((size_t)(tap*2 + kc)*4 + np*2)*512 + lane*8;
      short8 b0 = *(const short8*)bp;
      short8 b1w = *(const short8*)(bp + 512);
      #pragma unroll
      for (int r = 0; r < 2; ++r){
        acc[r][0] = __builtin_amdgcn_mfma_f32_16x16x32_bf16(b0,  af[r], acc[r][0], 0, 0, 0);
        acc[r][1] = __builtin_amdgcn_mfma_f32_16x16x32_bf16(b1w, af[r], acc[r][1], 0, 0, 0);
      }
    }
  }
  // epilogue: lane holds 4 consecutive channels at pixel (xs+m) -> 4x 8B stores
  f32x4 b2v[2];
  b2v[0] = *(const f32x4*)(b2 + (np*2 + 0)*16 + q*4);
  b2v[1] = *(const f32x4*)(b2 + (np*2 + 1)*16 + q*4);
  const int px = xs + m;
  #pragma unroll
  for (int r = 0; r < 2; ++r){
    int yout = y0 + 2*rp + r;
    #pragma unroll
    for (int n = 0; n < 2; ++n){
      s16x4 ov;
      #pragma unroll
      for (int rr = 0; rr < 4; ++rr) ov[rr] = (short)f2b(acc[r][n][rr] + b2v[n][rr]);
      int oo = (np*2 + n)*16 + q*4;
      if (img < 7)
        *(s16x4*)&fpad[((size_t)(yout+1)*PDIM + px+1)*448 + (size_t)img*64 + oo] = ov;
      else
        *(s16x4*)&prednhwc[(size_t)(img-7)*((size_t)HWF*64) + ((size_t)yout*IMW + px)*64 + oo] = ov;
    }
  }
}

// ========== LDS-staged MFMA implicit-GEMM 3x3 stride-1 conv (swizzled sA, stride 32) ==========
// OMODE 4: fuse (weights-as-A swap; NHWC64 out via 8B stores). OMODE 5: fp32 NCHW, orig orientation.
template<int STREAMS, int KC, int OMODE, int NTT, int SWZ>
__global__ __launch_bounds__(256) void cgemm(
    const u16t* __restrict__ A0, const u16t* __restrict__ A1,
    const u16t* __restrict__ Bp, const float* __restrict__ bias,
    float* __restrict__ outf, u16t* __restrict__ outb, u16t* __restrict__ outb2,
    int Cout, int blocksPerImg, int pitchIn, int csIn, size_t aImgStride, int KCtot)
{
  __shared__ u16t sA[STREAMS*108*32];
  int bid = blockIdx.x;
  if (SWZ) bid = (bid & 7)*(gridDim.x >> 3) + (bid >> 3);
  const int tid = threadIdx.x;
  const int wave = tid >> 6, lane = tid & 63;
  const int m = lane & 15, q = lane >> 4;
  const int img = bid / blocksPerImg;
  const int rem = bid - img*blocksPerImg;
  const int y0 = (rem/12)*4, xs = (rem%12)*16;
  const int rp = wave >> 1, np = wave & 1;
  const int ntB = (OMODE == 5) ? blockIdx.y*4 : 0;
  f32x4 acc[STREAMS][2][2];
  #pragma unroll
  for (int s = 0; s < STREAMS; ++s)
    #pragma unroll
    for (int r = 0; r < 2; ++r)
      #pragma unroll
      for (int n = 0; n < 2; ++n) acc[s][r][n] = (f32x4){0.f,0.f,0.f,0.f};

  #pragma unroll 1
  for (int kc = 0; kc < KC; ++kc){
    if (kc) __syncthreads();
    for (int u = tid; u < STREAMS*216; u += 256){
      int st = u/216, r2 = u%216, p = r2>>1, h = r2&1;
      int rr = p/18, cc = p%18;
      size_t ga = (size_t)img*aImgStride + ((size_t)(y0+rr)*pitchIn + xs+cc)*csIn + kc*32 + h*16;
      const u16t* gp = ((STREAMS==2 && st==1) ? A1 : A0) + ga;
      short8 v0 = *(const short8*)gp;
      short8 v1 = *(const short8*)(gp + 8);
      u16t* base = &sA[((size_t)(st*108 + p))*32];
      *(short8*)(base + ((2*h + p)&3)*8) = v0;
      *(short8*)(base + ((2*h + 1 + p)&3)*8) = v1;
    }
    __syncthreads();
    #pragma unroll
    for (int tap = 0; tap < 9; ++tap){
      const int dy = tap/3, dx = tap%3;
      short8 af[STREAMS][2];
      #pragma unroll
      for (int st = 0; st < STREAMS; ++st)
        #pragma unroll
        for (int r = 0; r < 2; ++r){
          int px = (2*rp + r + dy)*18 + dx + m;
          af[st][r] = *(const short8*)&sA[((size_t)(st*108 + px))*32 + ((q + px)&3)*8];
        }
      const u16t* bp = Bp + ((size_t)(tap*KCtot + kc)*NTT + ntB + np*2)*512 + lane*8;
      short8 b0 = *(const short8*)bp;
      short8 b1 = *(const short8*)(bp + 512);
      #pragma unroll
      for (int st = 0; st < STREAMS; ++st)
        #pragma unroll
        for (int r = 0; r < 2; ++r){
          if constexpr (OMODE == 4){
            acc[st][r][0] = __builtin_amdgcn_mfma_f32_16x16x32_bf16(b0, af[st][r], acc[st][r][0], 0, 0, 0);
            acc[st][r][1] = __builtin_amdgcn_mfma_f32_16x16x32_bf16(b1, af[st][r], acc[st][r][1], 0, 0, 0);
          } else {
            acc[st][r][0] = __builtin_amdgcn_mfma_f32_16x16x32_bf16(af[st][r], b0, acc[st][r][0], 0, 0, 0);
            acc[st][r][1] = __builtin_amdgcn_mfma_f32_16x16x32_bf16(af[st][r], b1, acc[st][r][1], 0, 0, 0);
          }
        }
    }
  }
  if constexpr (OMODE == 4){
    // D[o][px]: lane holds 4 consecutive channels at pixel xs+m
    f32x4 bv[2];
    bv[0] = *(const f32x4*)(bias + (np*2 + 0)*16 + q*4);
    bv[1] = *(const f32x4*)(bias + (np*2 + 1)*16 + q*4);
    const int px = xs + m;
    #pragma unroll
    for (int r = 0; r < 2; ++r){
      int yout = y0 + 2*rp + r;
      #pragma unroll
      for (int n = 0; n < 2; ++n){
        s16x4 ov;
        #pragma unroll
        for (int rr = 0; rr < 4; ++rr){
          float v = 0.1f*lrelu(acc[0][r][n][rr] + bv[n][rr]) + lrelu(acc[STREAMS-1][r][n][rr] + bv[n][rr]);
          ov[rr] = (short)f2b(v);
        }
        int oo = (np*2 + n)*16 + q*4;
        *(s16x4*)&outb[((size_t)(yout+1)*PDIM + px+1)*64 + oo] = ov;
      }
    }
  } else {
    const int px0 = q*4;
    #pragma unroll
    for (int r = 0; r < 2; ++r){
      int yout = y0 + 2*rp + r;
      #pragma unroll
      for (int n = 0; n < 2; ++n){
        int oL = (np*2 + n)*16 + m;
        int o = ntB*16 + oL;
        if (o < Cout){
          float bvv = bias[o];
          #pragma unroll
          for (int g = 0; g < 4; ++g){
            int px = xs + px0 + g;
            outf[(size_t)o*HWF + (size_t)yout*IMW + px] = acc[0][r][n][g] + bvv;
          }
        }
      }
    }
  }
}

// ---------- no-LDS MFMA implicit-GEMM (U-Net smalls); blockIdx.y = o-group of NT ----------
template<int NT, int KC, int STRIDE, int OMODE, int ACT, int SWZ>
__global__ __launch_bounds__(256) void gconv3(
    const u16t* __restrict__ A0, const u16t* __restrict__ Bp, const float* __restrict__ bias,
    float* __restrict__ outf, u16t* __restrict__ outb,
    int Cout, int Wout, int strips, int blocksPerImg,
    int pitchIn, int csIn, int coIn, size_t aImgStride,
    size_t outImgStride, int pitchOut, int csOut, int coOut,
    int KCtot, int NTtot)
{
  int bid = blockIdx.x;
  if (SWZ) bid = (bid & 7)*(gridDim.x >> 3) + (bid >> 3);
  const int wave = threadIdx.x >> 6;
  const int lane = threadIdx.x & 63;
  const int img = bid / blocksPerImg;
  const int sid = (bid - img*blocksPerImg)*4 + wave;
  const int y = sid / strips, xs = (sid % strips) * 16;
  const int m = lane & 15, q = lane >> 4;
  const int ntOff = blockIdx.y*NT;
  f32x4 acc[NT];
  #pragma unroll
  for (int nt = 0; nt < NT; ++nt) acc[nt] = (f32x4){0.f,0.f,0.f,0.f};

  for (int tap = 0; tap < 9; ++tap){
    int dy = tap/3, dx = tap%3;
    int row = STRIDE*y + dy;
    int col = (STRIDE == 1) ? (xs + m + dx) : (2*(xs + m) + dx);
    size_t abase = (size_t)img*aImgStride + ((size_t)row*pitchIn + col)*csIn + coIn + q*8;
    const u16t* ap0 = A0 + abase;
    const u16t* bp = Bp + ((size_t)(tap*KCtot)*NTtot + ntOff)*512 + lane*8;
    #pragma unroll
    for (int kc = 0; kc < KC; ++kc){
      short8 av0 = *(const short8*)(ap0 + kc*32);
      #pragma unroll
      for (int nt = 0; nt < NT; ++nt){
        short8 bv = *(const short8*)(bp + (size_t)(kc*NTtot + nt)*512);
        acc[nt] = __builtin_amdgcn_mfma_f32_16x16x32_bf16(av0, bv, acc[nt], 0, 0, 0);
      }
    }
  }
  const int prow0 = q*4;
  #pragma unroll
  for (int nt = 0; nt < NT; ++nt){
    int o = (ntOff + nt)*16 + m;
    if (o >= Cout) continue;
    float bv = bias[o];
    #pragma unroll
    for (int r = 0; r < 4; ++r){
      int px = xs + prow0 + r;
      if (px >= Wout) continue;
      float v = acc[nt][r] + bv;
      if (ACT) v = fmaxf(v, 0.f);
      if (OMODE == 0){
        outf[((size_t)img*Cout + o)*((size_t)Wout*Wout) + (size_t)y*Wout + px] = v;
      } else if (OMODE == 1){
        outb[(size_t)img*outImgStride + ((size_t)(y+1)*pitchOut + px+1)*csOut + coOut + o] = f2b(v);
      } else {
        outb[(size_t)img*outImgStride + ((size_t)y*pitchOut + px)*csOut + coOut + o] = f2b(v);
      }
    }
  }
}

// ---------- gating + flow-warp, channels-last bf16, XCD-banded, channel-quartered ----------
__global__ __launch_bounds__(256) void gate_nhwc(
    const u16t* __restrict__ fpad, const u16t* __restrict__ pred,
    const float* __restrict__ mv, u16t* __restrict__ spad)
{
  int bid = blockIdx.x;
  int cq = blockIdx.y;           // channel quarter: ch [cq*16, cq*16+16)
  int xcd = bid & 7, lb = bid >> 3;
  int idx = (xcd*18 + lb)*256 + threadIdx.x;
  int y = idx/IMW, x = idx%IMW;
  size_t pc = ((size_t)(y+1)*PDIM + (x+1))*448;
  const int co = cq*16;
  const u16t* rp = fpad + pc + 192 + co;
  short8 r8[2];
  #pragma unroll
  for (int c8 = 0; c8 < 2; ++c8) r8[c8] = *(const short8*)(rp + c8*8);
  #pragma unroll 1
  for (int t = 0; t < 7; ++t){
    const u16t* pp = pred + ((size_t)t*HWF + idx)*64 + co;
    u16t* sp = spad + pc + (size_t)t*64 + co;
    const u16t* tp[4]; float tw[4];
    if (t == 0){
      tp[0] = fpad + pc + co; tw[0] = 1.f;
      tp[1] = tp[2] = tp[3] = tp[0]; tw[1] = tw[2] = tw[3] = 0.f;
    } else {
      float fx = mv[(((size_t)(t-1)*HWF + idx))*2 + 0];
      float fy = mv[(((size_t)(t-1)*HWF + idx))*2 + 1];
      float ys = (float)y + fy, xsf = (float)x + fx;
      float y0f = floorf(ys), x0f = floorf(xsf);
      float wy = ys - y0f, wx = xsf - x0f;
      int y0 = (int)y0f, x0i = (int)x0f;
      int kk = 0;
      #pragma unroll
      for (int dy2 = 0; dy2 < 2; ++dy2)
        #pragma unroll
        for (int dx2 = 0; dx2 < 2; ++dx2){
          int yi = y0+dy2, xi = x0i+dx2;
          float wv = (dy2 ? wy : 1.f-wy)*(dx2 ? wx : 1.f-wx);
          bool ok = (yi >= 0 && yi <= 191) && (xi >= 0 && xi <= 191);
          int yc = min(max(yi,0),191), xc = min(max(xi,0),191);
          tp[kk] = fpad + ((size_t)(yc+1)*PDIM + xc+1)*448 + (size_t)(t-1)*64 + co;
          tw[kk] = ok ? wv : 0.f;
          ++kk;
        }
    }
    #pragma unroll
    for (int c8 = 0; c8 < 2; ++c8){
      short8 pv = *(const short8*)(pp + c8*8);
      short8 t0v = *(const short8*)(tp[0] + c8*8);
      short8 t1v = *(const short8*)(tp[1] + c8*8);
      short8 t2v = *(const short8*)(tp[2] + c8*8);
      short8 t3v = *(const short8*)(tp[3] + c8*8);
      short8 ov;
      #pragma unroll
      for (int j = 0; j < 8; ++j){
        float r = b2f((u16t)r8[c8][j]);
        float p = b2f((u16t)pv[j]);
        float a = tw[0]*b2f((u16t)t0v[j]) + tw[1]*b2f((u16t)t1v[j])
                + tw[2]*b2f((u16t)t2v[j]) + tw[3]*b2f((u16t)t3v[j]);
        float sv = a*sigmoidf(a*r) + p*sigmoidf(p*r);
        ov[j] = (short)f2b(sv);
      }
      *(short8*)(sp + c8*8) = ov;
    }
  }
}

// ---------------- convT 4x4 s2 p1 (+relu): parity-decomposed, fp32 in, bf16 NHWC out ----------------
__global__ __launch_bounds__(256) void convT_tile2(
    const float* __restrict__ in, const float* __restrict__ wp,
    const float* __restrict__ bias, u16t* __restrict__ outb,
    int Hin, int tilesX, int pitchOut, int csOut, int coOut)
{
  const int CC = 4;
  __shared__ float sIn[CC][10*11];
  __shared__ float sW[16][CC][4][4];
  const int Win = Hin;
  const int o0 = blockIdx.x*16;
  const int tile = blockIdx.y;
  const int ty0 = (tile/tilesX)*16, tx0 = (tile%tilesX)*16;
  const int tid = threadIdx.x;
  const int py = tid>>4, px = tid&15;
  const int ry = py&1, rx = px&1, par = ry*2 + rx;
  const int lr = py>>1, lc = px>>1;
  const int r0 = ty0>>1, c0 = tx0>>1;
  float acc[16] = {};
  for (int ib = 0; ib < 64; ib += CC){
    for (int i = tid; i < CC*100; i += 256){
      int c = i/100, rem = i%100, r = rem/10, col = rem%10;
      int gy = r0 - 1 + r, gx = c0 - 1 + col;
      float v = 0.f;
      if (gy >= 0 && gy < Hin && gx >= 0 && gx < Win)
        v = in[(size_t)(ib + c)*Hin*Win + gy*Win + gx];
      sIn[c][r*11 + col] = v;
    }
    for (int i = tid; i < 1024; i += 256){
      int ol = i >> 6, rem = i & 63, ci = rem >> 4, p2 = (rem >> 2) & 3, j = rem & 3;
      sW[ol][ci][p2][j] = wp[((size_t)((p2*64 + o0 + ol)*64) + ib + ci)*4 + j];
    }
    __syncthreads();
    #pragma unroll
    for (int ci = 0; ci < CC; ++ci){
      int rb = lr + ry, cb = lc + rx;
      float t00 = sIn[ci][rb*11 + cb],     t01 = sIn[ci][rb*11 + cb + 1];
      float t10 = sIn[ci][(rb+1)*11 + cb], t11 = sIn[ci][(rb+1)*11 + cb + 1];
      #pragma unroll
      for (int ol = 0; ol < 16; ++ol){
        const float* wv = &sW[ol][ci][par][0];
        acc[ol] += t00*wv[0] + t01*wv[1] + t10*wv[2] + t11*wv[3];
      }
    }
    __syncthreads();
  }
  int gy = ty0 + py, gx = tx0 + px;
  u16t* op = outb + ((size_t)(gy+1)*pitchOut + gx+1)*csOut + coOut + o0;
  short8 pa, pb;
  #pragma unroll
  for (int i = 0; i < 8; ++i) pa[i] = (short)f2b(fmaxf(acc[i] + bias[o0+i], 0.f));
  #pragma unroll
  for (int i = 0; i < 8; ++i) pb[i] = (short)f2b(fmaxf(acc[8+i] + bias[o0+8+i], 0.f));
  *(short8*)op = pa;
  *(short8*)(op + 8) = pb;
}

// ---------------- deformable conv ----------------
__global__ __launch_bounds__(256) void deform_sample_k(
    const float* __restrict__ lqs, const float* __restrict__ om,
    float* __restrict__ vbuf)
{
  int idx = blockIdx.x*256 + threadIdx.x;
  int g = blockIdx.y;
  int h = idx / IMW, x = idx % IMW;
  const float* img = lqs + (size_t)g*HWF;
  #pragma unroll
  for (int k = 0; k < 9; ++k){
    int j = g*9 + k;
    float offy = om[(size_t)(j*2 + 0)*HWF + idx];
    float offx = om[(size_t)(j*2 + 1)*HWF + idx];
    float m = sigmoidf(om[(size_t)(126 + j)*HWF + idx]);
    float ys = (float)(h + (k/3) - 1) + offy;
    float xs = (float)(x + (k%3) - 1) + offx;
    vbuf[(size_t)j*HWF + idx] = bilin(img, ys, xs, IMH, IMW) * m;
  }
}

__global__ __launch_bounds__(256) void deform_out_k(
    const float* __restrict__ vbuf, const float* __restrict__ dcw,
    const float* __restrict__ dcb, float* __restrict__ out)
{
  __shared__ float sw[16*63];
  int idx = blockIdx.x*256 + threadIdx.x;
  int o0 = blockIdx.y*16;
  for (int i = threadIdx.x; i < 16*63; i += 256)
    sw[i] = dcw[(size_t)o0*63 + i];
  __syncthreads();
  float v[63];
  #pragma unroll
  for (int j = 0; j < 63; ++j) v[j] = vbuf[(size_t)j*HWF + idx];
  for (int ol = 0; ol < 16; ++ol){
    float acc = dcb[o0 + ol];
    #pragma unroll
    for (int j = 0; j < 63; ++j) acc += v[j]*sw[ol*63 + j];
    out[(size_t)(o0 + ol)*HWF + idx] = fmaxf(acc, 0.f);
  }
}

extern "C" void kernel_launch(void* const* d_in, const int* in_sizes, int n_in,
                              void* d_out, int out_size, void* d_ws, size_t ws_size,
                              hipStream_t stream)
{
  const float* lqs   = (const float*)d_in[0];
  const float* preds = (const float*)d_in[1];
  const float* mv    = (const float*)d_in[2];
  const float* bw1   = (const float*)d_in[3];
  const float* bb1   = (const float*)d_in[4];
  const float* bw2   = (const float*)d_in[5];
  const float* bb2   = (const float*)d_in[6];
  const float* dn1w  = (const float*)d_in[7];
  const float* dn1b  = (const float*)d_in[8];
  const float* dn2w  = (const float*)d_in[9];
  const float* dn2b  = (const float*)d_in[10];
  const float* up1cw = (const float*)d_in[11];
  const float* up1cb = (const float*)d_in[12];
  const float* up1tw = (const float*)d_in[13];
  const float* up1tb = (const float*)d_in[14];
  const float* up2cw = (const float*)d_in[15];
  const float* up2cb = (const float*)d_in[16];
  const float* up2tw = (const float*)d_in[17];
  const float* up2tb = (const float*)d_in[18];
  const float* trcw  = (const float*)d_in[19];
  const float* trcb  = (const float*)d_in[20];
  const float* trtw  = (const float*)d_in[21];
  const float* trtb  = (const float*)d_in[22];
  const float* ffw   = (const float*)d_in[23];
  const float* ffb   = (const float*)d_in[24];
  const float* omw   = (const float*)d_in[25];
  const float* omb   = (const float*)d_in[26];
  const float* dcw   = (const float*)d_in[27];
  const float* dcb   = (const float*)d_in[28];
  float* outp = (float*)d_out;

  char* p = (char*)d_ws;
  const size_t PIMG64 = (size_t)PDIM*PDIM*64;
  u16t* spadreg  = (u16t*)p; p += 14*PIMG64*2;                // spad [194][194][448]; later featfpad
  u16t* fpad     = (u16t*)p; p += (size_t)PDIM*PDIM*448*2;    // feat NHWC448; later vbuf (fp32)
  u16t* prednhwc = (u16t*)p; p += (size_t)7*HWF*64*2;         // pred NHWC64; later om (fp32)
  u16t* out0pad  = (u16t*)p; p += (size_t)PDIM*PDIM*64*2;
  u16t* cat1pad  = (u16t*)p; p += (size_t)98*98*128*2;
  u16t* cat2pad  = (u16t*)p; p += (size_t)50*50*128*2;
  float* t0      = (float*)p; p += (size_t)24*24*64*4;
  float* u2      = (float*)p; p += (size_t)48*48*64*4;
  float* u1      = (float*)p; p += (size_t)96*96*64*4;
  u16t* ffwpack  = (u16t*)p; p += 258048*2;
  u16t* c2pack   = (u16t*)p; p += 36864*2;
  u16t* ompack   = (u16t*)p; p += 110592*2;
  u16t* dn1pack  = (u16t*)p; p += 36864*2;
  u16t* dn2pack  = (u16t*)p; p += 36864*2;
  u16t* trcpack  = (u16t*)p; p += 36864*2;
  u16t* up2cpack = (u16t*)p; p += 73728*2;
  u16t* up1cpack = (u16t*)p; p += 73728*2;
  u16t* w1pack   = (u16t*)p; p += 2048*2;
  float* wp0     = (float*)p; p += 65536*4;
  float* wp1     = (float*)p; p += 65536*4;
  float* wp2     = (float*)p; p += 65536*4;

  u16t* spad = spadreg;
  u16t* featfpad = spadreg;
  float* om = (float*)prednhwc;
  float* vbuf = (float*)fpad;

  dim3 blk(256);
  // setup
  PkD8 pk = {{ {ffw, ffwpack, 448, 64, 4, 258048}, {bw2, c2pack, 64, 64, 4, 36864},
               {omw, ompack, 64, 189, 12, 110592}, {dn1w, dn1pack, 64, 64, 4, 36864},
               {dn2w, dn2pack, 64, 64, 4, 36864},  {trcw, trcpack, 64, 64, 4, 36864},
               {up2cw, up2cpack, 128, 64, 4, 73728}, {up1cw, up1cpack, 128, 64, 4, 73728} }};
  pack_all<<<dim3(1008,8), blk, 0, stream>>>(pk);
  pack_w1<<<dim3(8), blk, 0, stream>>>(bw1, w1pack);
  RpD3 rp3 = {{ {trtw, wp0}, {up2tw, wp1}, {up1tw, wp2} }};
  repack_all<<<dim3(64,3), blk, 0, stream>>>(rp3);
  PzD5 pz = {{ {spad, 448, PDIM, 1, 0}, {fpad, 448, PDIM, 1, 0},
               {out0pad, 64, PDIM, 1, 0}, {cat1pad, 128, 98, 1, 0}, {cat2pad, 128, 50, 1, 0} }};
  padzero_all<<<dim3(2704,5), blk, 0, stream>>>(pz);
  // fused backbone (conv1 MFMA + conv2 MFMA, weights-as-A, no HBM intermediate)
  bbfused<<<dim3(8064), blk, 0, stream>>>(lqs, preds, w1pack, bb1, c2pack, bb2, fpad, prednhwc);
  // gate (+warp) -> spad (channel-quartered for occupancy)
  gate_nhwc<<<dim3(144,4), blk, 0, stream>>>(fpad, prednhwc, mv, spad);
  // fused dual conv -> out0pad (weights-as-A epilogue)
  cgemm<2,14,4,4,1><<<dim3(576,1), blk, 0, stream>>>(spad, fpad, ffwpack, ffb,
      nullptr, out0pad, nullptr, 64, 576, PDIM, 448, 0, 14);
  // U-Net (NT=1 o-splits for occupancy)
  gconv3<1,2,2,1,1,1><<<dim3(144,4), blk, 0, stream>>>(out0pad, dn1pack, dn1b, nullptr, cat1pad,
      64, 96, 6, 144, PDIM, 64, 0, 0, 0, 98, 128, 64, 2, 4);       // out1 -> cat1[64:]
  gconv3<1,2,2,1,1,0><<<dim3(36,4), blk, 0, stream>>>(cat1pad, dn2pack, dn2b, nullptr, cat2pad,
      64, 48, 3, 36, 98, 128, 64, 0, 0, 50, 128, 64, 2, 4);        // out2 -> cat2[64:]
  gconv3<1,2,2,0,1,0><<<dim3(12,4), blk, 0, stream>>>(cat2pad, trcpack, trcb, t0, nullptr,
      64, 24, 2, 12, 50, 128, 64, 0, 0, 0, 0, 0, 2, 4);            // t0 (fp32 NCHW)
  convT_tile2<<<dim3(4,9), blk, 0, stream>>>(t0, wp0, trtb, cat2pad, 24, 3, 50, 128, 0);   // t1 -> cat2[:64]
  gconv3<1,4,1,0,1,0><<<dim3(36,4), blk, 0, stream>>>(cat2pad, up2cpack, up2cb, u2, nullptr,
      64, 48, 3, 36, 50, 128, 0, 0, 0, 0, 0, 0, 4, 4);             // u2 (fp32 NCHW)
  convT_tile2<<<dim3(4,36), blk, 0, stream>>>(u2, wp1, up2tb, cat1pad, 48, 6, 98, 128, 0); // u2t -> cat1[:64]
  gconv3<1,4,1,0,1,1><<<dim3(144,4), blk, 0, stream>>>(cat1pad, up1cpack, up1cb, u1, nullptr,
      64, 96, 6, 144, 98, 128, 0, 0, 0, 0, 0, 0, 4, 4);            // u1 (fp32 NCHW)
  // final convT -> featfpad
  padzero2<<<dim3(194), blk, 0, stream>>>(featfpad, 64, PDIM);
  convT_tile2<<<dim3(4,144), blk, 0, stream>>>(u1, wp2, up1tb, featfpad, 96, 12, PDIM, 64, 0);
  // offsets/masks conv (64 -> 189)
  cgemm<1,2,5,12,1><<<dim3(576,3), blk, 0, stream>>>(featfpad, nullptr, ompack, omb,
      om, nullptr, nullptr, 189, 576, PDIM, 64, 0, 2);
  // deformable conv
  deform_sample_k<<<dim3(144,7), blk, 0, stream>>>(lqs, om, vbuf);
  deform_out_k<<<dim3(144,4), blk, 0, stream>>>(vbuf, dcw, dcb, outp);
}